// Round 9
// baseline (1632.982 us; speedup 1.0000x reference)
//
#include <hip/hip_runtime.h>
#include <cstddef>
#include <cstdint>

#define NN 20000
#define EE 160000
#define EPRIME 180000   // EE + NN (self loops)
#define GG 128
#define FF 114
#define HH 10
#define HFD 1140        // FF*HH
#define KP 1152         // padded feature dim (36*32, 9*128)
#define F1K 2280        // fcg1 K
#define F1KS 18         // split-K chunks
#define F1KC 128        // chunk size
#define NSCB 79         // scan blocks = cdiv(NN,256)

typedef unsigned short ushort_t;
typedef __attribute__((ext_vector_type(8))) short bf16x8;
typedef __attribute__((ext_vector_type(4))) float f32x4;

static inline int cdiv(int a, int b) { return (a + b - 1) / b; }

// ---------------- bf16 helpers ----------------

__device__ __forceinline__ ushort_t f2bf(float v) {
    union { float f; unsigned u; } c; c.f = v;
    unsigned u = c.u;
    unsigned r = (u + 0x7fffu + ((u >> 16) & 1u)) >> 16;   // RNE
    return (ushort_t)r;
}
__device__ __forceinline__ float bf2f(ushort_t h) {
    union { unsigned u; float f; } c; c.u = ((unsigned)h) << 16;
    return c.f;
}
// unpack packed (hi | lo<<16) u32 -> fp32 value
__device__ __forceinline__ float pk2f(unsigned w) {
    return bf2f((ushort_t)(w & 0xffffu)) + bf2f((ushort_t)(w >> 16));
}

__device__ __forceinline__ void gload16(const void* g, const ushort_t* l) {
    __builtin_amdgcn_global_load_lds(
        (const __attribute__((address_space(1))) unsigned int*)g,
        (__attribute__((address_space(3))) unsigned int*)l, 16, 0, 0);
}

// ---------------- CSR construction ----------------

__global__ void k_init(int* __restrict__ deg, int* __restrict__ gstart, int* __restrict__ gend) {
    int i = blockIdx.x * blockDim.x + threadIdx.x;
    if (i < NN) deg[i] = 1;               // self loop
    if (i < GG) { gstart[i] = NN; gend[i] = 0; }
}

__global__ void k_count(const int* __restrict__ ei, int* __restrict__ deg) {
    int i = blockIdx.x * blockDim.x + threadIdx.x;
    if (i < EE) atomicAdd(&deg[ei[EE + i]], 1);
}

// hierarchical scan: per-block inclusive + block totals
__global__ void k_scan1(const int* __restrict__ deg, int* __restrict__ offs, int* __restrict__ bsum) {
    __shared__ int tmp[256];
    int b = blockIdx.x, tid = threadIdx.x;
    int i = b * 256 + tid;
    int v = (i < NN) ? deg[i] : 0;
    tmp[tid] = v;
    __syncthreads();
#pragma unroll
    for (int off = 1; off < 256; off <<= 1) {
        int t = (tid >= off) ? tmp[tid - off] : 0;
        __syncthreads();
        tmp[tid] += t;
        __syncthreads();
    }
    if (i < NN) offs[i + 1] = tmp[tid];
    if (tid == 255) bsum[b] = tmp[255];
}

__global__ void k_scan2(int* __restrict__ bsum) {
    __shared__ int tmp[128];
    int tid = threadIdx.x;
    int v = (tid < NSCB) ? bsum[tid] : 0;
    tmp[tid] = v;
    __syncthreads();
#pragma unroll
    for (int off = 1; off < 128; off <<= 1) {
        int t = (tid >= off) ? tmp[tid - off] : 0;
        __syncthreads();
        tmp[tid] += t;
        __syncthreads();
    }
    if (tid < NSCB) bsum[tid] = tmp[tid] - v;   // exclusive prefix
}

// fused: finalize offs + cursor + dinv + graph ranges
__global__ void k_scan3prep(int* __restrict__ offs, const int* __restrict__ bsum,
                            int* __restrict__ cursor, const int* __restrict__ deg,
                            float* __restrict__ dinv, const int* __restrict__ batch,
                            int* __restrict__ gstart, int* __restrict__ gend) {
    int i = blockIdx.x * 256 + threadIdx.x;
    if (i < NN) {
        int o = offs[i + 1] + bsum[i >> 8];   // inclusive prefix up to i
        offs[i + 1] = o;
        cursor[i] = o - deg[i];               // exclusive prefix = offs[i]
        dinv[i] = rsqrtf((float)deg[i]);
        int b = batch[i];
        atomicMin(&gstart[b], i);
        atomicMax(&gend[b], i + 1);
    }
    if (i == 0) offs[0] = 0;
}

__global__ void k_fill(const int* __restrict__ ei, int* __restrict__ cursor, int* __restrict__ csr) {
    int i = blockIdx.x * blockDim.x + threadIdx.x;
    if (i < EPRIME) {
        int s, d;
        if (i < EE) { s = ei[i]; d = ei[EE + i]; }
        else        { s = i - EE; d = s; }
        int pos = atomicAdd(&cursor[d], 1);
        csr[pos] = s;
    }
}

// ---------------- split / transpose-split conversions ----------------

__global__ void k_split_x(const float* __restrict__ x, ushort_t* __restrict__ xhi, ushort_t* __restrict__ xlo) {
    int idx = blockIdx.x * 256 + threadIdx.x;
    if (idx >= NN * 128) return;
    int n = idx >> 7, k = idx & 127;
    float v = (k < FF) ? x[(size_t)n * FF + k] : 0.f;
    ushort_t hi = f2bf(v);
    ushort_t lo = f2bf(v - bf2f(hi));
    xhi[idx] = hi; xlo[idx] = lo;
}

// W [K,Nc] -> T[n][k]=W[k][n], split bf16, zero pad. Coalesced via LDS 64x64 tiles.
__global__ __launch_bounds__(256) void k_tsplitT(const float* __restrict__ W, int K, int Nc,
                                                 int Kpad, ushort_t* __restrict__ Thi,
                                                 ushort_t* __restrict__ Tlo) {
    __shared__ float tile[64][65];
    int kb = blockIdx.x * 64;
    int nb = blockIdx.y * 64;
    int c = threadIdx.x & 63, r4 = threadIdx.x >> 6;
#pragma unroll
    for (int rr = 0; rr < 16; ++rr) {
        int r = r4 * 16 + rr;
        int gk = kb + r, gn = nb + c;
        tile[r][c] = (gk < K && gn < Nc) ? W[(size_t)gk * Nc + gn] : 0.f;
    }
    __syncthreads();
#pragma unroll
    for (int rr = 0; rr < 16; ++rr) {
        int r = r4 * 16 + rr;
        int gn = nb + r, gk = kb + c;
        float v = tile[c][r];
        ushort_t hi = f2bf(v);
        ushort_t lo = f2bf(v - bf2f(hi));
        size_t o = (size_t)gn * Kpad + gk;
        Thi[o] = hi; Tlo[o] = lo;
    }
}

// ---------------- split-bf16 MFMA GEMM, 2-phase dbuf + COLUMN-MAJOR XCD swizzle ----------------
// Column-major block order under the XCD chunking: each XCD owns a column strip, so its
// B col-panel (2.4MB hi+lo) is L2-resident; L3 traffic drops from A*9+B*157 (~2.5GB) to
// A*8+B (~0.84GB). OUTMODE 0: fp32 C. OUTMODE 1: packed u32 (hi|lo<<16).

template <int OUTMODE>
__global__ __launch_bounds__(256) void mfma_gemm(
    const ushort_t* __restrict__ Ahi, const ushort_t* __restrict__ Alo,
    const ushort_t* __restrict__ Bthi, const ushort_t* __restrict__ Btlo,
    int lda, int ldb, int M, int Nreal, int ksteps, int nrb,
    float* __restrict__ C, int ldc,
    unsigned* __restrict__ Cpk, int ldcs) {
    __shared__ __align__(16) ushort_t lds[2 * 4 * 4096];   // [buf][plane][4 kg][128 row][8]
    const int tid = threadIdx.x;
    const int lane = tid & 63;
    const int w = tid >> 6;
    const int wr = w >> 1, wc = w & 1;

    // bijective XCD-chunked swizzle (m204)
    int nwg = gridDim.x;
    int q = nwg >> 3, r8 = nwg & 7;
    int xcd = blockIdx.x & 7, sidx = blockIdx.x >> 3;
    int wg = (xcd < r8 ? xcd * (q + 1) : r8 * (q + 1) + (xcd - r8) * q) + sidx;
    // column-major decode: XCD chunk walks rows within a column
    int bcol = wg / nrb, brow = wg - bcol * nrb;

    int row0 = brow * 128; if (row0 > M - 128) row0 = M - 128;   // overlap trick, idempotent writes
    const int col0 = bcol * 128;

    f32x4 acc[4][4];
#pragma unroll
    for (int i = 0; i < 4; ++i)
#pragma unroll
        for (int j = 0; j < 4; ++j) acc[i][j] = (f32x4){0.f, 0.f, 0.f, 0.f};

    const size_t ldaB = (size_t)lda * 2, ldbB = (size_t)ldb * 2;
    const char* pAhi[2]; const char* pAlo[2]; const char* pBhi[2]; const char* pBlo[2];
    unsigned ldsoff[2];
#pragma unroll
    for (int i = 0; i < 2; ++i) {
        int c = (w * 2 + i) * 64 + lane;
        int kg = c >> 7, r = c & 127;
        pAhi[i] = (const char*)Ahi + (size_t)(row0 + r) * ldaB + kg * 16;
        pAlo[i] = (const char*)Alo + (size_t)(row0 + r) * ldaB + kg * 16;
        pBhi[i] = (const char*)Bthi + (size_t)(col0 + r) * ldbB + kg * 16;
        pBlo[i] = (const char*)Btlo + (size_t)(col0 + r) * ldbB + kg * 16;
        ldsoff[i] = (w * 2 + i) * 512;
    }
    const int kgf = lane >> 4, r15 = lane & 15;

    auto STAGE = [&](int buf, int ks) {
        size_t kb = (size_t)ks * 64;
        unsigned bo = buf ? 16384u : 0u;
#pragma unroll
        for (int i = 0; i < 2; ++i) {
            gload16(pAhi[i] + kb, lds + bo + 0 * 4096 + ldsoff[i]);
            gload16(pAlo[i] + kb, lds + bo + 1 * 4096 + ldsoff[i]);
            gload16(pBhi[i] + kb, lds + bo + 2 * 4096 + ldsoff[i]);
            gload16(pBlo[i] + kb, lds + bo + 3 * 4096 + ldsoff[i]);
        }
    };

    STAGE(0, 0);
    asm volatile("s_waitcnt vmcnt(0)" ::: "memory");
    __syncthreads();
    int cur = 0;

    for (int ks = 0; ks < ksteps; ++ks) {
        if (ks + 1 < ksteps) STAGE(cur ^ 1, ks + 1);   // prefetch flies during MFMA
        const ushort_t* lb = lds + (cur ? 16384u : 0u);
        bf16x8 ah[4], al[4], bh[4], bl[4];
#pragma unroll
        for (int i = 0; i < 4; ++i) {
            int ra = wr * 64 + i * 16 + r15;
            int rb = wc * 64 + i * 16 + r15;
            ah[i] = *(const bf16x8*)(lb + 0 * 4096 + kgf * 1024 + ra * 8);
            al[i] = *(const bf16x8*)(lb + 1 * 4096 + kgf * 1024 + ra * 8);
            bh[i] = *(const bf16x8*)(lb + 2 * 4096 + kgf * 1024 + rb * 8);
            bl[i] = *(const bf16x8*)(lb + 3 * 4096 + kgf * 1024 + rb * 8);
        }
#pragma unroll
        for (int i = 0; i < 4; ++i)
#pragma unroll
            for (int j = 0; j < 4; ++j) {
                acc[i][j] = __builtin_amdgcn_mfma_f32_16x16x32_bf16(ah[i], bh[j], acc[i][j], 0, 0, 0);
                acc[i][j] = __builtin_amdgcn_mfma_f32_16x16x32_bf16(ah[i], bl[j], acc[i][j], 0, 0, 0);
                acc[i][j] = __builtin_amdgcn_mfma_f32_16x16x32_bf16(al[i], bh[j], acc[i][j], 0, 0, 0);
            }
        asm volatile("s_waitcnt vmcnt(0)" ::: "memory");
        __syncthreads();
        cur ^= 1;
    }

    const int g4 = lane >> 4;
#pragma unroll
    for (int i = 0; i < 4; ++i)
#pragma unroll
        for (int j = 0; j < 4; ++j) {
            int c = col0 + wc * 64 + j * 16 + r15;
#pragma unroll
            for (int reg = 0; reg < 4; ++reg) {
                int r = row0 + wr * 64 + i * 16 + g4 * 4 + reg;
                float v = acc[i][j][reg];
                if (OUTMODE == 0) {
                    if (r < M && c < Nreal) C[(size_t)r * ldc + c] = v;
                } else {
                    if (r < M) {
                        if (c >= Nreal) v = 0.f;
                        ushort_t hi = f2bf(v);
                        ushort_t lo = f2bf(v - bf2f(hi));
                        Cpk[(size_t)r * ldcs + c] = (unsigned)hi | ((unsigned)lo << 16);
                    }
                }
            }
        }
}

// ---------------- attention logits from packed h0 ----------------

__global__ void k_att(const unsigned* __restrict__ h0pk,
                      const float* __restrict__ att_src, const float* __restrict__ att_dst,
                      float* __restrict__ as_, float* __restrict__ ad_) {
    int id = blockIdx.x * blockDim.x + threadIdx.x;
    if (id >= NN * HH) return;
    int n = id / HH, h = id % HH;
    const unsigned* row = h0pk + (size_t)n * KP + h * FF;
    const float* ws = att_src + h * FF;
    const float* wd = att_dst + h * FF;
    float as = 0.f, ad = 0.f;
    for (int f = 0; f < FF; f += 2) {
        uint2 q = *(const uint2*)(row + f);
        float v0 = pk2f(q.x);
        float v1 = pk2f(q.y);
        as += v0 * ws[f] + v1 * ws[f + 1];
        ad += v0 * wd[f] + v1 * wd[f + 1];
    }
    as_[id] = as;
    ad_[id] = ad;
}

// ---------------- GAT aggregation: packed h0, 4-edge unroll ----------------
// softmax WITHOUT max-subtraction (shift-invariant; logits are O(1))

__global__ __launch_bounds__(256) void gat_agg(
    const unsigned* __restrict__ h0pk,
    const float* __restrict__ as_, const float* __restrict__ ad_,
    const int* __restrict__ offs, const int* __restrict__ csr,
    const float* __restrict__ bias,
    ushort_t* __restrict__ outhi, ushort_t* __restrict__ outlo) {
    int lane = threadIdx.x & 63;
    int n = blockIdx.x * 4 + (threadIdx.x >> 6);
    if (n >= NN) return;
    int beg = offs[n], end = offs[n + 1];
    float my_ad = (lane < HH) ? ad_[n * HH + lane] : 0.f;

    int hd[5][4];
#pragma unroll
    for (int j = 0; j < 5; ++j)
#pragma unroll
        for (int e = 0; e < 4; ++e) {
            int k = 4 * (lane + 64 * j) + e;
            hd[j][e] = (k < HFD) ? (k / FF) : 0;
        }

    float den = 0.f;
    float acc[5][4];
#pragma unroll
    for (int j = 0; j < 5; ++j)
#pragma unroll
        for (int e = 0; e < 4; ++e) acc[j][e] = 0.f;

    int eg = beg;
    for (; eg + 4 <= end; eg += 4) {
        int s0 = csr[eg], s1 = csr[eg + 1], s2 = csr[eg + 2], s3 = csr[eg + 3];
        float ex0 = 0.f, ex1 = 0.f, ex2 = 0.f, ex3 = 0.f;
        if (lane < HH) {
            float t0 = as_[s0 * HH + lane] + my_ad; t0 = (t0 >= 0.f) ? t0 : 0.2f * t0;
            float t1 = as_[s1 * HH + lane] + my_ad; t1 = (t1 >= 0.f) ? t1 : 0.2f * t1;
            float t2 = as_[s2 * HH + lane] + my_ad; t2 = (t2 >= 0.f) ? t2 : 0.2f * t2;
            float t3 = as_[s3 * HH + lane] + my_ad; t3 = (t3 >= 0.f) ? t3 : 0.2f * t3;
            ex0 = __expf(t0); ex1 = __expf(t1); ex2 = __expf(t2); ex3 = __expf(t3);
            den += (ex0 + ex1) + (ex2 + ex3);
        }
        const unsigned* hp0 = h0pk + (size_t)s0 * KP;
        const unsigned* hp1 = h0pk + (size_t)s1 * KP;
        const unsigned* hp2 = h0pk + (size_t)s2 * KP;
        const unsigned* hp3 = h0pk + (size_t)s3 * KP;
#pragma unroll
        for (int j = 0; j < 4; ++j) {
            int m = lane + 64 * j;
            uint4 q0 = *(const uint4*)(hp0 + 4 * m);
            uint4 q1 = *(const uint4*)(hp1 + 4 * m);
            uint4 q2 = *(const uint4*)(hp2 + 4 * m);
            uint4 q3 = *(const uint4*)(hp3 + 4 * m);
#pragma unroll
            for (int e = 0; e < 4; ++e) {
                unsigned u0 = (e == 0) ? q0.x : (e == 1) ? q0.y : (e == 2) ? q0.z : q0.w;
                unsigned u1 = (e == 0) ? q1.x : (e == 1) ? q1.y : (e == 2) ? q1.z : q1.w;
                unsigned u2 = (e == 0) ? q2.x : (e == 1) ? q2.y : (e == 2) ? q2.z : q2.w;
                unsigned u3 = (e == 0) ? q3.x : (e == 1) ? q3.y : (e == 2) ? q3.z : q3.w;
                int idx = hd[j][e];
                acc[j][e] += __shfl(ex0, idx, 64) * pk2f(u0) + __shfl(ex1, idx, 64) * pk2f(u1)
                           + __shfl(ex2, idx, 64) * pk2f(u2) + __shfl(ex3, idx, 64) * pk2f(u3);
            }
        }
        if (lane < 29) {
            int m = lane + 256;
            uint4 q0 = *(const uint4*)(hp0 + 4 * m);
            uint4 q1 = *(const uint4*)(hp1 + 4 * m);
            uint4 q2 = *(const uint4*)(hp2 + 4 * m);
            uint4 q3 = *(const uint4*)(hp3 + 4 * m);
#pragma unroll
            for (int e = 0; e < 4; ++e) {
                unsigned u0 = (e == 0) ? q0.x : (e == 1) ? q0.y : (e == 2) ? q0.z : q0.w;
                unsigned u1 = (e == 0) ? q1.x : (e == 1) ? q1.y : (e == 2) ? q1.z : q1.w;
                unsigned u2 = (e == 0) ? q2.x : (e == 1) ? q2.y : (e == 2) ? q2.z : q2.w;
                unsigned u3 = (e == 0) ? q3.x : (e == 1) ? q3.y : (e == 2) ? q3.z : q3.w;
                int idx = hd[4][e];
                acc[4][e] += __shfl(ex0, idx, 64) * pk2f(u0) + __shfl(ex1, idx, 64) * pk2f(u1)
                           + __shfl(ex2, idx, 64) * pk2f(u2) + __shfl(ex3, idx, 64) * pk2f(u3);
            }
        }
    }
    for (; eg < end; ++eg) {
        int s = csr[eg];
        float ex = 0.f;
        if (lane < HH) {
            float t = as_[s * HH + lane] + my_ad;
            t = (t >= 0.f) ? t : 0.2f * t;
            ex = __expf(t);
            den += ex;
        }
        const unsigned* hp = h0pk + (size_t)s * KP;
#pragma unroll
        for (int j = 0; j < 4; ++j) {
            int m = lane + 64 * j;
            uint4 q = *(const uint4*)(hp + 4 * m);
            acc[j][0] += __shfl(ex, hd[j][0], 64) * pk2f(q.x);
            acc[j][1] += __shfl(ex, hd[j][1], 64) * pk2f(q.y);
            acc[j][2] += __shfl(ex, hd[j][2], 64) * pk2f(q.z);
            acc[j][3] += __shfl(ex, hd[j][3], 64) * pk2f(q.w);
        }
        if (lane < 29) {
            int m = lane + 256;
            uint4 q = *(const uint4*)(hp + 4 * m);
            acc[4][0] += __shfl(ex, hd[4][0], 64) * pk2f(q.x);
            acc[4][1] += __shfl(ex, hd[4][1], 64) * pk2f(q.y);
            acc[4][2] += __shfl(ex, hd[4][2], 64) * pk2f(q.z);
            acc[4][3] += __shfl(ex, hd[4][3], 64) * pk2f(q.w);
        }
    }

#pragma unroll
    for (int j = 0; j < 5; ++j) {
        int m = lane + 64 * j;
        if (j == 4 && lane >= 32) break;
        unsigned ohx = 0, ohy = 0, olx = 0, oly = 0;
        if (j < 4 || lane < 29) {
            float vv[4];
#pragma unroll
            for (int e = 0; e < 4; ++e) {
                int k = 4 * m + e;
                float d = __shfl(den, hd[j][e], 64);
                float v = acc[j][e] / d + bias[k];
                vv[e] = (v >= 0.f) ? v : 0.01f * v;
            }
            ushort_t h0s = f2bf(vv[0]); ushort_t l0 = f2bf(vv[0] - bf2f(h0s));
            ushort_t h1s = f2bf(vv[1]); ushort_t l1 = f2bf(vv[1] - bf2f(h1s));
            ushort_t h2s = f2bf(vv[2]); ushort_t l2 = f2bf(vv[2] - bf2f(h2s));
            ushort_t h3s = f2bf(vv[3]); ushort_t l3 = f2bf(vv[3] - bf2f(h3s));
            ohx = (unsigned)h0s | ((unsigned)h1s << 16);
            ohy = (unsigned)h2s | ((unsigned)h3s << 16);
            olx = (unsigned)l0 | ((unsigned)l1 << 16);
            oly = (unsigned)l2 | ((unsigned)l3 << 16);
        }
        // lanes 29..31 at j=4 write zeros (pad cols 1140..1151 must be 0)
        *(uint2*)(outhi + (size_t)n * KP + 4 * m) = make_uint2(ohx, ohy);
        *(uint2*)(outlo + (size_t)n * KP + 4 * m) = make_uint2(olx, oly);
    }
}

// ---------------- GCN aggregation: 4-edge unroll ----------------

__global__ __launch_bounds__(256) void gcn_agg(
    const float* __restrict__ h2, const int* __restrict__ offs, const int* __restrict__ csr,
    const float* __restrict__ dinv, const float* __restrict__ bias, float* __restrict__ out) {
    int lane = threadIdx.x & 63;
    int n = blockIdx.x * 4 + (threadIdx.x >> 6);
    if (n >= NN) return;
    int beg = offs[n], end = offs[n + 1];
    float di = dinv[n];
    float4 acc[5];
#pragma unroll
    for (int j = 0; j < 5; ++j) acc[j] = make_float4(0.f, 0.f, 0.f, 0.f);

    int eg = beg;
    for (; eg + 4 <= end; eg += 4) {
        int s0 = csr[eg], s1 = csr[eg + 1], s2 = csr[eg + 2], s3 = csr[eg + 3];
        float w0 = dinv[s0] * di, w1 = dinv[s1] * di, w2 = dinv[s2] * di, w3 = dinv[s3] * di;
        const float* r0 = h2 + (size_t)s0 * HFD;
        const float* r1 = h2 + (size_t)s1 * HFD;
        const float* r2 = h2 + (size_t)s2 * HFD;
        const float* r3 = h2 + (size_t)s3 * HFD;
#pragma unroll
        for (int j = 0; j < 4; ++j) {
            int m = lane + 64 * j;
            float4 v0 = *(const float4*)(r0 + 4 * m);
            float4 v1 = *(const float4*)(r1 + 4 * m);
            float4 v2 = *(const float4*)(r2 + 4 * m);
            float4 v3 = *(const float4*)(r3 + 4 * m);
            acc[j].x += (w0 * v0.x + w1 * v1.x) + (w2 * v2.x + w3 * v3.x);
            acc[j].y += (w0 * v0.y + w1 * v1.y) + (w2 * v2.y + w3 * v3.y);
            acc[j].z += (w0 * v0.z + w1 * v1.z) + (w2 * v2.z + w3 * v3.z);
            acc[j].w += (w0 * v0.w + w1 * v1.w) + (w2 * v2.w + w3 * v3.w);
        }
        if (lane < 29) {
            int m = lane + 256;
            float4 v0 = *(const float4*)(r0 + 4 * m);
            float4 v1 = *(const float4*)(r1 + 4 * m);
            float4 v2 = *(const float4*)(r2 + 4 * m);
            float4 v3 = *(const float4*)(r3 + 4 * m);
            acc[4].x += (w0 * v0.x + w1 * v1.x) + (w2 * v2.x + w3 * v3.x);
            acc[4].y += (w0 * v0.y + w1 * v1.y) + (w2 * v2.y + w3 * v3.y);
            acc[4].z += (w0 * v0.z + w1 * v1.z) + (w2 * v2.z + w3 * v3.z);
            acc[4].w += (w0 * v0.w + w1 * v1.w) + (w2 * v2.w + w3 * v3.w);
        }
    }
    for (; eg < end; ++eg) {
        int s = csr[eg];
        float w = dinv[s] * di;
        const float* hrow = h2 + (size_t)s * HFD;
#pragma unroll
        for (int j = 0; j < 4; ++j) {
            float4 v = *(const float4*)(hrow + 4 * (lane + 64 * j));
            acc[j].x += w * v.x; acc[j].y += w * v.y;
            acc[j].z += w * v.z; acc[j].w += w * v.w;
        }
        if (lane < 29) {
            float4 v = *(const float4*)(hrow + 4 * (lane + 256));
            acc[4].x += w * v.x; acc[4].y += w * v.y;
            acc[4].z += w * v.z; acc[4].w += w * v.w;
        }
    }

#pragma unroll
    for (int j = 0; j < 5; ++j) {
        if (j == 4 && lane >= 29) break;
        int m = lane + 64 * j;
        float4 b4 = *(const float4*)(bias + 4 * m);
        float4 o;
        o.x = acc[j].x + b4.x; o.x = (o.x >= 0.f) ? o.x : 0.01f * o.x;
        o.y = acc[j].y + b4.y; o.y = (o.y >= 0.f) ? o.y : 0.01f * o.y;
        o.z = acc[j].z + b4.z; o.z = (o.z >= 0.f) ? o.z : 0.01f * o.z;
        o.w = acc[j].w + b4.w; o.w = (o.w >= 0.f) ? o.w : 0.01f * o.w;
        *(float4*)(out + (size_t)n * HFD + 4 * m) = o;
    }
}

// ---------------- graph pooling (max + mean), float4 ----------------

__global__ void k_pool(const float* __restrict__ hfeat, const int* __restrict__ gs,
                       const int* __restrict__ ge, float* __restrict__ gout) {
    int g = blockIdx.x;
    if (threadIdx.x >= 57) return;
    int m = blockIdx.y * 57 + threadIdx.x;
    int s = gs[g], e = ge[g];
    int cnt = e - s;
    float4 mx = make_float4(-1e30f, -1e30f, -1e30f, -1e30f);
    float4 sm = make_float4(0.f, 0.f, 0.f, 0.f);
    for (int r = s; r < e; ++r) {
        float4 v = *(const float4*)(hfeat + (size_t)r * HFD + 4 * m);
        mx.x = fmaxf(mx.x, v.x); mx.y = fmaxf(mx.y, v.y);
        mx.z = fmaxf(mx.z, v.z); mx.w = fmaxf(mx.w, v.w);
        sm.x += v.x; sm.y += v.y; sm.z += v.z; sm.w += v.w;
    }
    float4 mean;
    if (cnt <= 0) {
        mx = make_float4(0.f, 0.f, 0.f, 0.f);
        mean = make_float4(0.f, 0.f, 0.f, 0.f);
    } else {
        float inv = 1.f / (float)cnt;
        mean = make_float4(sm.x * inv, sm.y * inv, sm.z * inv, sm.w * inv);
    }
    *(float4*)(gout + (size_t)g * (2 * HFD) + 4 * m) = mx;
    *(float4*)(gout + (size_t)g * (2 * HFD) + HFD + 4 * m) = mean;
}

// ---------------- fcg1 split-K (kt loop MUST stay rolled — round-3 spill regression) ----------------

__global__ __launch_bounds__(256) void k_fcg1_part(
    const float* __restrict__ A, const float* __restrict__ B, float* __restrict__ part) {
    __shared__ float As[16][64 + 4];
    __shared__ float Bs[16][64 + 4];
    int tid = threadIdx.x;
    int tx = tid & 15, ty = tid >> 4;
    int row0 = blockIdx.y * 64, col0 = blockIdx.x * 64;
    int kbeg = blockIdx.z * F1KC;
    float acc[4][4] = {};
#pragma unroll 1
    for (int kt = 0; kt < F1KC / 16; ++kt) {
        int kk = kbeg + kt * 16;
#pragma unroll
        for (int l = 0; l < 4; ++l) {
            int idx = tid + 256 * l;
            int m = idx >> 4, k = idx & 15;
            int gr = row0 + m, gk = kk + k;
            As[k][m] = (gk < F1K) ? A[(size_t)gr * F1K + gk] : 0.f;
        }
#pragma unroll
        for (int l = 0; l < 4; ++l) {
            int idx = tid + 256 * l;
            int nn = idx & 63, k = idx >> 6;
            int gc = col0 + nn, gk = kk + k;
            Bs[k][nn] = (gc < 1000 && gk < F1K) ? B[(size_t)gk * 1000 + gc] : 0.f;
        }
        __syncthreads();
#pragma unroll
        for (int k = 0; k < 16; ++k) {
            float4 av = *(const float4*)&As[k][ty * 4];
            float4 bv = *(const float4*)&Bs[k][tx * 4];
            float a[4] = {av.x, av.y, av.z, av.w};
            float b[4] = {bv.x, bv.y, bv.z, bv.w};
#pragma unroll
            for (int i = 0; i < 4; ++i)
#pragma unroll
                for (int j = 0; j < 4; ++j) acc[i][j] += a[i] * b[j];
        }
        __syncthreads();
    }
    float* pc = part + (size_t)blockIdx.z * GG * 1000;
#pragma unroll
    for (int i = 0; i < 4; ++i) {
        int r = row0 + ty * 4 + i;
#pragma unroll
        for (int j = 0; j < 4; ++j) {
            int c = col0 + tx * 4 + j;
            if (c < 1000) pc[(size_t)r * 1000 + c] = acc[i][j];
        }
    }
}

__global__ void k_fcg1_red(const float* __restrict__ part, const float* __restrict__ bias,
                           float* __restrict__ out) {
    int idx = blockIdx.x * 256 + threadIdx.x;
    if (idx >= GG * 1000) return;
    float s = 0.f;
#pragma unroll
    for (int k = 0; k < F1KS; ++k) s += part[(size_t)k * GG * 1000 + idx];
    int n = idx % 1000;
    float v = s + bias[n];
    out[idx] = (v >= 0.f) ? v : 0.01f * v;
}

// ---------------- fcg2 ----------------

__global__ __launch_bounds__(256) void k_fcg2(const float* __restrict__ in, const float* __restrict__ W,
                                              const float* __restrict__ b, float* __restrict__ out) {
    __shared__ float part[4][64];
    int g = blockIdx.x;
    int o = threadIdx.x & 63, p = threadIdx.x >> 6;
    const float* row = in + (size_t)g * 1000;
    float acc = 0.f;
    for (int k = p * 250; k < (p + 1) * 250; ++k) acc += row[k] * W[k * 64 + o];
    part[p][o] = acc;
    __syncthreads();
    if (p == 0) out[(size_t)g * 64 + o] = part[0][o] + part[1][o] + part[2][o] + part[3][o] + b[o];
}

// ---------------- final head ----------------

__global__ __launch_bounds__(256) void k_final(
    const float* __restrict__ b1, const float* __restrict__ b2, const float* __restrict__ target,
    const float* __restrict__ fcxtW, const float* __restrict__ fcxtb,
    const float* __restrict__ fc1W, const float* __restrict__ fc1b,
    const float* __restrict__ fc2W, const float* __restrict__ fc2b,
    const float* __restrict__ outW, const float* __restrict__ outb,
    float* __restrict__ out) {
    __shared__ float xc[256];
    __shared__ float xt2[128];
    __shared__ float y1[128];
    __shared__ float y2[32];
    int g = blockIdx.x, t = threadIdx.x;
    if (t < 64) xc[t] = b1[(size_t)g * 64 + t];
    else if (t < 128) xc[t] = b2[(size_t)g * 64 + (t - 64)];
    {
        int c = t & 127, p = t >> 7;
        float acc = 0.f;
        const float* trow = target + (size_t)g * 1000;
        for (int k = p * 500; k < (p + 1) * 500; ++k) acc += trow[k] * fcxtW[k * 128 + c];
        if (p == 1) xt2[c] = acc;
        __syncthreads();
        if (p == 0) xc[128 + c] = acc + xt2[c] + fcxtb[c];
    }
    __syncthreads();
    if (t < 128) {
        float acc = 0.f;
        for (int k = 0; k < 256; ++k) acc += xc[k] * fc1W[k * 128 + t];
        acc += fc1b[t];
        y1[t] = (acc >= 0.f) ? acc : 0.01f * acc;
    }
    __syncthreads();
    if (t < 32) {
        float acc = 0.f;
        for (int k = 0; k < 128; ++k) acc += y1[k] * fc2W[k * 32 + t];
        acc += fc2b[t];
        y2[t] = (acc >= 0.f) ? acc : 0.01f * acc;
    }
    __syncthreads();
    if (t == 0) {
        float acc = 0.f;
        for (int k = 0; k < 32; ++k) acc += y2[k] * outW[k];
        out[g] = acc + outb[0];
    }
}

// ---------------- host launch ----------------

extern "C" void kernel_launch(void* const* d_in, const int* in_sizes, int n_in,
                              void* d_out, int out_size, void* d_ws, size_t ws_size,
                              hipStream_t stream) {
    (void)in_sizes; (void)n_in; (void)out_size; (void)ws_size;

    size_t off = 0;
    auto alloc = [&](size_t bytes) -> void* {
        void* p = (char*)d_ws + off;
        off += (bytes + 255) & ~(size_t)255;
        return p;
    };
    char* regionA = (char*)alloc((size_t)2 * NN * KP * 2);
    char* regionB = (char*)alloc((size_t)2 * NN * KP * 2);
    ushort_t* Bthi = (ushort_t*)alloc((size_t)KP * KP * 2);
    ushort_t* Btlo = (ushort_t*)alloc((size_t)KP * KP * 2);
    float* a_s    = (float*)alloc((size_t)NN * HH * 4);
    float* a_d    = (float*)alloc((size_t)NN * HH * 4);
    int*   deg    = (int*)alloc((size_t)NN * 4);
    int*   offs   = (int*)alloc((size_t)(NN + 1) * 4);
    int*   cursor = (int*)alloc((size_t)NN * 4);
    int*   csr    = (int*)alloc((size_t)EPRIME * 4);
    float* dinv   = (float*)alloc((size_t)NN * 4);
    int*   gstart = (int*)alloc((size_t)GG * 4);
    int*   gend   = (int*)alloc((size_t)GG * 4);
    int*   bsum   = (int*)alloc((size_t)128 * 4);
    float* gpool  = (float*)alloc((size_t)GG * 2 * HFD * 4);
    float* fc1out = (float*)alloc((size_t)GG * 1000 * 4);
    float* bout   = (float*)alloc((size_t)2 * GG * 64 * 4);

    // overlays
    unsigned* h0pk = (unsigned*)regionA;                     // packed (hi|lo<<16) [NN][KP]
    float*    h2f  = (float*)regionA;                        // after h0 is dead
    float*    f1part = (float*)regionA;                      // after h2 is dead
    ushort_t* xhi  = (ushort_t*)regionB;
    ushort_t* xlo  = (ushort_t*)regionB + (size_t)NN * 128;
    ushort_t* h1hi = (ushort_t*)regionB;                     // after x is dead
    ushort_t* h1lo = (ushort_t*)regionB + (size_t)NN * KP;
    float*    hgcn = (float*)regionB;                        // after h1 is dead

    const float* target = (const float*)d_in[6];
    const int NRB = cdiv(NN, 128);        // 157 row blocks
    const int NCB = KP / 128;             // 9 col blocks

    for (int b = 0; b < 2; ++b) {
        const float* x     = (const float*)d_in[b ? 3 : 0];
        const int*   ei    = (const int*)d_in[b ? 4 : 1];
        const int*   batch = (const int*)d_in[b ? 5 : 2];
        int pb = 7 + b * 10;
        const float* gatW    = (const float*)d_in[pb + 0];
        const float* att_src = (const float*)d_in[pb + 1];
        const float* att_dst = (const float*)d_in[pb + 2];
        const float* gatb    = (const float*)d_in[pb + 3];
        const float* gcnW    = (const float*)d_in[pb + 4];
        const float* gcnb    = (const float*)d_in[pb + 5];
        const float* f1W     = (const float*)d_in[pb + 6];
        const float* f1b     = (const float*)d_in[pb + 7];
        const float* f2W     = (const float*)d_in[pb + 8];
        const float* f2b     = (const float*)d_in[pb + 9];

        // CSR
        hipLaunchKernelGGL(k_init, dim3(cdiv(NN, 256)), dim3(256), 0, stream, deg, gstart, gend);
        hipLaunchKernelGGL(k_count, dim3(cdiv(EE, 256)), dim3(256), 0, stream, ei, deg);
        hipLaunchKernelGGL(k_scan1, dim3(NSCB), dim3(256), 0, stream, deg, offs, bsum);
        hipLaunchKernelGGL(k_scan2, dim3(1), dim3(128), 0, stream, bsum);
        hipLaunchKernelGGL(k_scan3prep, dim3(NSCB), dim3(256), 0, stream,
                           offs, bsum, cursor, deg, dinv, batch, gstart, gend);
        hipLaunchKernelGGL(k_fill, dim3(cdiv(EPRIME, 256)), dim3(256), 0, stream, ei, cursor, csr);

        // x -> split (regionB), gatW -> transpose split
        hipLaunchKernelGGL(k_split_x, dim3(cdiv(NN * 128, 256)), dim3(256), 0, stream, x, xhi, xlo);
        hipLaunchKernelGGL(k_tsplitT, dim3(128 / 64, KP / 64), dim3(256), 0, stream,
                           gatW, FF, HFD, 128, Bthi, Btlo);

        // h0 = x @ gatW -> packed (regionA). ksteps=4 (Kpad=128)
        hipLaunchKernelGGL((mfma_gemm<1>), dim3(NRB * NCB), dim3(256), 0, stream,
                           xhi, xlo, Bthi, Btlo, 128, 128, NN, HFD, 4, NRB,
                           (float*)nullptr, 0, h0pk, KP);

        // attention logits
        hipLaunchKernelGGL(k_att, dim3(cdiv(NN * HH, 256)), dim3(256), 0, stream,
                           h0pk, att_src, att_dst, a_s, a_d);

        // GAT aggregate -> h1 split (regionB)
        hipLaunchKernelGGL(gat_agg, dim3(cdiv(NN, 4)), dim3(256), 0, stream,
                           h0pk, a_s, a_d, offs, csr, gatb, h1hi, h1lo);

        // gcnW -> transpose split
        hipLaunchKernelGGL(k_tsplitT, dim3(KP / 64, KP / 64), dim3(256), 0, stream,
                           gcnW, HFD, HFD, KP, Bthi, Btlo);

        // h2 = h1 @ gcnW -> fp32 (regionA). ksteps=36
        hipLaunchKernelGGL((mfma_gemm<0>), dim3(NRB * NCB), dim3(256), 0, stream,
                           h1hi, h1lo, Bthi, Btlo, KP, KP, NN, HFD, KP / 32, NRB,
                           h2f, HFD, (unsigned*)nullptr, 0);

        // GCN aggregate -> hgcn (regionB)
        hipLaunchKernelGGL(gcn_agg, dim3(cdiv(NN, 4)), dim3(256), 0, stream,
                           h2f, offs, csr, dinv, gcnb, hgcn);

        // pooling
        hipLaunchKernelGGL(k_pool, dim3(GG, 5), dim3(64), 0, stream, hgcn, gstart, gend, gpool);

        // fcg1 split-K
        hipLaunchKernelGGL(k_fcg1_part, dim3(16, 2, F1KS), dim3(256), 0, stream,
                           gpool, f1W, f1part);
        hipLaunchKernelGGL(k_fcg1_red, dim3(cdiv(GG * 1000, 256)), dim3(256), 0, stream,
                           f1part, f1b, fc1out);

        // fcg2
        hipLaunchKernelGGL(k_fcg2, dim3(GG), dim3(256), 0, stream,
                           fc1out, f2W, f2b, bout + (size_t)b * GG * 64);
    }

    hipLaunchKernelGGL(k_final, dim3(GG), dim3(256), 0, stream,
                       bout, bout + (size_t)GG * 64, target,
                       (const float*)d_in[27], (const float*)d_in[28],
                       (const float*)d_in[29], (const float*)d_in[30],
                       (const float*)d_in[31], (const float*)d_in[32],
                       (const float*)d_in[33], (const float*)d_in[34],
                       (float*)d_out);
}

// Round 10
// 1590.373 us; speedup vs baseline: 1.0268x; 1.0268x over previous
//
#include <hip/hip_runtime.h>
#include <cstddef>
#include <cstdint>

#define NN 20000
#define EE 160000
#define EPRIME 180000   // EE + NN (self loops)
#define GG 128
#define FF 114
#define HH 10
#define HFD 1140        // FF*HH
#define KP 1152         // padded feature dim (36*32, 9*128)
#define F1K 2280        // fcg1 K
#define F1KS 18         // split-K chunks
#define F1KC 128        // chunk size
#define NSCB 79         // scan blocks = cdiv(NN,256)

typedef unsigned short ushort_t;
typedef __attribute__((ext_vector_type(8))) short bf16x8;
typedef __attribute__((ext_vector_type(4))) float f32x4;

static inline int cdiv(int a, int b) { return (a + b - 1) / b; }

// ---------------- bf16 helpers ----------------

__device__ __forceinline__ ushort_t f2bf(float v) {
    union { float f; unsigned u; } c; c.f = v;
    unsigned u = c.u;
    unsigned r = (u + 0x7fffu + ((u >> 16) & 1u)) >> 16;   // RNE
    return (ushort_t)r;
}
__device__ __forceinline__ float bf2f(ushort_t h) {
    union { unsigned u; float f; } c; c.u = ((unsigned)h) << 16;
    return c.f;
}

__device__ __forceinline__ void gload16(const void* g, const ushort_t* l) {
    __builtin_amdgcn_global_load_lds(
        (const __attribute__((address_space(1))) unsigned int*)g,
        (__attribute__((address_space(3))) unsigned int*)l, 16, 0, 0);
}

// ---------------- CSR construction ----------------

__global__ void k_init(int* __restrict__ deg, int* __restrict__ gstart, int* __restrict__ gend) {
    int i = blockIdx.x * blockDim.x + threadIdx.x;
    if (i < NN) deg[i] = 1;               // self loop
    if (i < GG) { gstart[i] = NN; gend[i] = 0; }
}

__global__ void k_count(const int* __restrict__ ei, int* __restrict__ deg) {
    int i = blockIdx.x * blockDim.x + threadIdx.x;
    if (i < EE) atomicAdd(&deg[ei[EE + i]], 1);
}

// hierarchical scan: per-block inclusive + block totals
__global__ void k_scan1(const int* __restrict__ deg, int* __restrict__ offs, int* __restrict__ bsum) {
    __shared__ int tmp[256];
    int b = blockIdx.x, tid = threadIdx.x;
    int i = b * 256 + tid;
    int v = (i < NN) ? deg[i] : 0;
    tmp[tid] = v;
    __syncthreads();
#pragma unroll
    for (int off = 1; off < 256; off <<= 1) {
        int t = (tid >= off) ? tmp[tid - off] : 0;
        __syncthreads();
        tmp[tid] += t;
        __syncthreads();
    }
    if (i < NN) offs[i + 1] = tmp[tid];
    if (tid == 255) bsum[b] = tmp[255];
}

__global__ void k_scan2(int* __restrict__ bsum) {
    __shared__ int tmp[128];
    int tid = threadIdx.x;
    int v = (tid < NSCB) ? bsum[tid] : 0;
    tmp[tid] = v;
    __syncthreads();
#pragma unroll
    for (int off = 1; off < 128; off <<= 1) {
        int t = (tid >= off) ? tmp[tid - off] : 0;
        __syncthreads();
        tmp[tid] += t;
        __syncthreads();
    }
    if (tid < NSCB) bsum[tid] = tmp[tid] - v;   // exclusive prefix
}

// fused: finalize offs + cursor + dinv + graph ranges
__global__ void k_scan3prep(int* __restrict__ offs, const int* __restrict__ bsum,
                            int* __restrict__ cursor, const int* __restrict__ deg,
                            float* __restrict__ dinv, const int* __restrict__ batch,
                            int* __restrict__ gstart, int* __restrict__ gend) {
    int i = blockIdx.x * 256 + threadIdx.x;
    if (i < NN) {
        int o = offs[i + 1] + bsum[i >> 8];   // inclusive prefix up to i
        offs[i + 1] = o;
        cursor[i] = o - deg[i];               // exclusive prefix = offs[i]
        dinv[i] = rsqrtf((float)deg[i]);
        int b = batch[i];
        atomicMin(&gstart[b], i);
        atomicMax(&gend[b], i + 1);
    }
    if (i == 0) offs[0] = 0;
}

__global__ void k_fill(const int* __restrict__ ei, int* __restrict__ cursor, int* __restrict__ csr) {
    int i = blockIdx.x * blockDim.x + threadIdx.x;
    if (i < EPRIME) {
        int s, d;
        if (i < EE) { s = ei[i]; d = ei[EE + i]; }
        else        { s = i - EE; d = s; }
        int pos = atomicAdd(&cursor[d], 1);
        csr[pos] = s;
    }
}

// ---------------- split / transpose-split conversions ----------------

__global__ void k_split_x(const float* __restrict__ x, ushort_t* __restrict__ xhi, ushort_t* __restrict__ xlo) {
    int idx = blockIdx.x * 256 + threadIdx.x;
    if (idx >= NN * 128) return;
    int n = idx >> 7, k = idx & 127;
    float v = (k < FF) ? x[(size_t)n * FF + k] : 0.f;
    ushort_t hi = f2bf(v);
    ushort_t lo = f2bf(v - bf2f(hi));
    xhi[idx] = hi; xlo[idx] = lo;
}

// W [K,Nc] -> T[n][k]=W[k][n], split bf16, zero pad. Coalesced via LDS 64x64 tiles.
__global__ __launch_bounds__(256) void k_tsplitT(const float* __restrict__ W, int K, int Nc,
                                                 int Kpad, ushort_t* __restrict__ Thi,
                                                 ushort_t* __restrict__ Tlo) {
    __shared__ float tile[64][65];
    int kb = blockIdx.x * 64;
    int nb = blockIdx.y * 64;
    int c = threadIdx.x & 63, r4 = threadIdx.x >> 6;
#pragma unroll
    for (int rr = 0; rr < 16; ++rr) {
        int r = r4 * 16 + rr;
        int gk = kb + r, gn = nb + c;
        tile[r][c] = (gk < K && gn < Nc) ? W[(size_t)gk * Nc + gn] : 0.f;
    }
    __syncthreads();
#pragma unroll
    for (int rr = 0; rr < 16; ++rr) {
        int r = r4 * 16 + rr;
        int gn = nb + r, gk = kb + c;
        float v = tile[c][r];
        ushort_t hi = f2bf(v);
        ushort_t lo = f2bf(v - bf2f(hi));
        size_t o = (size_t)gn * Kpad + gk;
        Thi[o] = hi; Tlo[o] = lo;
    }
}

// ---------------- split-bf16 MFMA GEMM, 2-phase dbuf + ROW-MAJOR XCD swizzle ----------------
// (r5/r8 structure: best measured 252us. r6 3-stage, r7 B-direct, r9 col-major all regressed —
//  kernel is L2/L3-BW-bound; keep minimal-HBM row-major layout.)
// Output: bf16 single plane [M][ldcs], zero-padded cols >= Nreal (gather consumers read bf16).

__global__ __launch_bounds__(256) void mfma_gemm(
    const ushort_t* __restrict__ Ahi, const ushort_t* __restrict__ Alo,
    const ushort_t* __restrict__ Bthi, const ushort_t* __restrict__ Btlo,
    int lda, int ldb, int M, int Nreal, int ksteps, int ncb,
    ushort_t* __restrict__ Cb, int ldcs) {
    __shared__ __align__(16) ushort_t lds[2 * 4 * 4096];   // [buf][plane][4 kg][128 row][8]
    const int tid = threadIdx.x;
    const int lane = tid & 63;
    const int w = tid >> 6;
    const int wr = w >> 1, wc = w & 1;

    // bijective XCD-chunked swizzle (m204), row-major block decode
    int nwg = gridDim.x;
    int q = nwg >> 3, r8 = nwg & 7;
    int xcd = blockIdx.x & 7, sidx = blockIdx.x >> 3;
    int wg = (xcd < r8 ? xcd * (q + 1) : r8 * (q + 1) + (xcd - r8) * q) + sidx;
    int brow = wg / ncb, bcol = wg - brow * ncb;

    int row0 = brow * 128; if (row0 > M - 128) row0 = M - 128;   // overlap trick, idempotent writes
    const int col0 = bcol * 128;

    f32x4 acc[4][4];
#pragma unroll
    for (int i = 0; i < 4; ++i)
#pragma unroll
        for (int j = 0; j < 4; ++j) acc[i][j] = (f32x4){0.f, 0.f, 0.f, 0.f};

    const size_t ldaB = (size_t)lda * 2, ldbB = (size_t)ldb * 2;
    const char* pAhi[2]; const char* pAlo[2]; const char* pBhi[2]; const char* pBlo[2];
    unsigned ldsoff[2];
#pragma unroll
    for (int i = 0; i < 2; ++i) {
        int c = (w * 2 + i) * 64 + lane;
        int kg = c >> 7, r = c & 127;
        pAhi[i] = (const char*)Ahi + (size_t)(row0 + r) * ldaB + kg * 16;
        pAlo[i] = (const char*)Alo + (size_t)(row0 + r) * ldaB + kg * 16;
        pBhi[i] = (const char*)Bthi + (size_t)(col0 + r) * ldbB + kg * 16;
        pBlo[i] = (const char*)Btlo + (size_t)(col0 + r) * ldbB + kg * 16;
        ldsoff[i] = (w * 2 + i) * 512;
    }
    const int kgf = lane >> 4, r15 = lane & 15;

    auto STAGE = [&](int buf, int ks) {
        size_t kb = (size_t)ks * 64;
        unsigned bo = buf ? 16384u : 0u;
#pragma unroll
        for (int i = 0; i < 2; ++i) {
            gload16(pAhi[i] + kb, lds + bo + 0 * 4096 + ldsoff[i]);
            gload16(pAlo[i] + kb, lds + bo + 1 * 4096 + ldsoff[i]);
            gload16(pBhi[i] + kb, lds + bo + 2 * 4096 + ldsoff[i]);
            gload16(pBlo[i] + kb, lds + bo + 3 * 4096 + ldsoff[i]);
        }
    };

    STAGE(0, 0);
    asm volatile("s_waitcnt vmcnt(0)" ::: "memory");
    __syncthreads();
    int cur = 0;

    for (int ks = 0; ks < ksteps; ++ks) {
        if (ks + 1 < ksteps) STAGE(cur ^ 1, ks + 1);   // prefetch flies during MFMA
        const ushort_t* lb = lds + (cur ? 16384u : 0u);
        bf16x8 ah[4], al[4], bh[4], bl[4];
#pragma unroll
        for (int i = 0; i < 4; ++i) {
            int ra = wr * 64 + i * 16 + r15;
            int rb = wc * 64 + i * 16 + r15;
            ah[i] = *(const bf16x8*)(lb + 0 * 4096 + kgf * 1024 + ra * 8);
            al[i] = *(const bf16x8*)(lb + 1 * 4096 + kgf * 1024 + ra * 8);
            bh[i] = *(const bf16x8*)(lb + 2 * 4096 + kgf * 1024 + rb * 8);
            bl[i] = *(const bf16x8*)(lb + 3 * 4096 + kgf * 1024 + rb * 8);
        }
#pragma unroll
        for (int i = 0; i < 4; ++i)
#pragma unroll
            for (int j = 0; j < 4; ++j) {
                acc[i][j] = __builtin_amdgcn_mfma_f32_16x16x32_bf16(ah[i], bh[j], acc[i][j], 0, 0, 0);
                acc[i][j] = __builtin_amdgcn_mfma_f32_16x16x32_bf16(ah[i], bl[j], acc[i][j], 0, 0, 0);
                acc[i][j] = __builtin_amdgcn_mfma_f32_16x16x32_bf16(al[i], bh[j], acc[i][j], 0, 0, 0);
            }
        asm volatile("s_waitcnt vmcnt(0)" ::: "memory");
        __syncthreads();
        cur ^= 1;
    }

    const int g4 = lane >> 4;
#pragma unroll
    for (int i = 0; i < 4; ++i)
#pragma unroll
        for (int j = 0; j < 4; ++j) {
            int c = col0 + wc * 64 + j * 16 + r15;
#pragma unroll
            for (int reg = 0; reg < 4; ++reg) {
                int r = row0 + wr * 64 + i * 16 + g4 * 4 + reg;
                if (r < M) {
                    float v = (c < Nreal) ? acc[i][j][reg] : 0.f;
                    Cb[(size_t)r * ldcs + c] = f2bf(v);
                }
            }
        }
}

// ---------------- attention logits from bf16 h0 ----------------

__global__ void k_att(const ushort_t* __restrict__ h0b,
                      const float* __restrict__ att_src, const float* __restrict__ att_dst,
                      float* __restrict__ as_, float* __restrict__ ad_) {
    int id = blockIdx.x * blockDim.x + threadIdx.x;
    if (id >= NN * HH) return;
    int n = id / HH, h = id % HH;
    const ushort_t* row = h0b + (size_t)n * KP + h * FF;
    const float* ws = att_src + h * FF;
    const float* wd = att_dst + h * FF;
    float as = 0.f, ad = 0.f;
    for (int f = 0; f < FF; f += 2) {
        unsigned qq = *(const unsigned*)(row + f);
        float v0 = bf2f((ushort_t)(qq & 0xffffu));
        float v1 = bf2f((ushort_t)(qq >> 16));
        as += v0 * ws[f] + v1 * ws[f + 1];
        ad += v0 * wd[f] + v1 * wd[f + 1];
    }
    as_[id] = as;
    ad_[id] = ad;
}

// ---------------- GAT aggregation: bf16 gathers, 8-edge groups + clamped-4 tail ----------------
// softmax WITHOUT max-subtraction (shift-invariant; logits are O(1)).
// 8-elem column groups per lane: j0 k=8*lane, j1 k=512+8*lane, j2 (lane<16) k=1024+8*lane.
// Head index within an 8-elem run crosses a 114-boundary at most once: base head hA, next hB,
// crossing position cr (elems e>=cr use hB). Pads (k>=1140) hold zeros -> weight irrelevant.

template <int NU>
__device__ __forceinline__ void gat_group(
    int eg, int end, int lane, float my_ad,
    const int* __restrict__ csr, const float* __restrict__ as_,
    const ushort_t* __restrict__ h0b,
    int hA0, int hB0, int cr0, int hA1, int hB1, int cr1,
    int hA2, int hB2, int cr2,
    float& den, float* acc0, float* acc1, float* acc2) {
    int s[NU]; float ex[NU];
#pragma unroll
    for (int u = 0; u < NU; ++u) {
        int idx = eg + u; if (idx > end - 1) idx = end - 1;   // clamp (weight zeroed below)
        s[u] = csr[idx];
    }
#pragma unroll
    for (int u = 0; u < NU; ++u) {
        float e = 0.f;
        if (lane < HH) {
            float t = as_[s[u] * HH + lane] + my_ad;
            t = (t >= 0.f) ? t : 0.2f * t;
            e = __expf(t);
            if (eg + u >= end) e = 0.f;
        }
        ex[u] = e;
        den += e;
    }
    const int kb0 = 8 * lane, kb1 = 512 + 8 * lane, kb2 = 1024 + 8 * lane;
    bf16x8 qv[NU];
    // j0
#pragma unroll
    for (int u = 0; u < NU; ++u) qv[u] = *(const bf16x8*)(h0b + (size_t)s[u] * KP + kb0);
#pragma unroll
    for (int u = 0; u < NU; ++u) {
        float wA = __shfl(ex[u], hA0, 64), wB = __shfl(ex[u], hB0, 64);
#pragma unroll
        for (int e = 0; e < 8; ++e)
            acc0[e] += ((e >= cr0) ? wB : wA) * bf2f((ushort_t)qv[u][e]);
    }
    // j1
#pragma unroll
    for (int u = 0; u < NU; ++u) qv[u] = *(const bf16x8*)(h0b + (size_t)s[u] * KP + kb1);
#pragma unroll
    for (int u = 0; u < NU; ++u) {
        float wA = __shfl(ex[u], hA1, 64), wB = __shfl(ex[u], hB1, 64);
#pragma unroll
        for (int e = 0; e < 8; ++e)
            acc1[e] += ((e >= cr1) ? wB : wA) * bf2f((ushort_t)qv[u][e]);
    }
    // j2 (lane<16; shfl sources 8/9 are active in this branch)
    if (lane < 16) {
#pragma unroll
        for (int u = 0; u < NU; ++u) qv[u] = *(const bf16x8*)(h0b + (size_t)s[u] * KP + kb2);
#pragma unroll
        for (int u = 0; u < NU; ++u) {
            float wA = __shfl(ex[u], hA2, 64), wB = __shfl(ex[u], hB2, 64);
#pragma unroll
            for (int e = 0; e < 8; ++e)
                acc2[e] += ((e >= cr2) ? wB : wA) * bf2f((ushort_t)qv[u][e]);
        }
    }
}

__global__ __launch_bounds__(256) void gat_agg(
    const ushort_t* __restrict__ h0b,
    const float* __restrict__ as_, const float* __restrict__ ad_,
    const int* __restrict__ offs, const int* __restrict__ csr,
    const float* __restrict__ bias,
    ushort_t* __restrict__ outhi, ushort_t* __restrict__ outlo) {
    int lane = threadIdx.x & 63;
    int n = blockIdx.x * 4 + (threadIdx.x >> 6);
    if (n >= NN) return;
    int beg = offs[n], end = offs[n + 1];
    float my_ad = (lane < HH) ? ad_[n * HH + lane] : 0.f;

    const int kb0 = 8 * lane, kb1 = 512 + 8 * lane, kb2 = 1024 + 8 * lane;
    int hA0 = min(kb0 / FF, HH - 1), hB0 = min(hA0 + 1, HH - 1);
    int cr0 = (kb0 / FF + 1) * FF - kb0;
    int hA1 = min(kb1 / FF, HH - 1), hB1 = min(hA1 + 1, HH - 1);
    int cr1 = (kb1 / FF + 1) * FF - kb1;
    int hA2 = min(kb2 / FF, HH - 1), hB2 = min(hA2 + 1, HH - 1);
    int cr2 = (kb2 / FF + 1) * FF - kb2;

    float den = 0.f;
    float acc0[8] = {}, acc1[8] = {}, acc2[8] = {};

    int eg = beg;
    for (; eg + 8 <= end; eg += 8)
        gat_group<8>(eg, end, lane, my_ad, csr, as_, h0b,
                     hA0, hB0, cr0, hA1, hB1, cr1, hA2, hB2, cr2, den, acc0, acc1, acc2);
    for (; eg < end; eg += 4)
        gat_group<4>(eg, end, lane, my_ad, csr, as_, h0b,
                     hA0, hB0, cr0, hA1, hB1, cr1, hA2, hB2, cr2, den, acc0, acc1, acc2);

    // write-out: alpha = acc/den, + bias, lrelu, split hi/lo (full precision h1)
    {
        bf16x8 vh, vl;
#pragma unroll
        for (int e = 0; e < 8; ++e) {
            int k = kb0 + e;
            float d = __shfl(den, (e >= cr0) ? hB0 : hA0, 64);
            float v = acc0[e] / d + bias[k];
            v = (v >= 0.f) ? v : 0.01f * v;
            ushort_t h = f2bf(v);
            vh[e] = (short)h; vl[e] = (short)f2bf(v - bf2f(h));
        }
        *(bf16x8*)(outhi + (size_t)n * KP + kb0) = vh;
        *(bf16x8*)(outlo + (size_t)n * KP + kb0) = vl;
#pragma unroll
        for (int e = 0; e < 8; ++e) {
            int k = kb1 + e;
            float d = __shfl(den, (e >= cr1) ? hB1 : hA1, 64);
            float v = acc1[e] / d + bias[k];
            v = (v >= 0.f) ? v : 0.01f * v;
            ushort_t h = f2bf(v);
            vh[e] = (short)h; vl[e] = (short)f2bf(v - bf2f(h));
        }
        *(bf16x8*)(outhi + (size_t)n * KP + kb1) = vh;
        *(bf16x8*)(outlo + (size_t)n * KP + kb1) = vl;
    }
    if (lane < 16) {
        bf16x8 vh, vl;
#pragma unroll
        for (int e = 0; e < 8; ++e) {
            int k = kb2 + e;
            float v = 0.f;
            if (k < HFD) {
                float d = __shfl(den, (e >= cr2) ? hB2 : hA2, 64);
                v = acc2[e] / d + bias[k];
                v = (v >= 0.f) ? v : 0.01f * v;
            } else {
                (void)__shfl(den, hA2, 64);   // keep shfl uniform within branch
            }
            ushort_t h = f2bf(v);
            vh[e] = (short)h; vl[e] = (short)f2bf(v - bf2f(h));
        }
        *(bf16x8*)(outhi + (size_t)n * KP + kb2) = vh;
        *(bf16x8*)(outlo + (size_t)n * KP + kb2) = vl;
    }
}

// ---------------- GCN aggregation: bf16 gathers, 8-edge groups + clamped-4 tail ----------------

template <int NU>
__device__ __forceinline__ void gcn_group(
    int eg, int end, int lane, float di,
    const int* __restrict__ csr, const float* __restrict__ dinv,
    const ushort_t* __restrict__ h2b,
    float* acc0, float* acc1, float* acc2) {
    int s[NU]; float w[NU];
#pragma unroll
    for (int u = 0; u < NU; ++u) {
        int idx = eg + u; if (idx > end - 1) idx = end - 1;
        s[u] = csr[idx];
    }
#pragma unroll
    for (int u = 0; u < NU; ++u) {
        float ww = dinv[s[u]] * di;
        w[u] = (eg + u < end) ? ww : 0.f;
    }
    const int kb0 = 8 * lane, kb1 = 512 + 8 * lane, kb2 = 1024 + 8 * lane;
    bf16x8 qv[NU];
#pragma unroll
    for (int u = 0; u < NU; ++u) qv[u] = *(const bf16x8*)(h2b + (size_t)s[u] * KP + kb0);
#pragma unroll
    for (int u = 0; u < NU; ++u)
#pragma unroll
        for (int e = 0; e < 8; ++e) acc0[e] += w[u] * bf2f((ushort_t)qv[u][e]);
#pragma unroll
    for (int u = 0; u < NU; ++u) qv[u] = *(const bf16x8*)(h2b + (size_t)s[u] * KP + kb1);
#pragma unroll
    for (int u = 0; u < NU; ++u)
#pragma unroll
        for (int e = 0; e < 8; ++e) acc1[e] += w[u] * bf2f((ushort_t)qv[u][e]);
    if (lane < 16) {
#pragma unroll
        for (int u = 0; u < NU; ++u) qv[u] = *(const bf16x8*)(h2b + (size_t)s[u] * KP + kb2);
#pragma unroll
        for (int u = 0; u < NU; ++u)
#pragma unroll
            for (int e = 0; e < 8; ++e) acc2[e] += w[u] * bf2f((ushort_t)qv[u][e]);
    }
}

__global__ __launch_bounds__(256) void gcn_agg(
    const ushort_t* __restrict__ h2b, const int* __restrict__ offs, const int* __restrict__ csr,
    const float* __restrict__ dinv, const float* __restrict__ bias, float* __restrict__ out) {
    int lane = threadIdx.x & 63;
    int n = blockIdx.x * 4 + (threadIdx.x >> 6);
    if (n >= NN) return;
    int beg = offs[n], end = offs[n + 1];
    float di = dinv[n];
    float acc0[8] = {}, acc1[8] = {}, acc2[8] = {};

    int eg = beg;
    for (; eg + 8 <= end; eg += 8)
        gcn_group<8>(eg, end, lane, di, csr, dinv, h2b, acc0, acc1, acc2);
    for (; eg < end; eg += 4)
        gcn_group<4>(eg, end, lane, di, csr, dinv, h2b, acc0, acc1, acc2);

    const int kb0 = 8 * lane, kb1 = 512 + 8 * lane, kb2 = 1024 + 8 * lane;
    {
        float4 o1, o2;
        float v;
        v = acc0[0] + bias[kb0 + 0]; o1.x = (v >= 0.f) ? v : 0.01f * v;
        v = acc0[1] + bias[kb0 + 1]; o1.y = (v >= 0.f) ? v : 0.01f * v;
        v = acc0[2] + bias[kb0 + 2]; o1.z = (v >= 0.f) ? v : 0.01f * v;
        v = acc0[3] + bias[kb0 + 3]; o1.w = (v >= 0.f) ? v : 0.01f * v;
        v = acc0[4] + bias[kb0 + 4]; o2.x = (v >= 0.f) ? v : 0.01f * v;
        v = acc0[5] + bias[kb0 + 5]; o2.y = (v >= 0.f) ? v : 0.01f * v;
        v = acc0[6] + bias[kb0 + 6]; o2.z = (v >= 0.f) ? v : 0.01f * v;
        v = acc0[7] + bias[kb0 + 7]; o2.w = (v >= 0.f) ? v : 0.01f * v;
        *(float4*)(out + (size_t)n * HFD + kb0) = o1;
        *(float4*)(out + (size_t)n * HFD + kb0 + 4) = o2;
        v = acc1[0] + bias[kb1 + 0]; o1.x = (v >= 0.f) ? v : 0.01f * v;
        v = acc1[1] + bias[kb1 + 1]; o1.y = (v >= 0.f) ? v : 0.01f * v;
        v = acc1[2] + bias[kb1 + 2]; o1.z = (v >= 0.f) ? v : 0.01f * v;
        v = acc1[3] + bias[kb1 + 3]; o1.w = (v >= 0.f) ? v : 0.01f * v;
        v = acc1[4] + bias[kb1 + 4]; o2.x = (v >= 0.f) ? v : 0.01f * v;
        v = acc1[5] + bias[kb1 + 5]; o2.y = (v >= 0.f) ? v : 0.01f * v;
        v = acc1[6] + bias[kb1 + 6]; o2.z = (v >= 0.f) ? v : 0.01f * v;
        v = acc1[7] + bias[kb1 + 7]; o2.w = (v >= 0.f) ? v : 0.01f * v;
        *(float4*)(out + (size_t)n * HFD + kb1) = o1;
        *(float4*)(out + (size_t)n * HFD + kb1 + 4) = o2;
    }
    if (lane < 16) {
#pragma unroll
        for (int e = 0; e < 8; ++e) {
            int k = kb2 + e;
            if (k < HFD) {
                float v = acc2[e] + bias[k];
                out[(size_t)n * HFD + k] = (v >= 0.f) ? v : 0.01f * v;
            }
        }
    }
}

// ---------------- graph pooling (max + mean), float4 ----------------

__global__ void k_pool(const float* __restrict__ hfeat, const int* __restrict__ gs,
                       const int* __restrict__ ge, float* __restrict__ gout) {
    int g = blockIdx.x;
    if (threadIdx.x >= 57) return;
    int m = blockIdx.y * 57 + threadIdx.x;
    int s = gs[g], e = ge[g];
    int cnt = e - s;
    float4 mx = make_float4(-1e30f, -1e30f, -1e30f, -1e30f);
    float4 sm = make_float4(0.f, 0.f, 0.f, 0.f);
    for (int r = s; r < e; ++r) {
        float4 v = *(const float4*)(hfeat + (size_t)r * HFD + 4 * m);
        mx.x = fmaxf(mx.x, v.x); mx.y = fmaxf(mx.y, v.y);
        mx.z = fmaxf(mx.z, v.z); mx.w = fmaxf(mx.w, v.w);
        sm.x += v.x; sm.y += v.y; sm.z += v.z; sm.w += v.w;
    }
    float4 mean;
    if (cnt <= 0) {
        mx = make_float4(0.f, 0.f, 0.f, 0.f);
        mean = make_float4(0.f, 0.f, 0.f, 0.f);
    } else {
        float inv = 1.f / (float)cnt;
        mean = make_float4(sm.x * inv, sm.y * inv, sm.z * inv, sm.w * inv);
    }
    *(float4*)(gout + (size_t)g * (2 * HFD) + 4 * m) = mx;
    *(float4*)(gout + (size_t)g * (2 * HFD) + HFD + 4 * m) = mean;
}

// ---------------- fcg1 split-K (kt loop MUST stay rolled — round-3 spill regression) ----------------

__global__ __launch_bounds__(256) void k_fcg1_part(
    const float* __restrict__ A, const float* __restrict__ B, float* __restrict__ part) {
    __shared__ float As[16][64 + 4];
    __shared__ float Bs[16][64 + 4];
    int tid = threadIdx.x;
    int tx = tid & 15, ty = tid >> 4;
    int row0 = blockIdx.y * 64, col0 = blockIdx.x * 64;
    int kbeg = blockIdx.z * F1KC;
    float acc[4][4] = {};
#pragma unroll 1
    for (int kt = 0; kt < F1KC / 16; ++kt) {
        int kk = kbeg + kt * 16;
#pragma unroll
        for (int l = 0; l < 4; ++l) {
            int idx = tid + 256 * l;
            int m = idx >> 4, k = idx & 15;
            int gr = row0 + m, gk = kk + k;
            As[k][m] = (gk < F1K) ? A[(size_t)gr * F1K + gk] : 0.f;
        }
#pragma unroll
        for (int l = 0; l < 4; ++l) {
            int idx = tid + 256 * l;
            int nn = idx & 63, k = idx >> 6;
            int gc = col0 + nn, gk = kk + k;
            Bs[k][nn] = (gc < 1000 && gk < F1K) ? B[(size_t)gk * 1000 + gc] : 0.f;
        }
        __syncthreads();
#pragma unroll
        for (int k = 0; k < 16; ++k) {
            float4 av = *(const float4*)&As[k][ty * 4];
            float4 bv = *(const float4*)&Bs[k][tx * 4];
            float a[4] = {av.x, av.y, av.z, av.w};
            float b[4] = {bv.x, bv.y, bv.z, bv.w};
#pragma unroll
            for (int i = 0; i < 4; ++i)
#pragma unroll
                for (int j = 0; j < 4; ++j) acc[i][j] += a[i] * b[j];
        }
        __syncthreads();
    }
    float* pc = part + (size_t)blockIdx.z * GG * 1000;
#pragma unroll
    for (int i = 0; i < 4; ++i) {
        int r = row0 + ty * 4 + i;
#pragma unroll
        for (int j = 0; j < 4; ++j) {
            int c = col0 + tx * 4 + j;
            if (c < 1000) pc[(size_t)r * 1000 + c] = acc[i][j];
        }
    }
}

__global__ void k_fcg1_red(const float* __restrict__ part, const float* __restrict__ bias,
                           float* __restrict__ out) {
    int idx = blockIdx.x * 256 + threadIdx.x;
    if (idx >= GG * 1000) return;
    float s = 0.f;
#pragma unroll
    for (int k = 0; k < F1KS; ++k) s += part[(size_t)k * GG * 1000 + idx];
    int n = idx % 1000;
    float v = s + bias[n];
    out[idx] = (v >= 0.f) ? v : 0.01f * v;
}

// ---------------- fcg2 ----------------

__global__ __launch_bounds__(256) void k_fcg2(const float* __restrict__ in, const float* __restrict__ W,
                                              const float* __restrict__ b, float* __restrict__ out) {
    __shared__ float part[4][64];
    int g = blockIdx.x;
    int o = threadIdx.x & 63, p = threadIdx.x >> 6;
    const float* row = in + (size_t)g * 1000;
    float acc = 0.f;
    for (int k = p * 250; k < (p + 1) * 250; ++k) acc += row[k] * W[k * 64 + o];
    part[p][o] = acc;
    __syncthreads();
    if (p == 0) out[(size_t)g * 64 + o] = part[0][o] + part[1][o] + part[2][o] + part[3][o] + b[o];
}

// ---------------- final head ----------------

__global__ __launch_bounds__(256) void k_final(
    const float* __restrict__ b1, const float* __restrict__ b2, const float* __restrict__ target,
    const float* __restrict__ fcxtW, const float* __restrict__ fcxtb,
    const float* __restrict__ fc1W, const float* __restrict__ fc1b,
    const float* __restrict__ fc2W, const float* __restrict__ fc2b,
    const float* __restrict__ outW, const float* __restrict__ outb,
    float* __restrict__ out) {
    __shared__ float xc[256];
    __shared__ float xt2[128];
    __shared__ float y1[128];
    __shared__ float y2[32];
    int g = blockIdx.x, t = threadIdx.x;
    if (t < 64) xc[t] = b1[(size_t)g * 64 + t];
    else if (t < 128) xc[t] = b2[(size_t)g * 64 + (t - 64)];
    {
        int c = t & 127, p = t >> 7;
        float acc = 0.f;
        const float* trow = target + (size_t)g * 1000;
        for (int k = p * 500; k < (p + 1) * 500; ++k) acc += trow[k] * fcxtW[k * 128 + c];
        if (p == 1) xt2[c] = acc;
        __syncthreads();
        if (p == 0) xc[128 + c] = acc + xt2[c] + fcxtb[c];
    }
    __syncthreads();
    if (t < 128) {
        float acc = 0.f;
        for (int k = 0; k < 256; ++k) acc += xc[k] * fc1W[k * 128 + t];
        acc += fc1b[t];
        y1[t] = (acc >= 0.f) ? acc : 0.01f * acc;
    }
    __syncthreads();
    if (t < 32) {
        float acc = 0.f;
        for (int k = 0; k < 128; ++k) acc += y1[k] * fc2W[k * 32 + t];
        acc += fc2b[t];
        y2[t] = (acc >= 0.f) ? acc : 0.01f * acc;
    }
    __syncthreads();
    if (t == 0) {
        float acc = 0.f;
        for (int k = 0; k < 32; ++k) acc += y2[k] * outW[k];
        out[g] = acc + outb[0];
    }
}

// ---------------- host launch ----------------

extern "C" void kernel_launch(void* const* d_in, const int* in_sizes, int n_in,
                              void* d_out, int out_size, void* d_ws, size_t ws_size,
                              hipStream_t stream) {
    (void)in_sizes; (void)n_in; (void)out_size; (void)ws_size;

    size_t off = 0;
    auto alloc = [&](size_t bytes) -> void* {
        void* p = (char*)d_ws + off;
        off += (bytes + 255) & ~(size_t)255;
        return p;
    };
    char* regionA = (char*)alloc((size_t)2 * NN * KP * 2);
    char* regionB = (char*)alloc((size_t)2 * NN * KP * 2);
    ushort_t* Bthi = (ushort_t*)alloc((size_t)KP * KP * 2);
    ushort_t* Btlo = (ushort_t*)alloc((size_t)KP * KP * 2);
    float* a_s    = (float*)alloc((size_t)NN * HH * 4);
    float* a_d    = (float*)alloc((size_t)NN * HH * 4);
    int*   deg    = (int*)alloc((size_t)NN * 4);
    int*   offs   = (int*)alloc((size_t)(NN + 1) * 4);
    int*   cursor = (int*)alloc((size_t)NN * 4);
    int*   csr    = (int*)alloc((size_t)EPRIME * 4);
    float* dinv   = (float*)alloc((size_t)NN * 4);
    int*   gstart = (int*)alloc((size_t)GG * 4);
    int*   gend   = (int*)alloc((size_t)GG * 4);
    int*   bsum   = (int*)alloc((size_t)128 * 4);
    float* gpool  = (float*)alloc((size_t)GG * 2 * HFD * 4);
    float* fc1out = (float*)alloc((size_t)GG * 1000 * 4);
    float* bout   = (float*)alloc((size_t)2 * GG * 64 * 4);

    // overlays
    ushort_t* h0b  = (ushort_t*)regionA;                     // bf16 [NN][KP], zero-padded
    ushort_t* h2b  = (ushort_t*)regionA;                     // after h0b dead (post gat_agg)
    float*    f1part = (float*)regionA;                      // after h2b dead (post gcn_agg)
    ushort_t* xhi  = (ushort_t*)regionB;
    ushort_t* xlo  = (ushort_t*)regionB + (size_t)NN * 128;
    ushort_t* h1hi = (ushort_t*)regionB;                     // after x is dead
    ushort_t* h1lo = (ushort_t*)regionB + (size_t)NN * KP;
    float*    hgcn = (float*)regionB;                        // after h1 is dead

    const float* target = (const float*)d_in[6];
    const int NRB = cdiv(NN, 128);        // 157 row blocks
    const int NCB = KP / 128;             // 9 col blocks

    for (int b = 0; b < 2; ++b) {
        const float* x     = (const float*)d_in[b ? 3 : 0];
        const int*   ei    = (const int*)d_in[b ? 4 : 1];
        const int*   batch = (const int*)d_in[b ? 5 : 2];
        int pb = 7 + b * 10;
        const float* gatW    = (const float*)d_in[pb + 0];
        const float* att_src = (const float*)d_in[pb + 1];
        const float* att_dst = (const float*)d_in[pb + 2];
        const float* gatb    = (const float*)d_in[pb + 3];
        const float* gcnW    = (const float*)d_in[pb + 4];
        const float* gcnb    = (const float*)d_in[pb + 5];
        const float* f1W     = (const float*)d_in[pb + 6];
        const float* f1b     = (const float*)d_in[pb + 7];
        const float* f2W     = (const float*)d_in[pb + 8];
        const float* f2b     = (const float*)d_in[pb + 9];

        // CSR
        hipLaunchKernelGGL(k_init, dim3(cdiv(NN, 256)), dim3(256), 0, stream, deg, gstart, gend);
        hipLaunchKernelGGL(k_count, dim3(cdiv(EE, 256)), dim3(256), 0, stream, ei, deg);
        hipLaunchKernelGGL(k_scan1, dim3(NSCB), dim3(256), 0, stream, deg, offs, bsum);
        hipLaunchKernelGGL(k_scan2, dim3(1), dim3(128), 0, stream, bsum);
        hipLaunchKernelGGL(k_scan3prep, dim3(NSCB), dim3(256), 0, stream,
                           offs, bsum, cursor, deg, dinv, batch, gstart, gend);
        hipLaunchKernelGGL(k_fill, dim3(cdiv(EPRIME, 256)), dim3(256), 0, stream, ei, cursor, csr);

        // x -> split (regionB), gatW -> transpose split
        hipLaunchKernelGGL(k_split_x, dim3(cdiv(NN * 128, 256)), dim3(256), 0, stream, x, xhi, xlo);
        hipLaunchKernelGGL(k_tsplitT, dim3(128 / 64, KP / 64), dim3(256), 0, stream,
                           gatW, FF, HFD, 128, Bthi, Btlo);

        // h0 = x @ gatW -> bf16 (regionA). ksteps=4 (Kpad=128)
        hipLaunchKernelGGL(mfma_gemm, dim3(NRB * NCB), dim3(256), 0, stream,
                           xhi, xlo, Bthi, Btlo, 128, 128, NN, HFD, 4, NCB, h0b, KP);

        // attention logits
        hipLaunchKernelGGL(k_att, dim3(cdiv(NN * HH, 256)), dim3(256), 0, stream,
                           h0b, att_src, att_dst, a_s, a_d);

        // GAT aggregate -> h1 split (regionB)
        hipLaunchKernelGGL(gat_agg, dim3(cdiv(NN, 4)), dim3(256), 0, stream,
                           h0b, a_s, a_d, offs, csr, gatb, h1hi, h1lo);

        // gcnW -> transpose split
        hipLaunchKernelGGL(k_tsplitT, dim3(KP / 64, KP / 64), dim3(256), 0, stream,
                           gcnW, HFD, HFD, KP, Bthi, Btlo);

        // h2 = h1 @ gcnW -> bf16 (regionA). ksteps=36
        hipLaunchKernelGGL(mfma_gemm, dim3(NRB * NCB), dim3(256), 0, stream,
                           h1hi, h1lo, Bthi, Btlo, KP, KP, NN, HFD, KP / 32, NCB, h2b, KP);

        // GCN aggregate -> hgcn fp32 (regionB)
        hipLaunchKernelGGL(gcn_agg, dim3(cdiv(NN, 4)), dim3(256), 0, stream,
                           h2b, offs, csr, dinv, gcnb, hgcn);

        // pooling
        hipLaunchKernelGGL(k_pool, dim3(GG, 5), dim3(64), 0, stream, hgcn, gstart, gend, gpool);

        // fcg1 split-K
        hipLaunchKernelGGL(k_fcg1_part, dim3(16, 2, F1KS), dim3(256), 0, stream,
                           gpool, f1W, f1part);
        hipLaunchKernelGGL(k_fcg1_red, dim3(cdiv(GG * 1000, 256)), dim3(256), 0, stream,
                           f1part, f1b, fc1out);

        // fcg2
        hipLaunchKernelGGL(k_fcg2, dim3(GG), dim3(256), 0, stream,
                           fc1out, f2W, f2b, bout + (size_t)b * GG * 64);
    }

    hipLaunchKernelGGL(k_final, dim3(GG), dim3(256), 0, stream,
                       bout, bout + (size_t)GG * 64, target,
                       (const float*)d_in[27], (const float*)d_in[28],
                       (const float*)d_in[29], (const float*)d_in[30],
                       (const float*)d_in[31], (const float*)d_in[32],
                       (const float*)d_in[33], (const float*)d_in[34],
                       (float*)d_out);
}

// Round 11
// 1469.798 us; speedup vs baseline: 1.1110x; 1.0820x over previous
//
#include <hip/hip_runtime.h>
#include <cstddef>
#include <cstdint>

#define NN 20000
#define EE 160000
#define EPRIME 180000   // EE + NN (self loops)
#define GG 128
#define FF 114
#define HH 10
#define HFD 1140        // FF*HH
#define KP 1152         // padded feature dim (36*32, 9*128)
#define F1K 2280        // fcg1 K
#define F1KS 18         // split-K chunks
#define F1KC 128        // chunk size
#define NSCB 79         // scan blocks = cdiv(NN,256)

typedef unsigned short ushort_t;
typedef __attribute__((ext_vector_type(8))) short bf16x8;
typedef __attribute__((ext_vector_type(4))) float f32x4;

static inline int cdiv(int a, int b) { return (a + b - 1) / b; }

// ---------------- bf16 helpers ----------------

__device__ __forceinline__ ushort_t f2bf(float v) {
    union { float f; unsigned u; } c; c.f = v;
    unsigned u = c.u;
    unsigned r = (u + 0x7fffu + ((u >> 16) & 1u)) >> 16;   // RNE
    return (ushort_t)r;
}
__device__ __forceinline__ float bf2f(ushort_t h) {
    union { unsigned u; float f; } c; c.u = ((unsigned)h) << 16;
    return c.f;
}

__device__ __forceinline__ void gload16(const void* g, const ushort_t* l) {
    __builtin_amdgcn_global_load_lds(
        (const __attribute__((address_space(1))) unsigned int*)g,
        (__attribute__((address_space(3))) unsigned int*)l, 16, 0, 0);
}

// ---------------- CSR construction ----------------

__global__ void k_init(int* __restrict__ deg, int* __restrict__ gstart, int* __restrict__ gend) {
    int i = blockIdx.x * blockDim.x + threadIdx.x;
    if (i < NN) deg[i] = 1;               // self loop
    if (i < GG) { gstart[i] = NN; gend[i] = 0; }
}

__global__ void k_count(const int* __restrict__ ei, int* __restrict__ deg) {
    int i = blockIdx.x * blockDim.x + threadIdx.x;
    if (i < EE) atomicAdd(&deg[ei[EE + i]], 1);
}

// hierarchical scan: per-block inclusive + block totals
__global__ void k_scan1(const int* __restrict__ deg, int* __restrict__ offs, int* __restrict__ bsum) {
    __shared__ int tmp[256];
    int b = blockIdx.x, tid = threadIdx.x;
    int i = b * 256 + tid;
    int v = (i < NN) ? deg[i] : 0;
    tmp[tid] = v;
    __syncthreads();
#pragma unroll
    for (int off = 1; off < 256; off <<= 1) {
        int t = (tid >= off) ? tmp[tid - off] : 0;
        __syncthreads();
        tmp[tid] += t;
        __syncthreads();
    }
    if (i < NN) offs[i + 1] = tmp[tid];
    if (tid == 255) bsum[b] = tmp[255];
}

__global__ void k_scan2(int* __restrict__ bsum) {
    __shared__ int tmp[128];
    int tid = threadIdx.x;
    int v = (tid < NSCB) ? bsum[tid] : 0;
    tmp[tid] = v;
    __syncthreads();
#pragma unroll
    for (int off = 1; off < 128; off <<= 1) {
        int t = (tid >= off) ? tmp[tid - off] : 0;
        __syncthreads();
        tmp[tid] += t;
        __syncthreads();
    }
    if (tid < NSCB) bsum[tid] = tmp[tid] - v;   // exclusive prefix
}

// fused: finalize offs + cursor + dinv + graph ranges
__global__ void k_scan3prep(int* __restrict__ offs, const int* __restrict__ bsum,
                            int* __restrict__ cursor, const int* __restrict__ deg,
                            float* __restrict__ dinv, const int* __restrict__ batch,
                            int* __restrict__ gstart, int* __restrict__ gend) {
    int i = blockIdx.x * 256 + threadIdx.x;
    if (i < NN) {
        int o = offs[i + 1] + bsum[i >> 8];   // inclusive prefix up to i
        offs[i + 1] = o;
        cursor[i] = o - deg[i];               // exclusive prefix = offs[i]
        dinv[i] = rsqrtf((float)deg[i]);
        int b = batch[i];
        atomicMin(&gstart[b], i);
        atomicMax(&gend[b], i + 1);
    }
    if (i == 0) offs[0] = 0;
}

__global__ void k_fill(const int* __restrict__ ei, int* __restrict__ cursor, int* __restrict__ csr) {
    int i = blockIdx.x * blockDim.x + threadIdx.x;
    if (i < EPRIME) {
        int s, d;
        if (i < EE) { s = ei[i]; d = ei[EE + i]; }
        else        { s = i - EE; d = s; }
        int pos = atomicAdd(&cursor[d], 1);
        csr[pos] = s;
    }
}

// ---------------- split / transpose-split conversions ----------------

__global__ void k_split_x(const float* __restrict__ x, ushort_t* __restrict__ xhi, ushort_t* __restrict__ xlo) {
    int idx = blockIdx.x * 256 + threadIdx.x;
    if (idx >= NN * 128) return;
    int n = idx >> 7, k = idx & 127;
    float v = (k < FF) ? x[(size_t)n * FF + k] : 0.f;
    ushort_t hi = f2bf(v);
    ushort_t lo = f2bf(v - bf2f(hi));
    xhi[idx] = hi; xlo[idx] = lo;
}

// W [K,Nc] -> T[n][k]=W[k][n], split bf16, zero pad. Coalesced via LDS 64x64 tiles.
__global__ __launch_bounds__(256) void k_tsplitT(const float* __restrict__ W, int K, int Nc,
                                                 int Kpad, ushort_t* __restrict__ Thi,
                                                 ushort_t* __restrict__ Tlo) {
    __shared__ float tile[64][65];
    int kb = blockIdx.x * 64;
    int nb = blockIdx.y * 64;
    int c = threadIdx.x & 63, r4 = threadIdx.x >> 6;
#pragma unroll
    for (int rr = 0; rr < 16; ++rr) {
        int r = r4 * 16 + rr;
        int gk = kb + r, gn = nb + c;
        tile[r][c] = (gk < K && gn < Nc) ? W[(size_t)gk * Nc + gn] : 0.f;
    }
    __syncthreads();
#pragma unroll
    for (int rr = 0; rr < 16; ++rr) {
        int r = r4 * 16 + rr;
        int gn = nb + r, gk = kb + c;
        float v = tile[c][r];
        ushort_t hi = f2bf(v);
        ushort_t lo = f2bf(v - bf2f(hi));
        size_t o = (size_t)gn * Kpad + gk;
        Thi[o] = hi; Tlo[o] = lo;
    }
}

// ---------------- split-bf16 MFMA GEMM, 2-phase dbuf + ROW-MAJOR XCD swizzle ----------------
// ASPLIT=1: A split hi/lo (4 planes, 3 MFMA terms). ASPLIT=0: A bf16-only (3 planes, 2 terms,
// stage 24KB, LDS 48KB -> 3 blocks/CU; uses r10's measured 7.6x error headroom).
// Output: bf16 single plane [M][ldcs], zero-padded cols >= Nreal.

template <int ASPLIT>
__global__ __launch_bounds__(256) void mfma_gemm(
    const ushort_t* __restrict__ Ahi, const ushort_t* __restrict__ Alo,
    const ushort_t* __restrict__ Bthi, const ushort_t* __restrict__ Btlo,
    int lda, int ldb, int M, int Nreal, int ksteps, int ncb,
    ushort_t* __restrict__ Cb, int ldcs) {
    constexpr unsigned STG = (ASPLIT ? 4 : 3) * 4096;   // ushorts per stage
    constexpr unsigned OFF_BH = (ASPLIT ? 2 : 1) * 4096;
    constexpr unsigned OFF_BL = OFF_BH + 4096;
    __shared__ __align__(16) ushort_t lds[2 * STG];
    const int tid = threadIdx.x;
    const int lane = tid & 63;
    const int w = tid >> 6;
    const int wr = w >> 1, wc = w & 1;

    // bijective XCD-chunked swizzle (m204), row-major block decode
    int nwg = gridDim.x;
    int q = nwg >> 3, r8 = nwg & 7;
    int xcd = blockIdx.x & 7, sidx = blockIdx.x >> 3;
    int wg = (xcd < r8 ? xcd * (q + 1) : r8 * (q + 1) + (xcd - r8) * q) + sidx;
    int brow = wg / ncb, bcol = wg - brow * ncb;

    int row0 = brow * 128; if (row0 > M - 128) row0 = M - 128;   // overlap trick, idempotent writes
    const int col0 = bcol * 128;

    f32x4 acc[4][4];
#pragma unroll
    for (int i = 0; i < 4; ++i)
#pragma unroll
        for (int j = 0; j < 4; ++j) acc[i][j] = (f32x4){0.f, 0.f, 0.f, 0.f};

    const size_t ldaB = (size_t)lda * 2, ldbB = (size_t)ldb * 2;
    const char* pAhi[2]; const char* pAlo[2]; const char* pBhi[2]; const char* pBlo[2];
    unsigned ldsoff[2];
#pragma unroll
    for (int i = 0; i < 2; ++i) {
        int c = (w * 2 + i) * 64 + lane;
        int kg = c >> 7, r = c & 127;
        pAhi[i] = (const char*)Ahi + (size_t)(row0 + r) * ldaB + kg * 16;
        if (ASPLIT) pAlo[i] = (const char*)Alo + (size_t)(row0 + r) * ldaB + kg * 16;
        pBhi[i] = (const char*)Bthi + (size_t)(col0 + r) * ldbB + kg * 16;
        pBlo[i] = (const char*)Btlo + (size_t)(col0 + r) * ldbB + kg * 16;
        ldsoff[i] = (w * 2 + i) * 512;
    }
    const int kgf = lane >> 4, r15 = lane & 15;

    auto STAGE = [&](int buf, int ks) {
        size_t kb = (size_t)ks * 64;
        unsigned bo = buf ? STG : 0u;
#pragma unroll
        for (int i = 0; i < 2; ++i) {
            gload16(pAhi[i] + kb, lds + bo + 0 + ldsoff[i]);
            if (ASPLIT) gload16(pAlo[i] + kb, lds + bo + 4096 + ldsoff[i]);
            gload16(pBhi[i] + kb, lds + bo + OFF_BH + ldsoff[i]);
            gload16(pBlo[i] + kb, lds + bo + OFF_BL + ldsoff[i]);
        }
    };

    STAGE(0, 0);
    asm volatile("s_waitcnt vmcnt(0)" ::: "memory");
    __syncthreads();
    int cur = 0;

    for (int ks = 0; ks < ksteps; ++ks) {
        if (ks + 1 < ksteps) STAGE(cur ^ 1, ks + 1);   // prefetch flies during MFMA
        const ushort_t* lb = lds + (cur ? STG : 0u);
        bf16x8 ah[4], al[4], bh[4], bl[4];
#pragma unroll
        for (int i = 0; i < 4; ++i) {
            int ra = wr * 64 + i * 16 + r15;
            int rb = wc * 64 + i * 16 + r15;
            ah[i] = *(const bf16x8*)(lb + 0 + kgf * 1024 + ra * 8);
            if (ASPLIT) al[i] = *(const bf16x8*)(lb + 4096 + kgf * 1024 + ra * 8);
            bh[i] = *(const bf16x8*)(lb + OFF_BH + kgf * 1024 + rb * 8);
            bl[i] = *(const bf16x8*)(lb + OFF_BL + kgf * 1024 + rb * 8);
        }
#pragma unroll
        for (int i = 0; i < 4; ++i)
#pragma unroll
            for (int j = 0; j < 4; ++j) {
                acc[i][j] = __builtin_amdgcn_mfma_f32_16x16x32_bf16(ah[i], bh[j], acc[i][j], 0, 0, 0);
                acc[i][j] = __builtin_amdgcn_mfma_f32_16x16x32_bf16(ah[i], bl[j], acc[i][j], 0, 0, 0);
                if (ASPLIT)
                    acc[i][j] = __builtin_amdgcn_mfma_f32_16x16x32_bf16(al[i], bh[j], acc[i][j], 0, 0, 0);
            }
        asm volatile("s_waitcnt vmcnt(0)" ::: "memory");
        __syncthreads();
        cur ^= 1;
    }

    const int g4 = lane >> 4;
#pragma unroll
    for (int i = 0; i < 4; ++i)
#pragma unroll
        for (int j = 0; j < 4; ++j) {
            int c = col0 + wc * 64 + j * 16 + r15;
#pragma unroll
            for (int reg = 0; reg < 4; ++reg) {
                int r = row0 + wr * 64 + i * 16 + g4 * 4 + reg;
                if (r < M) {
                    float v = (c < Nreal) ? acc[i][j][reg] : 0.f;
                    Cb[(size_t)r * ldcs + c] = f2bf(v);
                }
            }
        }
}

// ---------------- attention logits from bf16 h0 ----------------

__global__ void k_att(const ushort_t* __restrict__ h0b,
                      const float* __restrict__ att_src, const float* __restrict__ att_dst,
                      float* __restrict__ as_, float* __restrict__ ad_) {
    int id = blockIdx.x * blockDim.x + threadIdx.x;
    if (id >= NN * HH) return;
    int n = id / HH, h = id % HH;
    const ushort_t* row = h0b + (size_t)n * KP + h * FF;
    const float* ws = att_src + h * FF;
    const float* wd = att_dst + h * FF;
    float as = 0.f, ad = 0.f;
    for (int f = 0; f < FF; f += 2) {
        unsigned qq = *(const unsigned*)(row + f);
        float v0 = bf2f((ushort_t)(qq & 0xffffu));
        float v1 = bf2f((ushort_t)(qq >> 16));
        as += v0 * ws[f] + v1 * ws[f + 1];
        ad += v0 * wd[f] + v1 * wd[f + 1];
    }
    as_[id] = as;
    ad_[id] = ad;
}

// ---------------- GAT aggregation: bf16 gathers, 8-edge groups + clamped-4 tail ----------------
// softmax WITHOUT max-subtraction (shift-invariant; logits are O(1)).
// Output: single bf16 plane h1b (zero-padded) — GEMM2 consumes A-side bf16-only.

template <int NU>
__device__ __forceinline__ void gat_group(
    int eg, int end, int lane, float my_ad,
    const int* __restrict__ csr, const float* __restrict__ as_,
    const ushort_t* __restrict__ h0b,
    int hA0, int hB0, int cr0, int hA1, int hB1, int cr1,
    int hA2, int hB2, int cr2,
    float& den, float* acc0, float* acc1, float* acc2) {
    int s[NU]; float ex[NU];
#pragma unroll
    for (int u = 0; u < NU; ++u) {
        int idx = eg + u; if (idx > end - 1) idx = end - 1;   // clamp (weight zeroed below)
        s[u] = csr[idx];
    }
#pragma unroll
    for (int u = 0; u < NU; ++u) {
        float e = 0.f;
        if (lane < HH) {
            float t = as_[s[u] * HH + lane] + my_ad;
            t = (t >= 0.f) ? t : 0.2f * t;
            e = __expf(t);
            if (eg + u >= end) e = 0.f;
        }
        ex[u] = e;
        den += e;
    }
    const int kb0 = 8 * lane, kb1 = 512 + 8 * lane, kb2 = 1024 + 8 * lane;
    bf16x8 qv[NU];
    // j0
#pragma unroll
    for (int u = 0; u < NU; ++u) qv[u] = *(const bf16x8*)(h0b + (size_t)s[u] * KP + kb0);
#pragma unroll
    for (int u = 0; u < NU; ++u) {
        float wA = __shfl(ex[u], hA0, 64), wB = __shfl(ex[u], hB0, 64);
#pragma unroll
        for (int e = 0; e < 8; ++e)
            acc0[e] += ((e >= cr0) ? wB : wA) * bf2f((ushort_t)qv[u][e]);
    }
    // j1
#pragma unroll
    for (int u = 0; u < NU; ++u) qv[u] = *(const bf16x8*)(h0b + (size_t)s[u] * KP + kb1);
#pragma unroll
    for (int u = 0; u < NU; ++u) {
        float wA = __shfl(ex[u], hA1, 64), wB = __shfl(ex[u], hB1, 64);
#pragma unroll
        for (int e = 0; e < 8; ++e)
            acc1[e] += ((e >= cr1) ? wB : wA) * bf2f((ushort_t)qv[u][e]);
    }
    // j2 (lane<16)
    if (lane < 16) {
#pragma unroll
        for (int u = 0; u < NU; ++u) qv[u] = *(const bf16x8*)(h0b + (size_t)s[u] * KP + kb2);
#pragma unroll
        for (int u = 0; u < NU; ++u) {
            float wA = __shfl(ex[u], hA2, 64), wB = __shfl(ex[u], hB2, 64);
#pragma unroll
            for (int e = 0; e < 8; ++e)
                acc2[e] += ((e >= cr2) ? wB : wA) * bf2f((ushort_t)qv[u][e]);
        }
    }
}

__global__ __launch_bounds__(256) void gat_agg(
    const ushort_t* __restrict__ h0b,
    const float* __restrict__ as_, const float* __restrict__ ad_,
    const int* __restrict__ offs, const int* __restrict__ csr,
    const float* __restrict__ bias,
    ushort_t* __restrict__ outb) {
    int lane = threadIdx.x & 63;
    int n = blockIdx.x * 4 + (threadIdx.x >> 6);
    if (n >= NN) return;
    int beg = offs[n], end = offs[n + 1];
    float my_ad = (lane < HH) ? ad_[n * HH + lane] : 0.f;

    const int kb0 = 8 * lane, kb1 = 512 + 8 * lane, kb2 = 1024 + 8 * lane;
    int hA0 = min(kb0 / FF, HH - 1), hB0 = min(hA0 + 1, HH - 1);
    int cr0 = (kb0 / FF + 1) * FF - kb0;
    int hA1 = min(kb1 / FF, HH - 1), hB1 = min(hA1 + 1, HH - 1);
    int cr1 = (kb1 / FF + 1) * FF - kb1;
    int hA2 = min(kb2 / FF, HH - 1), hB2 = min(hA2 + 1, HH - 1);
    int cr2 = (kb2 / FF + 1) * FF - kb2;

    float den = 0.f;
    float acc0[8] = {}, acc1[8] = {}, acc2[8] = {};

    int eg = beg;
    for (; eg + 8 <= end; eg += 8)
        gat_group<8>(eg, end, lane, my_ad, csr, as_, h0b,
                     hA0, hB0, cr0, hA1, hB1, cr1, hA2, hB2, cr2, den, acc0, acc1, acc2);
    for (; eg < end; eg += 4)
        gat_group<4>(eg, end, lane, my_ad, csr, as_, h0b,
                     hA0, hB0, cr0, hA1, hB1, cr1, hA2, hB2, cr2, den, acc0, acc1, acc2);

    // write-out: alpha = acc/den, + bias, lrelu -> bf16 single plane
    {
        bf16x8 vb;
#pragma unroll
        for (int e = 0; e < 8; ++e) {
            int k = kb0 + e;
            float d = __shfl(den, (e >= cr0) ? hB0 : hA0, 64);
            float v = acc0[e] / d + bias[k];
            v = (v >= 0.f) ? v : 0.01f * v;
            vb[e] = (short)f2bf(v);
        }
        *(bf16x8*)(outb + (size_t)n * KP + kb0) = vb;
#pragma unroll
        for (int e = 0; e < 8; ++e) {
            int k = kb1 + e;
            float d = __shfl(den, (e >= cr1) ? hB1 : hA1, 64);
            float v = acc1[e] / d + bias[k];
            v = (v >= 0.f) ? v : 0.01f * v;
            vb[e] = (short)f2bf(v);
        }
        *(bf16x8*)(outb + (size_t)n * KP + kb1) = vb;
    }
    if (lane < 16) {
        bf16x8 vb;
#pragma unroll
        for (int e = 0; e < 8; ++e) {
            int k = kb2 + e;
            float v = 0.f;
            if (k < HFD) {
                float d = __shfl(den, (e >= cr2) ? hB2 : hA2, 64);
                v = acc2[e] / d + bias[k];
                v = (v >= 0.f) ? v : 0.01f * v;
            } else {
                (void)__shfl(den, hA2, 64);   // keep shfl uniform within branch
            }
            vb[e] = (short)f2bf(v);
        }
        *(bf16x8*)(outb + (size_t)n * KP + kb2) = vb;
    }
}

// ---------------- GCN aggregation: bf16 gathers, 8-edge groups + clamped-4 tail ----------------

template <int NU>
__device__ __forceinline__ void gcn_group(
    int eg, int end, int lane, float di,
    const int* __restrict__ csr, const float* __restrict__ dinv,
    const ushort_t* __restrict__ h2b,
    float* acc0, float* acc1, float* acc2) {
    int s[NU]; float w[NU];
#pragma unroll
    for (int u = 0; u < NU; ++u) {
        int idx = eg + u; if (idx > end - 1) idx = end - 1;
        s[u] = csr[idx];
    }
#pragma unroll
    for (int u = 0; u < NU; ++u) {
        float ww = dinv[s[u]] * di;
        w[u] = (eg + u < end) ? ww : 0.f;
    }
    const int kb0 = 8 * lane, kb1 = 512 + 8 * lane, kb2 = 1024 + 8 * lane;
    bf16x8 qv[NU];
#pragma unroll
    for (int u = 0; u < NU; ++u) qv[u] = *(const bf16x8*)(h2b + (size_t)s[u] * KP + kb0);
#pragma unroll
    for (int u = 0; u < NU; ++u)
#pragma unroll
        for (int e = 0; e < 8; ++e) acc0[e] += w[u] * bf2f((ushort_t)qv[u][e]);
#pragma unroll
    for (int u = 0; u < NU; ++u) qv[u] = *(const bf16x8*)(h2b + (size_t)s[u] * KP + kb1);
#pragma unroll
    for (int u = 0; u < NU; ++u)
#pragma unroll
        for (int e = 0; e < 8; ++e) acc1[e] += w[u] * bf2f((ushort_t)qv[u][e]);
    if (lane < 16) {
#pragma unroll
        for (int u = 0; u < NU; ++u) qv[u] = *(const bf16x8*)(h2b + (size_t)s[u] * KP + kb2);
#pragma unroll
        for (int u = 0; u < NU; ++u)
#pragma unroll
            for (int e = 0; e < 8; ++e) acc2[e] += w[u] * bf2f((ushort_t)qv[u][e]);
    }
}

__global__ __launch_bounds__(256) void gcn_agg(
    const ushort_t* __restrict__ h2b, const int* __restrict__ offs, const int* __restrict__ csr,
    const float* __restrict__ dinv, const float* __restrict__ bias, float* __restrict__ out) {
    int lane = threadIdx.x & 63;
    int n = blockIdx.x * 4 + (threadIdx.x >> 6);
    if (n >= NN) return;
    int beg = offs[n], end = offs[n + 1];
    float di = dinv[n];
    float acc0[8] = {}, acc1[8] = {}, acc2[8] = {};

    int eg = beg;
    for (; eg + 8 <= end; eg += 8)
        gcn_group<8>(eg, end, lane, di, csr, dinv, h2b, acc0, acc1, acc2);
    for (; eg < end; eg += 4)
        gcn_group<4>(eg, end, lane, di, csr, dinv, h2b, acc0, acc1, acc2);

    const int kb0 = 8 * lane, kb1 = 512 + 8 * lane, kb2 = 1024 + 8 * lane;
    {
        float4 o1, o2;
        float v;
        v = acc0[0] + bias[kb0 + 0]; o1.x = (v >= 0.f) ? v : 0.01f * v;
        v = acc0[1] + bias[kb0 + 1]; o1.y = (v >= 0.f) ? v : 0.01f * v;
        v = acc0[2] + bias[kb0 + 2]; o1.z = (v >= 0.f) ? v : 0.01f * v;
        v = acc0[3] + bias[kb0 + 3]; o1.w = (v >= 0.f) ? v : 0.01f * v;
        v = acc0[4] + bias[kb0 + 4]; o2.x = (v >= 0.f) ? v : 0.01f * v;
        v = acc0[5] + bias[kb0 + 5]; o2.y = (v >= 0.f) ? v : 0.01f * v;
        v = acc0[6] + bias[kb0 + 6]; o2.z = (v >= 0.f) ? v : 0.01f * v;
        v = acc0[7] + bias[kb0 + 7]; o2.w = (v >= 0.f) ? v : 0.01f * v;
        *(float4*)(out + (size_t)n * HFD + kb0) = o1;
        *(float4*)(out + (size_t)n * HFD + kb0 + 4) = o2;
        v = acc1[0] + bias[kb1 + 0]; o1.x = (v >= 0.f) ? v : 0.01f * v;
        v = acc1[1] + bias[kb1 + 1]; o1.y = (v >= 0.f) ? v : 0.01f * v;
        v = acc1[2] + bias[kb1 + 2]; o1.z = (v >= 0.f) ? v : 0.01f * v;
        v = acc1[3] + bias[kb1 + 3]; o1.w = (v >= 0.f) ? v : 0.01f * v;
        v = acc1[4] + bias[kb1 + 4]; o2.x = (v >= 0.f) ? v : 0.01f * v;
        v = acc1[5] + bias[kb1 + 5]; o2.y = (v >= 0.f) ? v : 0.01f * v;
        v = acc1[6] + bias[kb1 + 6]; o2.z = (v >= 0.f) ? v : 0.01f * v;
        v = acc1[7] + bias[kb1 + 7]; o2.w = (v >= 0.f) ? v : 0.01f * v;
        *(float4*)(out + (size_t)n * HFD + kb1) = o1;
        *(float4*)(out + (size_t)n * HFD + kb1 + 4) = o2;
    }
    if (lane < 16) {
#pragma unroll
        for (int e = 0; e < 8; ++e) {
            int k = kb2 + e;
            if (k < HFD) {
                float v = acc2[e] + bias[k];
                out[(size_t)n * HFD + k] = (v >= 0.f) ? v : 0.01f * v;
            }
        }
    }
}

// ---------------- graph pooling (max + mean), float4 ----------------

__global__ void k_pool(const float* __restrict__ hfeat, const int* __restrict__ gs,
                       const int* __restrict__ ge, float* __restrict__ gout) {
    int g = blockIdx.x;
    if (threadIdx.x >= 57) return;
    int m = blockIdx.y * 57 + threadIdx.x;
    int s = gs[g], e = ge[g];
    int cnt = e - s;
    float4 mx = make_float4(-1e30f, -1e30f, -1e30f, -1e30f);
    float4 sm = make_float4(0.f, 0.f, 0.f, 0.f);
    for (int r = s; r < e; ++r) {
        float4 v = *(const float4*)(hfeat + (size_t)r * HFD + 4 * m);
        mx.x = fmaxf(mx.x, v.x); mx.y = fmaxf(mx.y, v.y);
        mx.z = fmaxf(mx.z, v.z); mx.w = fmaxf(mx.w, v.w);
        sm.x += v.x; sm.y += v.y; sm.z += v.z; sm.w += v.w;
    }
    float4 mean;
    if (cnt <= 0) {
        mx = make_float4(0.f, 0.f, 0.f, 0.f);
        mean = make_float4(0.f, 0.f, 0.f, 0.f);
    } else {
        float inv = 1.f / (float)cnt;
        mean = make_float4(sm.x * inv, sm.y * inv, sm.z * inv, sm.w * inv);
    }
    *(float4*)(gout + (size_t)g * (2 * HFD) + 4 * m) = mx;
    *(float4*)(gout + (size_t)g * (2 * HFD) + HFD + 4 * m) = mean;
}

// ---------------- fcg1 split-K (kt loop MUST stay rolled — round-3 spill regression) ----------------

__global__ __launch_bounds__(256) void k_fcg1_part(
    const float* __restrict__ A, const float* __restrict__ B, float* __restrict__ part) {
    __shared__ float As[16][64 + 4];
    __shared__ float Bs[16][64 + 4];
    int tid = threadIdx.x;
    int tx = tid & 15, ty = tid >> 4;
    int row0 = blockIdx.y * 64, col0 = blockIdx.x * 64;
    int kbeg = blockIdx.z * F1KC;
    float acc[4][4] = {};
#pragma unroll 1
    for (int kt = 0; kt < F1KC / 16; ++kt) {
        int kk = kbeg + kt * 16;
#pragma unroll
        for (int l = 0; l < 4; ++l) {
            int idx = tid + 256 * l;
            int m = idx >> 4, k = idx & 15;
            int gr = row0 + m, gk = kk + k;
            As[k][m] = (gk < F1K) ? A[(size_t)gr * F1K + gk] : 0.f;
        }
#pragma unroll
        for (int l = 0; l < 4; ++l) {
            int idx = tid + 256 * l;
            int nn = idx & 63, k = idx >> 6;
            int gc = col0 + nn, gk = kk + k;
            Bs[k][nn] = (gc < 1000 && gk < F1K) ? B[(size_t)gk * 1000 + gc] : 0.f;
        }
        __syncthreads();
#pragma unroll
        for (int k = 0; k < 16; ++k) {
            float4 av = *(const float4*)&As[k][ty * 4];
            float4 bv = *(const float4*)&Bs[k][tx * 4];
            float a[4] = {av.x, av.y, av.z, av.w};
            float b[4] = {bv.x, bv.y, bv.z, bv.w};
#pragma unroll
            for (int i = 0; i < 4; ++i)
#pragma unroll
                for (int j = 0; j < 4; ++j) acc[i][j] += a[i] * b[j];
        }
        __syncthreads();
    }
    float* pc = part + (size_t)blockIdx.z * GG * 1000;
#pragma unroll
    for (int i = 0; i < 4; ++i) {
        int r = row0 + ty * 4 + i;
#pragma unroll
        for (int j = 0; j < 4; ++j) {
            int c = col0 + tx * 4 + j;
            if (c < 1000) pc[(size_t)r * 1000 + c] = acc[i][j];
        }
    }
}

__global__ void k_fcg1_red(const float* __restrict__ part, const float* __restrict__ bias,
                           float* __restrict__ out) {
    int idx = blockIdx.x * 256 + threadIdx.x;
    if (idx >= GG * 1000) return;
    float s = 0.f;
#pragma unroll
    for (int k = 0; k < F1KS; ++k) s += part[(size_t)k * GG * 1000 + idx];
    int n = idx % 1000;
    float v = s + bias[n];
    out[idx] = (v >= 0.f) ? v : 0.01f * v;
}

// ---------------- fcg2 ----------------

__global__ __launch_bounds__(256) void k_fcg2(const float* __restrict__ in, const float* __restrict__ W,
                                              const float* __restrict__ b, float* __restrict__ out) {
    __shared__ float part[4][64];
    int g = blockIdx.x;
    int o = threadIdx.x & 63, p = threadIdx.x >> 6;
    const float* row = in + (size_t)g * 1000;
    float acc = 0.f;
    for (int k = p * 250; k < (p + 1) * 250; ++k) acc += row[k] * W[k * 64 + o];
    part[p][o] = acc;
    __syncthreads();
    if (p == 0) out[(size_t)g * 64 + o] = part[0][o] + part[1][o] + part[2][o] + part[3][o] + b[o];
}

// ---------------- final head ----------------

__global__ __launch_bounds__(256) void k_final(
    const float* __restrict__ b1, const float* __restrict__ b2, const float* __restrict__ target,
    const float* __restrict__ fcxtW, const float* __restrict__ fcxtb,
    const float* __restrict__ fc1W, const float* __restrict__ fc1b,
    const float* __restrict__ fc2W, const float* __restrict__ fc2b,
    const float* __restrict__ outW, const float* __restrict__ outb,
    float* __restrict__ out) {
    __shared__ float xc[256];
    __shared__ float xt2[128];
    __shared__ float y1[128];
    __shared__ float y2[32];
    int g = blockIdx.x, t = threadIdx.x;
    if (t < 64) xc[t] = b1[(size_t)g * 64 + t];
    else if (t < 128) xc[t] = b2[(size_t)g * 64 + (t - 64)];
    {
        int c = t & 127, p = t >> 7;
        float acc = 0.f;
        const float* trow = target + (size_t)g * 1000;
        for (int k = p * 500; k < (p + 1) * 500; ++k) acc += trow[k] * fcxtW[k * 128 + c];
        if (p == 1) xt2[c] = acc;
        __syncthreads();
        if (p == 0) xc[128 + c] = acc + xt2[c] + fcxtb[c];
    }
    __syncthreads();
    if (t < 128) {
        float acc = 0.f;
        for (int k = 0; k < 256; ++k) acc += xc[k] * fc1W[k * 128 + t];
        acc += fc1b[t];
        y1[t] = (acc >= 0.f) ? acc : 0.01f * acc;
    }
    __syncthreads();
    if (t < 32) {
        float acc = 0.f;
        for (int k = 0; k < 128; ++k) acc += y1[k] * fc2W[k * 32 + t];
        acc += fc2b[t];
        y2[t] = (acc >= 0.f) ? acc : 0.01f * acc;
    }
    __syncthreads();
    if (t == 0) {
        float acc = 0.f;
        for (int k = 0; k < 32; ++k) acc += y2[k] * outW[k];
        out[g] = acc + outb[0];
    }
}

// ---------------- host launch ----------------

extern "C" void kernel_launch(void* const* d_in, const int* in_sizes, int n_in,
                              void* d_out, int out_size, void* d_ws, size_t ws_size,
                              hipStream_t stream) {
    (void)in_sizes; (void)n_in; (void)out_size; (void)ws_size;

    size_t off = 0;
    auto alloc = [&](size_t bytes) -> void* {
        void* p = (char*)d_ws + off;
        off += (bytes + 255) & ~(size_t)255;
        return p;
    };
    char* regionA = (char*)alloc((size_t)2 * NN * KP * 2);
    char* regionB = (char*)alloc((size_t)2 * NN * KP * 2);
    ushort_t* Bthi = (ushort_t*)alloc((size_t)KP * KP * 2);
    ushort_t* Btlo = (ushort_t*)alloc((size_t)KP * KP * 2);
    float* a_s    = (float*)alloc((size_t)NN * HH * 4);
    float* a_d    = (float*)alloc((size_t)NN * HH * 4);
    int*   deg    = (int*)alloc((size_t)NN * 4);
    int*   offs   = (int*)alloc((size_t)(NN + 1) * 4);
    int*   cursor = (int*)alloc((size_t)NN * 4);
    int*   csr    = (int*)alloc((size_t)EPRIME * 4);
    float* dinv   = (float*)alloc((size_t)NN * 4);
    int*   gstart = (int*)alloc((size_t)GG * 4);
    int*   gend   = (int*)alloc((size_t)GG * 4);
    int*   bsum   = (int*)alloc((size_t)128 * 4);
    float* gpool  = (float*)alloc((size_t)GG * 2 * HFD * 4);
    float* fc1out = (float*)alloc((size_t)GG * 1000 * 4);
    float* bout   = (float*)alloc((size_t)2 * GG * 64 * 4);

    // overlays
    ushort_t* h0b  = (ushort_t*)regionA;                     // bf16 [NN][KP], zero-padded
    ushort_t* h2b  = (ushort_t*)regionA;                     // after h0b dead (post gat_agg)
    float*    f1part = (float*)regionA;                      // after h2b dead (post gcn_agg)
    ushort_t* xhi  = (ushort_t*)regionB;
    ushort_t* xlo  = (ushort_t*)regionB + (size_t)NN * 128;
    ushort_t* h1b  = (ushort_t*)regionB;                     // bf16 [NN][KP], after x is dead
    float*    hgcn = (float*)regionB;                        // after h1 is dead

    const float* target = (const float*)d_in[6];
    const int NRB = cdiv(NN, 128);        // 157 row blocks
    const int NCB = KP / 128;             // 9 col blocks

    for (int b = 0; b < 2; ++b) {
        const float* x     = (const float*)d_in[b ? 3 : 0];
        const int*   ei    = (const int*)d_in[b ? 4 : 1];
        const int*   batch = (const int*)d_in[b ? 5 : 2];
        int pb = 7 + b * 10;
        const float* gatW    = (const float*)d_in[pb + 0];
        const float* att_src = (const float*)d_in[pb + 1];
        const float* att_dst = (const float*)d_in[pb + 2];
        const float* gatb    = (const float*)d_in[pb + 3];
        const float* gcnW    = (const float*)d_in[pb + 4];
        const float* gcnb    = (const float*)d_in[pb + 5];
        const float* f1W     = (const float*)d_in[pb + 6];
        const float* f1b     = (const float*)d_in[pb + 7];
        const float* f2W     = (const float*)d_in[pb + 8];
        const float* f2b     = (const float*)d_in[pb + 9];

        // CSR
        hipLaunchKernelGGL(k_init, dim3(cdiv(NN, 256)), dim3(256), 0, stream, deg, gstart, gend);
        hipLaunchKernelGGL(k_count, dim3(cdiv(EE, 256)), dim3(256), 0, stream, ei, deg);
        hipLaunchKernelGGL(k_scan1, dim3(NSCB), dim3(256), 0, stream, deg, offs, bsum);
        hipLaunchKernelGGL(k_scan2, dim3(1), dim3(128), 0, stream, bsum);
        hipLaunchKernelGGL(k_scan3prep, dim3(NSCB), dim3(256), 0, stream,
                           offs, bsum, cursor, deg, dinv, batch, gstart, gend);
        hipLaunchKernelGGL(k_fill, dim3(cdiv(EPRIME, 256)), dim3(256), 0, stream, ei, cursor, csr);

        // x -> split (regionB), gatW -> transpose split
        hipLaunchKernelGGL(k_split_x, dim3(cdiv(NN * 128, 256)), dim3(256), 0, stream, x, xhi, xlo);
        hipLaunchKernelGGL(k_tsplitT, dim3(128 / 64, KP / 64), dim3(256), 0, stream,
                           gatW, FF, HFD, 128, Bthi, Btlo);

        // h0 = x @ gatW -> bf16 (regionA). ksteps=4 (Kpad=128), split A
        hipLaunchKernelGGL((mfma_gemm<1>), dim3(NRB * NCB), dim3(256), 0, stream,
                           xhi, xlo, Bthi, Btlo, 128, 128, NN, HFD, 4, NCB, h0b, KP);

        // attention logits
        hipLaunchKernelGGL(k_att, dim3(cdiv(NN * HH, 256)), dim3(256), 0, stream,
                           h0b, att_src, att_dst, a_s, a_d);

        // GAT aggregate -> h1 bf16 single plane (regionB)
        hipLaunchKernelGGL(gat_agg, dim3(cdiv(NN, 4)), dim3(256), 0, stream,
                           h0b, a_s, a_d, offs, csr, gatb, h1b);

        // gcnW -> transpose split
        hipLaunchKernelGGL(k_tsplitT, dim3(KP / 64, KP / 64), dim3(256), 0, stream,
                           gcnW, HFD, HFD, KP, Bthi, Btlo);

        // h2 = h1 @ gcnW -> bf16 (regionA). ksteps=36, A bf16-only (3 planes, 2 MFMA terms)
        hipLaunchKernelGGL((mfma_gemm<0>), dim3(NRB * NCB), dim3(256), 0, stream,
                           h1b, (const ushort_t*)nullptr, Bthi, Btlo, KP, KP, NN, HFD, KP / 32, NCB,
                           h2b, KP);

        // GCN aggregate -> hgcn fp32 (regionB)
        hipLaunchKernelGGL(gcn_agg, dim3(cdiv(NN, 4)), dim3(256), 0, stream,
                           h2b, offs, csr, dinv, gcnb, hgcn);

        // pooling
        hipLaunchKernelGGL(k_pool, dim3(GG, 5), dim3(64), 0, stream, hgcn, gstart, gend, gpool);

        // fcg1 split-K
        hipLaunchKernelGGL(k_fcg1_part, dim3(16, 2, F1KS), dim3(256), 0, stream,
                           gpool, f1W, f1part);
        hipLaunchKernelGGL(k_fcg1_red, dim3(cdiv(GG * 1000, 256)), dim3(256), 0, stream,
                           f1part, f1b, fc1out);

        // fcg2
        hipLaunchKernelGGL(k_fcg2, dim3(GG), dim3(256), 0, stream,
                           fc1out, f2W, f2b, bout + (size_t)b * GG * 64);
    }

    hipLaunchKernelGGL(k_final, dim3(GG), dim3(256), 0, stream,
                       bout, bout + (size_t)GG * 64, target,
                       (const float*)d_in[27], (const float*)d_in[28],
                       (const float*)d_in[29], (const float*)d_in[30],
                       (const float*)d_in[31], (const float*)d_in[32],
                       (const float*)d_in[33], (const float*)d_in[34],
                       (float*)d_out);
}

// Round 12
// 1418.345 us; speedup vs baseline: 1.1513x; 1.0363x over previous
//
#include <hip/hip_runtime.h>
#include <cstddef>
#include <cstdint>

#define NN 20000
#define EE 160000
#define EPRIME 180000   // EE + NN (self loops)
#define GG 128
#define FF 114
#define HH 10
#define HFD 1140        // FF*HH
#define KP 1152         // padded feature dim (36*32, 9*128)
#define F1K 2280        // fcg1 K
#define F1KS 18         // split-K chunks
#define F1KC 128        // chunk size
#define NSCB 79         // scan blocks = cdiv(NN,256)

typedef unsigned short ushort_t;
typedef __attribute__((ext_vector_type(8))) short bf16x8;
typedef __attribute__((ext_vector_type(4))) float f32x4;

static inline int cdiv(int a, int b) { return (a + b - 1) / b; }

// ---------------- bf16 helpers ----------------

__device__ __forceinline__ ushort_t f2bf(float v) {
    union { float f; unsigned u; } c; c.f = v;
    unsigned u = c.u;
    unsigned r = (u + 0x7fffu + ((u >> 16) & 1u)) >> 16;   // RNE
    return (ushort_t)r;
}
__device__ __forceinline__ float bf2f(ushort_t h) {
    union { unsigned u; float f; } c; c.u = ((unsigned)h) << 16;
    return c.f;
}

__device__ __forceinline__ void gload16(const void* g, const ushort_t* l) {
    __builtin_amdgcn_global_load_lds(
        (const __attribute__((address_space(1))) unsigned int*)g,
        (__attribute__((address_space(3))) unsigned int*)l, 16, 0, 0);
}

// ---------------- CSR construction ----------------

__global__ void k_init(int* __restrict__ deg, int* __restrict__ gstart, int* __restrict__ gend) {
    int i = blockIdx.x * blockDim.x + threadIdx.x;
    if (i < NN) deg[i] = 1;               // self loop
    if (i < GG) { gstart[i] = NN; gend[i] = 0; }
}

__global__ void k_count(const int* __restrict__ ei, int* __restrict__ deg) {
    int i = blockIdx.x * blockDim.x + threadIdx.x;
    if (i < EE) atomicAdd(&deg[ei[EE + i]], 1);
}

// hierarchical scan: per-block inclusive + block totals
__global__ void k_scan1(const int* __restrict__ deg, int* __restrict__ offs, int* __restrict__ bsum) {
    __shared__ int tmp[256];
    int b = blockIdx.x, tid = threadIdx.x;
    int i = b * 256 + tid;
    int v = (i < NN) ? deg[i] : 0;
    tmp[tid] = v;
    __syncthreads();
#pragma unroll
    for (int off = 1; off < 256; off <<= 1) {
        int t = (tid >= off) ? tmp[tid - off] : 0;
        __syncthreads();
        tmp[tid] += t;
        __syncthreads();
    }
    if (i < NN) offs[i + 1] = tmp[tid];
    if (tid == 255) bsum[b] = tmp[255];
}

__global__ void k_scan2(int* __restrict__ bsum) {
    __shared__ int tmp[128];
    int tid = threadIdx.x;
    int v = (tid < NSCB) ? bsum[tid] : 0;
    tmp[tid] = v;
    __syncthreads();
#pragma unroll
    for (int off = 1; off < 128; off <<= 1) {
        int t = (tid >= off) ? tmp[tid - off] : 0;
        __syncthreads();
        tmp[tid] += t;
        __syncthreads();
    }
    if (tid < NSCB) bsum[tid] = tmp[tid] - v;   // exclusive prefix
}

// fused: finalize offs + cursor + dinv + graph ranges
__global__ void k_scan3prep(int* __restrict__ offs, const int* __restrict__ bsum,
                            int* __restrict__ cursor, const int* __restrict__ deg,
                            float* __restrict__ dinv, const int* __restrict__ batch,
                            int* __restrict__ gstart, int* __restrict__ gend) {
    int i = blockIdx.x * 256 + threadIdx.x;
    if (i < NN) {
        int o = offs[i + 1] + bsum[i >> 8];   // inclusive prefix up to i
        offs[i + 1] = o;
        cursor[i] = o - deg[i];               // exclusive prefix = offs[i]
        dinv[i] = rsqrtf((float)deg[i]);
        int b = batch[i];
        atomicMin(&gstart[b], i);
        atomicMax(&gend[b], i + 1);
    }
    if (i == 0) offs[0] = 0;
}

__global__ void k_fill(const int* __restrict__ ei, int* __restrict__ cursor, int* __restrict__ csr) {
    int i = blockIdx.x * blockDim.x + threadIdx.x;
    if (i < EPRIME) {
        int s, d;
        if (i < EE) { s = ei[i]; d = ei[EE + i]; }
        else        { s = i - EE; d = s; }
        int pos = atomicAdd(&cursor[d], 1);
        csr[pos] = s;
    }
}

// ---------------- split / transpose-split conversions ----------------

__global__ void k_split_x(const float* __restrict__ x, ushort_t* __restrict__ xhi, ushort_t* __restrict__ xlo) {
    int idx = blockIdx.x * 256 + threadIdx.x;
    if (idx >= NN * 128) return;
    int n = idx >> 7, k = idx & 127;
    float v = (k < FF) ? x[(size_t)n * FF + k] : 0.f;
    ushort_t hi = f2bf(v);
    ushort_t lo = f2bf(v - bf2f(hi));
    xhi[idx] = hi; xlo[idx] = lo;
}

// W [K,Nc] -> T[n][k]=W[k][n], split bf16, zero pad. Coalesced via LDS 64x64 tiles.
__global__ __launch_bounds__(256) void k_tsplitT(const float* __restrict__ W, int K, int Nc,
                                                 int Kpad, ushort_t* __restrict__ Thi,
                                                 ushort_t* __restrict__ Tlo) {
    __shared__ float tile[64][65];
    int kb = blockIdx.x * 64;
    int nb = blockIdx.y * 64;
    int c = threadIdx.x & 63, r4 = threadIdx.x >> 6;
#pragma unroll
    for (int rr = 0; rr < 16; ++rr) {
        int r = r4 * 16 + rr;
        int gk = kb + r, gn = nb + c;
        tile[r][c] = (gk < K && gn < Nc) ? W[(size_t)gk * Nc + gn] : 0.f;
    }
    __syncthreads();
#pragma unroll
    for (int rr = 0; rr < 16; ++rr) {
        int r = r4 * 16 + rr;
        int gn = nb + r, gk = kb + c;
        float v = tile[c][r];
        ushort_t hi = f2bf(v);
        ushort_t lo = f2bf(v - bf2f(hi));
        size_t o = (size_t)gn * Kpad + gk;
        Thi[o] = hi; Tlo[o] = lo;
    }
}

// ---------------- split-bf16 MFMA GEMM, 2-phase dbuf + ROW-MAJOR XCD swizzle ----------------
// ASPLIT=1: A split hi/lo (4 planes, 3 MFMA terms). ASPLIT=0: A bf16-only (3 planes, 2 terms).
// Output: bf16 single plane [M][ldcs], zero-padded cols >= Nreal.

template <int ASPLIT>
__global__ __launch_bounds__(256) void mfma_gemm(
    const ushort_t* __restrict__ Ahi, const ushort_t* __restrict__ Alo,
    const ushort_t* __restrict__ Bthi, const ushort_t* __restrict__ Btlo,
    int lda, int ldb, int M, int Nreal, int ksteps, int ncb,
    ushort_t* __restrict__ Cb, int ldcs) {
    constexpr unsigned STG = (ASPLIT ? 4 : 3) * 4096;   // ushorts per stage
    constexpr unsigned OFF_BH = (ASPLIT ? 2 : 1) * 4096;
    constexpr unsigned OFF_BL = OFF_BH + 4096;
    __shared__ __align__(16) ushort_t lds[2 * STG];
    const int tid = threadIdx.x;
    const int lane = tid & 63;
    const int w = tid >> 6;
    const int wr = w >> 1, wc = w & 1;

    // bijective XCD-chunked swizzle (m204), row-major block decode
    int nwg = gridDim.x;
    int q = nwg >> 3, r8 = nwg & 7;
    int xcd = blockIdx.x & 7, sidx = blockIdx.x >> 3;
    int wg = (xcd < r8 ? xcd * (q + 1) : r8 * (q + 1) + (xcd - r8) * q) + sidx;
    int brow = wg / ncb, bcol = wg - brow * ncb;

    int row0 = brow * 128; if (row0 > M - 128) row0 = M - 128;   // overlap trick, idempotent writes
    const int col0 = bcol * 128;

    f32x4 acc[4][4];
#pragma unroll
    for (int i = 0; i < 4; ++i)
#pragma unroll
        for (int j = 0; j < 4; ++j) acc[i][j] = (f32x4){0.f, 0.f, 0.f, 0.f};

    const size_t ldaB = (size_t)lda * 2, ldbB = (size_t)ldb * 2;
    const char* pAhi[2]; const char* pAlo[2]; const char* pBhi[2]; const char* pBlo[2];
    unsigned ldsoff[2];
#pragma unroll
    for (int i = 0; i < 2; ++i) {
        int c = (w * 2 + i) * 64 + lane;
        int kg = c >> 7, r = c & 127;
        pAhi[i] = (const char*)Ahi + (size_t)(row0 + r) * ldaB + kg * 16;
        if (ASPLIT) pAlo[i] = (const char*)Alo + (size_t)(row0 + r) * ldaB + kg * 16;
        pBhi[i] = (const char*)Bthi + (size_t)(col0 + r) * ldbB + kg * 16;
        pBlo[i] = (const char*)Btlo + (size_t)(col0 + r) * ldbB + kg * 16;
        ldsoff[i] = (w * 2 + i) * 512;
    }
    const int kgf = lane >> 4, r15 = lane & 15;

    auto STAGE = [&](int buf, int ks) {
        size_t kb = (size_t)ks * 64;
        unsigned bo = buf ? STG : 0u;
#pragma unroll
        for (int i = 0; i < 2; ++i) {
            gload16(pAhi[i] + kb, lds + bo + 0 + ldsoff[i]);
            if (ASPLIT) gload16(pAlo[i] + kb, lds + bo + 4096 + ldsoff[i]);
            gload16(pBhi[i] + kb, lds + bo + OFF_BH + ldsoff[i]);
            gload16(pBlo[i] + kb, lds + bo + OFF_BL + ldsoff[i]);
        }
    };

    STAGE(0, 0);
    asm volatile("s_waitcnt vmcnt(0)" ::: "memory");
    __syncthreads();
    int cur = 0;

    for (int ks = 0; ks < ksteps; ++ks) {
        if (ks + 1 < ksteps) STAGE(cur ^ 1, ks + 1);   // prefetch flies during MFMA
        const ushort_t* lb = lds + (cur ? STG : 0u);
        bf16x8 ah[4], al[4], bh[4], bl[4];
#pragma unroll
        for (int i = 0; i < 4; ++i) {
            int ra = wr * 64 + i * 16 + r15;
            int rb = wc * 64 + i * 16 + r15;
            ah[i] = *(const bf16x8*)(lb + 0 + kgf * 1024 + ra * 8);
            if (ASPLIT) al[i] = *(const bf16x8*)(lb + 4096 + kgf * 1024 + ra * 8);
            bh[i] = *(const bf16x8*)(lb + OFF_BH + kgf * 1024 + rb * 8);
            bl[i] = *(const bf16x8*)(lb + OFF_BL + kgf * 1024 + rb * 8);
        }
#pragma unroll
        for (int i = 0; i < 4; ++i)
#pragma unroll
            for (int j = 0; j < 4; ++j) {
                acc[i][j] = __builtin_amdgcn_mfma_f32_16x16x32_bf16(ah[i], bh[j], acc[i][j], 0, 0, 0);
                acc[i][j] = __builtin_amdgcn_mfma_f32_16x16x32_bf16(ah[i], bl[j], acc[i][j], 0, 0, 0);
                if (ASPLIT)
                    acc[i][j] = __builtin_amdgcn_mfma_f32_16x16x32_bf16(al[i], bh[j], acc[i][j], 0, 0, 0);
            }
        asm volatile("s_waitcnt vmcnt(0)" ::: "memory");
        __syncthreads();
        cur ^= 1;
    }

    const int g4 = lane >> 4;
#pragma unroll
    for (int i = 0; i < 4; ++i)
#pragma unroll
        for (int j = 0; j < 4; ++j) {
            int c = col0 + wc * 64 + j * 16 + r15;
#pragma unroll
            for (int reg = 0; reg < 4; ++reg) {
                int r = row0 + wr * 64 + i * 16 + g4 * 4 + reg;
                if (r < M) {
                    float v = (c < Nreal) ? acc[i][j][reg] : 0.f;
                    Cb[(size_t)r * ldcs + c] = f2bf(v);
                }
            }
        }
}

// ---------------- attention logits from bf16 h0 ----------------

__global__ void k_att(const ushort_t* __restrict__ h0b,
                      const float* __restrict__ att_src, const float* __restrict__ att_dst,
                      float* __restrict__ as_, float* __restrict__ ad_) {
    int id = blockIdx.x * blockDim.x + threadIdx.x;
    if (id >= NN * HH) return;
    int n = id / HH, h = id % HH;
    const ushort_t* row = h0b + (size_t)n * KP + h * FF;
    const float* ws = att_src + h * FF;
    const float* wd = att_dst + h * FF;
    float as = 0.f, ad = 0.f;
    for (int f = 0; f < FF; f += 2) {
        unsigned qq = *(const unsigned*)(row + f);
        float v0 = bf2f((ushort_t)(qq & 0xffffu));
        float v1 = bf2f((ushort_t)(qq >> 16));
        as += v0 * ws[f] + v1 * ws[f + 1];
        ad += v0 * wd[f] + v1 * wd[f + 1];
    }
    as_[id] = as;
    ad_[id] = ad;
}

// ---------------- GAT aggregation: wave-PAIR per node (feature split), bf16 gathers ----------------
// half 0: k in [0,512) U [1024,1152) (lanes<16); half 1: k in [512,1024).
// Both waves redundantly compute per-edge softmax weights (lanes 0..9) — no cross-wave comm.
// softmax WITHOUT max-subtraction (shift-invariant; logits are O(1)).

template <int NU, int HASB>
__device__ __forceinline__ void gat_grp(
    int eg, int end, int lane, float my_ad,
    const int* __restrict__ csr, const float* __restrict__ as_,
    const ushort_t* __restrict__ h0b,
    int kbA, int hAA, int hBA, int crA,
    int kbB, int hAB, int hBB, int crB,
    float& den, float* accA, float* accB) {
    int s[NU]; float ex[NU];
#pragma unroll
    for (int u = 0; u < NU; ++u) {
        int idx = eg + u; if (idx > end - 1) idx = end - 1;   // clamp (weight zeroed below)
        s[u] = csr[idx];
    }
#pragma unroll
    for (int u = 0; u < NU; ++u) {
        float e = 0.f;
        if (lane < HH) {
            float t = as_[s[u] * HH + lane] + my_ad;
            t = (t >= 0.f) ? t : 0.2f * t;
            e = __expf(t);
            if (eg + u >= end) e = 0.f;
        }
        ex[u] = e;
        den += e;
    }
    bf16x8 qv[NU];
#pragma unroll
    for (int u = 0; u < NU; ++u) qv[u] = *(const bf16x8*)(h0b + (size_t)s[u] * KP + kbA);
#pragma unroll
    for (int u = 0; u < NU; ++u) {
        float wA = __shfl(ex[u], hAA, 64), wB = __shfl(ex[u], hBA, 64);
#pragma unroll
        for (int e = 0; e < 8; ++e)
            accA[e] += ((e >= crA) ? wB : wA) * bf2f((ushort_t)qv[u][e]);
    }
    if (HASB && lane < 16) {
#pragma unroll
        for (int u = 0; u < NU; ++u) qv[u] = *(const bf16x8*)(h0b + (size_t)s[u] * KP + kbB);
#pragma unroll
        for (int u = 0; u < NU; ++u) {
            float wA = __shfl(ex[u], hAB, 64), wB = __shfl(ex[u], hBB, 64);
#pragma unroll
            for (int e = 0; e < 8; ++e)
                accB[e] += ((e >= crB) ? wB : wA) * bf2f((ushort_t)qv[u][e]);
        }
    }
}

__global__ __launch_bounds__(256) void gat_agg(
    const ushort_t* __restrict__ h0b,
    const float* __restrict__ as_, const float* __restrict__ ad_,
    const int* __restrict__ offs, const int* __restrict__ csr,
    const float* __restrict__ bias,
    ushort_t* __restrict__ outb) {
    int lane = threadIdx.x & 63;
    int wid = threadIdx.x >> 6;
    int n = blockIdx.x * 2 + (wid >> 1);   // 2 nodes per block, wave-pair per node
    int half = wid & 1;
    if (n >= NN) return;
    int beg = offs[n], end = offs[n + 1];
    float my_ad = (lane < HH) ? ad_[n * HH + lane] : 0.f;

    // column groups for this wave
    const int kbA = (half ? 512 : 0) + 8 * lane;
    const int kbB = 1024 + 8 * lane;                 // only half==0, lanes<16
    int hAA = min(kbA / FF, HH - 1), hBA = min(hAA + 1, HH - 1);
    int crA = (kbA / FF + 1) * FF - kbA;
    int hAB = min(kbB / FF, HH - 1), hBB = min(hAB + 1, HH - 1);
    int crB = (kbB / FF + 1) * FF - kbB;

    float den = 0.f;
    float accA[8] = {}, accB[8] = {};

    int eg = beg;
    if (half == 0) {
        for (; eg + 8 <= end; eg += 8)
            gat_grp<8, 1>(eg, end, lane, my_ad, csr, as_, h0b,
                          kbA, hAA, hBA, crA, kbB, hAB, hBB, crB, den, accA, accB);
        for (; eg < end; eg += 4)
            gat_grp<4, 1>(eg, end, lane, my_ad, csr, as_, h0b,
                          kbA, hAA, hBA, crA, kbB, hAB, hBB, crB, den, accA, accB);
    } else {
        for (; eg + 8 <= end; eg += 8)
            gat_grp<8, 0>(eg, end, lane, my_ad, csr, as_, h0b,
                          kbA, hAA, hBA, crA, kbB, hAB, hBB, crB, den, accA, accB);
        for (; eg < end; eg += 4)
            gat_grp<4, 0>(eg, end, lane, my_ad, csr, as_, h0b,
                          kbA, hAA, hBA, crA, kbB, hAB, hBB, crB, den, accA, accB);
    }

    // write-out: alpha = acc/den, + bias, lrelu -> bf16 single plane
    {
        bf16x8 vb;
#pragma unroll
        for (int e = 0; e < 8; ++e) {
            int k = kbA + e;
            float d = __shfl(den, (e >= crA) ? hBA : hAA, 64);
            float v = accA[e] / d + bias[k];
            v = (v >= 0.f) ? v : 0.01f * v;
            vb[e] = (short)f2bf(v);
        }
        *(bf16x8*)(outb + (size_t)n * KP + kbA) = vb;
    }
    if (half == 0 && lane < 16) {
        bf16x8 vb;
#pragma unroll
        for (int e = 0; e < 8; ++e) {
            int k = kbB + e;
            float v = 0.f;
            if (k < HFD) {
                float d = __shfl(den, (e >= crB) ? hBB : hAB, 64);
                v = accB[e] / d + bias[k];
                v = (v >= 0.f) ? v : 0.01f * v;
            } else {
                (void)__shfl(den, hAB, 64);   // keep shfl uniform within branch
            }
            vb[e] = (short)f2bf(v);
        }
        *(bf16x8*)(outb + (size_t)n * KP + kbB) = vb;
    }
}

// ---------------- GCN aggregation: wave-PAIR per node (feature split), bf16 gathers ----------------

template <int NU, int HASB>
__device__ __forceinline__ void gcn_grp(
    int eg, int end, int lane, float di,
    const int* __restrict__ csr, const float* __restrict__ dinv,
    const ushort_t* __restrict__ h2b, int kbA, int kbB,
    float* accA, float* accB) {
    int s[NU]; float w[NU];
#pragma unroll
    for (int u = 0; u < NU; ++u) {
        int idx = eg + u; if (idx > end - 1) idx = end - 1;
        s[u] = csr[idx];
    }
#pragma unroll
    for (int u = 0; u < NU; ++u) {
        float ww = dinv[s[u]] * di;
        w[u] = (eg + u < end) ? ww : 0.f;
    }
    bf16x8 qv[NU];
#pragma unroll
    for (int u = 0; u < NU; ++u) qv[u] = *(const bf16x8*)(h2b + (size_t)s[u] * KP + kbA);
#pragma unroll
    for (int u = 0; u < NU; ++u)
#pragma unroll
        for (int e = 0; e < 8; ++e) accA[e] += w[u] * bf2f((ushort_t)qv[u][e]);
    if (HASB && lane < 16) {
#pragma unroll
        for (int u = 0; u < NU; ++u) qv[u] = *(const bf16x8*)(h2b + (size_t)s[u] * KP + kbB);
#pragma unroll
        for (int u = 0; u < NU; ++u)
#pragma unroll
            for (int e = 0; e < 8; ++e) accB[e] += w[u] * bf2f((ushort_t)qv[u][e]);
    }
}

__global__ __launch_bounds__(256) void gcn_agg(
    const ushort_t* __restrict__ h2b, const int* __restrict__ offs, const int* __restrict__ csr,
    const float* __restrict__ dinv, const float* __restrict__ bias, float* __restrict__ out) {
    int lane = threadIdx.x & 63;
    int wid = threadIdx.x >> 6;
    int n = blockIdx.x * 2 + (wid >> 1);
    int half = wid & 1;
    if (n >= NN) return;
    int beg = offs[n], end = offs[n + 1];
    float di = dinv[n];
    const int kbA = (half ? 512 : 0) + 8 * lane;
    const int kbB = 1024 + 8 * lane;
    float accA[8] = {}, accB[8] = {};

    int eg = beg;
    if (half == 0) {
        for (; eg + 8 <= end; eg += 8)
            gcn_grp<8, 1>(eg, end, lane, di, csr, dinv, h2b, kbA, kbB, accA, accB);
        for (; eg < end; eg += 4)
            gcn_grp<4, 1>(eg, end, lane, di, csr, dinv, h2b, kbA, kbB, accA, accB);
    } else {
        for (; eg + 8 <= end; eg += 8)
            gcn_grp<8, 0>(eg, end, lane, di, csr, dinv, h2b, kbA, kbB, accA, accB);
        for (; eg < end; eg += 4)
            gcn_grp<4, 0>(eg, end, lane, di, csr, dinv, h2b, kbA, kbB, accA, accB);
    }

    {
        float4 o1, o2;
        float v;
        v = accA[0] + bias[kbA + 0]; o1.x = (v >= 0.f) ? v : 0.01f * v;
        v = accA[1] + bias[kbA + 1]; o1.y = (v >= 0.f) ? v : 0.01f * v;
        v = accA[2] + bias[kbA + 2]; o1.z = (v >= 0.f) ? v : 0.01f * v;
        v = accA[3] + bias[kbA + 3]; o1.w = (v >= 0.f) ? v : 0.01f * v;
        v = accA[4] + bias[kbA + 4]; o2.x = (v >= 0.f) ? v : 0.01f * v;
        v = accA[5] + bias[kbA + 5]; o2.y = (v >= 0.f) ? v : 0.01f * v;
        v = accA[6] + bias[kbA + 6]; o2.z = (v >= 0.f) ? v : 0.01f * v;
        v = accA[7] + bias[kbA + 7]; o2.w = (v >= 0.f) ? v : 0.01f * v;
        *(float4*)(out + (size_t)n * HFD + kbA) = o1;
        *(float4*)(out + (size_t)n * HFD + kbA + 4) = o2;
    }
    if (half == 0 && lane < 16) {
#pragma unroll
        for (int e = 0; e < 8; ++e) {
            int k = kbB + e;
            if (k < HFD) {
                float v = accB[e] + bias[k];
                out[(size_t)n * HFD + k] = (v >= 0.f) ? v : 0.01f * v;
            }
        }
    }
}

// ---------------- graph pooling (max + mean), float4 ----------------

__global__ void k_pool(const float* __restrict__ hfeat, const int* __restrict__ gs,
                       const int* __restrict__ ge, float* __restrict__ gout) {
    int g = blockIdx.x;
    if (threadIdx.x >= 57) return;
    int m = blockIdx.y * 57 + threadIdx.x;
    int s = gs[g], e = ge[g];
    int cnt = e - s;
    float4 mx = make_float4(-1e30f, -1e30f, -1e30f, -1e30f);
    float4 sm = make_float4(0.f, 0.f, 0.f, 0.f);
    for (int r = s; r < e; ++r) {
        float4 v = *(const float4*)(hfeat + (size_t)r * HFD + 4 * m);
        mx.x = fmaxf(mx.x, v.x); mx.y = fmaxf(mx.y, v.y);
        mx.z = fmaxf(mx.z, v.z); mx.w = fmaxf(mx.w, v.w);
        sm.x += v.x; sm.y += v.y; sm.z += v.z; sm.w += v.w;
    }
    float4 mean;
    if (cnt <= 0) {
        mx = make_float4(0.f, 0.f, 0.f, 0.f);
        mean = make_float4(0.f, 0.f, 0.f, 0.f);
    } else {
        float inv = 1.f / (float)cnt;
        mean = make_float4(sm.x * inv, sm.y * inv, sm.z * inv, sm.w * inv);
    }
    *(float4*)(gout + (size_t)g * (2 * HFD) + 4 * m) = mx;
    *(float4*)(gout + (size_t)g * (2 * HFD) + HFD + 4 * m) = mean;
}

// ---------------- fcg1 split-K (kt loop MUST stay rolled — round-3 spill regression) ----------------

__global__ __launch_bounds__(256) void k_fcg1_part(
    const float* __restrict__ A, const float* __restrict__ B, float* __restrict__ part) {
    __shared__ float As[16][64 + 4];
    __shared__ float Bs[16][64 + 4];
    int tid = threadIdx.x;
    int tx = tid & 15, ty = tid >> 4;
    int row0 = blockIdx.y * 64, col0 = blockIdx.x * 64;
    int kbeg = blockIdx.z * F1KC;
    float acc[4][4] = {};
#pragma unroll 1
    for (int kt = 0; kt < F1KC / 16; ++kt) {
        int kk = kbeg + kt * 16;
#pragma unroll
        for (int l = 0; l < 4; ++l) {
            int idx = tid + 256 * l;
            int m = idx >> 4, k = idx & 15;
            int gr = row0 + m, gk = kk + k;
            As[k][m] = (gk < F1K) ? A[(size_t)gr * F1K + gk] : 0.f;
        }
#pragma unroll
        for (int l = 0; l < 4; ++l) {
            int idx = tid + 256 * l;
            int nn = idx & 63, k = idx >> 6;
            int gc = col0 + nn, gk = kk + k;
            Bs[k][nn] = (gc < 1000 && gk < F1K) ? B[(size_t)gk * 1000 + gc] : 0.f;
        }
        __syncthreads();
#pragma unroll
        for (int k = 0; k < 16; ++k) {
            float4 av = *(const float4*)&As[k][ty * 4];
            float4 bv = *(const float4*)&Bs[k][tx * 4];
            float a[4] = {av.x, av.y, av.z, av.w};
            float b[4] = {bv.x, bv.y, bv.z, bv.w};
#pragma unroll
            for (int i = 0; i < 4; ++i)
#pragma unroll
                for (int j = 0; j < 4; ++j) acc[i][j] += a[i] * b[j];
        }
        __syncthreads();
    }
    float* pc = part + (size_t)blockIdx.z * GG * 1000;
#pragma unroll
    for (int i = 0; i < 4; ++i) {
        int r = row0 + ty * 4 + i;
#pragma unroll
        for (int j = 0; j < 4; ++j) {
            int c = col0 + tx * 4 + j;
            if (c < 1000) pc[(size_t)r * 1000 + c] = acc[i][j];
        }
    }
}

__global__ void k_fcg1_red(const float* __restrict__ part, const float* __restrict__ bias,
                           float* __restrict__ out) {
    int idx = blockIdx.x * 256 + threadIdx.x;
    if (idx >= GG * 1000) return;
    float s = 0.f;
#pragma unroll
    for (int k = 0; k < F1KS; ++k) s += part[(size_t)k * GG * 1000 + idx];
    int n = idx % 1000;
    float v = s + bias[n];
    out[idx] = (v >= 0.f) ? v : 0.01f * v;
}

// ---------------- fcg2 ----------------

__global__ __launch_bounds__(256) void k_fcg2(const float* __restrict__ in, const float* __restrict__ W,
                                              const float* __restrict__ b, float* __restrict__ out) {
    __shared__ float part[4][64];
    int g = blockIdx.x;
    int o = threadIdx.x & 63, p = threadIdx.x >> 6;
    const float* row = in + (size_t)g * 1000;
    float acc = 0.f;
    for (int k = p * 250; k < (p + 1) * 250; ++k) acc += row[k] * W[k * 64 + o];
    part[p][o] = acc;
    __syncthreads();
    if (p == 0) out[(size_t)g * 64 + o] = part[0][o] + part[1][o] + part[2][o] + part[3][o] + b[o];
}

// ---------------- final head ----------------

__global__ __launch_bounds__(256) void k_final(
    const float* __restrict__ b1, const float* __restrict__ b2, const float* __restrict__ target,
    const float* __restrict__ fcxtW, const float* __restrict__ fcxtb,
    const float* __restrict__ fc1W, const float* __restrict__ fc1b,
    const float* __restrict__ fc2W, const float* __restrict__ fc2b,
    const float* __restrict__ outW, const float* __restrict__ outb,
    float* __restrict__ out) {
    __shared__ float xc[256];
    __shared__ float xt2[128];
    __shared__ float y1[128];
    __shared__ float y2[32];
    int g = blockIdx.x, t = threadIdx.x;
    if (t < 64) xc[t] = b1[(size_t)g * 64 + t];
    else if (t < 128) xc[t] = b2[(size_t)g * 64 + (t - 64)];
    {
        int c = t & 127, p = t >> 7;
        float acc = 0.f;
        const float* trow = target + (size_t)g * 1000;
        for (int k = p * 500; k < (p + 1) * 500; ++k) acc += trow[k] * fcxtW[k * 128 + c];
        if (p == 1) xt2[c] = acc;
        __syncthreads();
        if (p == 0) xc[128 + c] = acc + xt2[c] + fcxtb[c];
    }
    __syncthreads();
    if (t < 128) {
        float acc = 0.f;
        for (int k = 0; k < 256; ++k) acc += xc[k] * fc1W[k * 128 + t];
        acc += fc1b[t];
        y1[t] = (acc >= 0.f) ? acc : 0.01f * acc;
    }
    __syncthreads();
    if (t < 32) {
        float acc = 0.f;
        for (int k = 0; k < 128; ++k) acc += y1[k] * fc2W[k * 32 + t];
        acc += fc2b[t];
        y2[t] = (acc >= 0.f) ? acc : 0.01f * acc;
    }
    __syncthreads();
    if (t == 0) {
        float acc = 0.f;
        for (int k = 0; k < 32; ++k) acc += y2[k] * outW[k];
        out[g] = acc + outb[0];
    }
}

// ---------------- host launch ----------------

extern "C" void kernel_launch(void* const* d_in, const int* in_sizes, int n_in,
                              void* d_out, int out_size, void* d_ws, size_t ws_size,
                              hipStream_t stream) {
    (void)in_sizes; (void)n_in; (void)out_size; (void)ws_size;

    size_t off = 0;
    auto alloc = [&](size_t bytes) -> void* {
        void* p = (char*)d_ws + off;
        off += (bytes + 255) & ~(size_t)255;
        return p;
    };
    char* regionA = (char*)alloc((size_t)2 * NN * KP * 2);
    char* regionB = (char*)alloc((size_t)2 * NN * KP * 2);
    ushort_t* Bthi = (ushort_t*)alloc((size_t)KP * KP * 2);
    ushort_t* Btlo = (ushort_t*)alloc((size_t)KP * KP * 2);
    float* a_s    = (float*)alloc((size_t)NN * HH * 4);
    float* a_d    = (float*)alloc((size_t)NN * HH * 4);
    int*   deg    = (int*)alloc((size_t)NN * 4);
    int*   offs   = (int*)alloc((size_t)(NN + 1) * 4);
    int*   cursor = (int*)alloc((size_t)NN * 4);
    int*   csr    = (int*)alloc((size_t)EPRIME * 4);
    float* dinv   = (float*)alloc((size_t)NN * 4);
    int*   gstart = (int*)alloc((size_t)GG * 4);
    int*   gend   = (int*)alloc((size_t)GG * 4);
    int*   bsum   = (int*)alloc((size_t)128 * 4);
    float* gpool  = (float*)alloc((size_t)GG * 2 * HFD * 4);
    float* fc1out = (float*)alloc((size_t)GG * 1000 * 4);
    float* bout   = (float*)alloc((size_t)2 * GG * 64 * 4);

    // overlays
    ushort_t* h0b  = (ushort_t*)regionA;                     // bf16 [NN][KP], zero-padded
    ushort_t* h2b  = (ushort_t*)regionA;                     // after h0b dead (post gat_agg)
    float*    f1part = (float*)regionA;                      // after h2b dead (post gcn_agg)
    ushort_t* xhi  = (ushort_t*)regionB;
    ushort_t* xlo  = (ushort_t*)regionB + (size_t)NN * 128;
    ushort_t* h1b  = (ushort_t*)regionB;                     // bf16 [NN][KP], after x is dead
    float*    hgcn = (float*)regionB;                        // after h1 is dead

    const float* target = (const float*)d_in[6];
    const int NRB = cdiv(NN, 128);        // 157 row blocks
    const int NCB = KP / 128;             // 9 col blocks

    for (int b = 0; b < 2; ++b) {
        const float* x     = (const float*)d_in[b ? 3 : 0];
        const int*   ei    = (const int*)d_in[b ? 4 : 1];
        const int*   batch = (const int*)d_in[b ? 5 : 2];
        int pb = 7 + b * 10;
        const float* gatW    = (const float*)d_in[pb + 0];
        const float* att_src = (const float*)d_in[pb + 1];
        const float* att_dst = (const float*)d_in[pb + 2];
        const float* gatb    = (const float*)d_in[pb + 3];
        const float* gcnW    = (const float*)d_in[pb + 4];
        const float* gcnb    = (const float*)d_in[pb + 5];
        const float* f1W     = (const float*)d_in[pb + 6];
        const float* f1b     = (const float*)d_in[pb + 7];
        const float* f2W     = (const float*)d_in[pb + 8];
        const float* f2b     = (const float*)d_in[pb + 9];

        // CSR
        hipLaunchKernelGGL(k_init, dim3(cdiv(NN, 256)), dim3(256), 0, stream, deg, gstart, gend);
        hipLaunchKernelGGL(k_count, dim3(cdiv(EE, 256)), dim3(256), 0, stream, ei, deg);
        hipLaunchKernelGGL(k_scan1, dim3(NSCB), dim3(256), 0, stream, deg, offs, bsum);
        hipLaunchKernelGGL(k_scan2, dim3(1), dim3(128), 0, stream, bsum);
        hipLaunchKernelGGL(k_scan3prep, dim3(NSCB), dim3(256), 0, stream,
                           offs, bsum, cursor, deg, dinv, batch, gstart, gend);
        hipLaunchKernelGGL(k_fill, dim3(cdiv(EPRIME, 256)), dim3(256), 0, stream, ei, cursor, csr);

        // x -> split (regionB), gatW -> transpose split
        hipLaunchKernelGGL(k_split_x, dim3(cdiv(NN * 128, 256)), dim3(256), 0, stream, x, xhi, xlo);
        hipLaunchKernelGGL(k_tsplitT, dim3(128 / 64, KP / 64), dim3(256), 0, stream,
                           gatW, FF, HFD, 128, Bthi, Btlo);

        // h0 = x @ gatW -> bf16 (regionA). ksteps=4 (Kpad=128), split A
        hipLaunchKernelGGL((mfma_gemm<1>), dim3(NRB * NCB), dim3(256), 0, stream,
                           xhi, xlo, Bthi, Btlo, 128, 128, NN, HFD, 4, NCB, h0b, KP);

        // attention logits
        hipLaunchKernelGGL(k_att, dim3(cdiv(NN * HH, 256)), dim3(256), 0, stream,
                           h0b, att_src, att_dst, a_s, a_d);

        // GAT aggregate -> h1 bf16 single plane (regionB), wave-pair per node
        hipLaunchKernelGGL(gat_agg, dim3(cdiv(NN, 2)), dim3(256), 0, stream,
                           h0b, a_s, a_d, offs, csr, gatb, h1b);

        // gcnW -> transpose split
        hipLaunchKernelGGL(k_tsplitT, dim3(KP / 64, KP / 64), dim3(256), 0, stream,
                           gcnW, HFD, HFD, KP, Bthi, Btlo);

        // h2 = h1 @ gcnW -> bf16 (regionA). ksteps=36, A bf16-only (3 planes, 2 MFMA terms)
        hipLaunchKernelGGL((mfma_gemm<0>), dim3(NRB * NCB), dim3(256), 0, stream,
                           h1b, (const ushort_t*)nullptr, Bthi, Btlo, KP, KP, NN, HFD, KP / 32, NCB,
                           h2b, KP);

        // GCN aggregate -> hgcn fp32 (regionB), wave-pair per node
        hipLaunchKernelGGL(gcn_agg, dim3(cdiv(NN, 2)), dim3(256), 0, stream,
                           h2b, offs, csr, dinv, gcnb, hgcn);

        // pooling
        hipLaunchKernelGGL(k_pool, dim3(GG, 5), dim3(64), 0, stream, hgcn, gstart, gend, gpool);

        // fcg1 split-K
        hipLaunchKernelGGL(k_fcg1_part, dim3(16, 2, F1KS), dim3(256), 0, stream,
                           gpool, f1W, f1part);
        hipLaunchKernelGGL(k_fcg1_red, dim3(cdiv(GG * 1000, 256)), dim3(256), 0, stream,
                           f1part, f1b, fc1out);

        // fcg2
        hipLaunchKernelGGL(k_fcg2, dim3(GG), dim3(256), 0, stream,
                           fc1out, f2W, f2b, bout + (size_t)b * GG * 64);
    }

    hipLaunchKernelGGL(k_final, dim3(GG), dim3(256), 0, stream,
                       bout, bout + (size_t)GG * 64, target,
                       (const float*)d_in[27], (const float*)d_in[28],
                       (const float*)d_in[29], (const float*)d_in[30],
                       (const float*)d_in[31], (const float*)d_in[32],
                       (const float*)d_in[33], (const float*)d_in[34],
                       (float*)d_out);
}

// Round 13
// 1278.564 us; speedup vs baseline: 1.2772x; 1.1093x over previous
//
#include <hip/hip_runtime.h>
#include <cstddef>
#include <cstdint>

#define NN 20000
#define EE 160000
#define EPRIME 180000   // EE + NN (self loops)
#define GG 128
#define FF 114
#define HH 10
#define HFD 1140        // FF*HH
#define KP 1152         // padded feature dim (36*32, 9*128)
#define F1K 2280        // fcg1 K
#define F1KS 18         // split-K chunks
#define F1KC 128        // chunk size
#define NSCB 79         // scan blocks = cdiv(NN,256)

typedef unsigned short ushort_t;
typedef __attribute__((ext_vector_type(8))) short bf16x8;
typedef __attribute__((ext_vector_type(4))) float f32x4;

static inline int cdiv(int a, int b) { return (a + b - 1) / b; }

// ---------------- bf16 helpers ----------------

__device__ __forceinline__ ushort_t f2bf(float v) {
    union { float f; unsigned u; } c; c.f = v;
    unsigned u = c.u;
    unsigned r = (u + 0x7fffu + ((u >> 16) & 1u)) >> 16;   // RNE
    return (ushort_t)r;
}
__device__ __forceinline__ float bf2f(ushort_t h) {
    union { unsigned u; float f; } c; c.u = ((unsigned)h) << 16;
    return c.f;
}

__device__ __forceinline__ void gload16(const void* g, const ushort_t* l) {
    __builtin_amdgcn_global_load_lds(
        (const __attribute__((address_space(1))) unsigned int*)g,
        (__attribute__((address_space(3))) unsigned int*)l, 16, 0, 0);
}

// ---------------- CSR construction ----------------

__global__ void k_init(int* __restrict__ deg, int* __restrict__ gstart, int* __restrict__ gend) {
    int i = blockIdx.x * blockDim.x + threadIdx.x;
    if (i < NN) deg[i] = 1;               // self loop
    if (i < GG) { gstart[i] = NN; gend[i] = 0; }
}

__global__ void k_count(const int* __restrict__ ei, int* __restrict__ deg) {
    int i = blockIdx.x * blockDim.x + threadIdx.x;
    if (i < EE) atomicAdd(&deg[ei[EE + i]], 1);
}

// hierarchical scan: per-block inclusive + block totals
__global__ void k_scan1(const int* __restrict__ deg, int* __restrict__ offs, int* __restrict__ bsum) {
    __shared__ int tmp[256];
    int b = blockIdx.x, tid = threadIdx.x;
    int i = b * 256 + tid;
    int v = (i < NN) ? deg[i] : 0;
    tmp[tid] = v;
    __syncthreads();
#pragma unroll
    for (int off = 1; off < 256; off <<= 1) {
        int t = (tid >= off) ? tmp[tid - off] : 0;
        __syncthreads();
        tmp[tid] += t;
        __syncthreads();
    }
    if (i < NN) offs[i + 1] = tmp[tid];
    if (tid == 255) bsum[b] = tmp[255];
}

__global__ void k_scan2(int* __restrict__ bsum) {
    __shared__ int tmp[128];
    int tid = threadIdx.x;
    int v = (tid < NSCB) ? bsum[tid] : 0;
    tmp[tid] = v;
    __syncthreads();
#pragma unroll
    for (int off = 1; off < 128; off <<= 1) {
        int t = (tid >= off) ? tmp[tid - off] : 0;
        __syncthreads();
        tmp[tid] += t;
        __syncthreads();
    }
    if (tid < NSCB) bsum[tid] = tmp[tid] - v;   // exclusive prefix
}

// fused: finalize offs + cursor + dinv + graph ranges
__global__ void k_scan3prep(int* __restrict__ offs, const int* __restrict__ bsum,
                            int* __restrict__ cursor, const int* __restrict__ deg,
                            float* __restrict__ dinv, const int* __restrict__ batch,
                            int* __restrict__ gstart, int* __restrict__ gend) {
    int i = blockIdx.x * 256 + threadIdx.x;
    if (i < NN) {
        int o = offs[i + 1] + bsum[i >> 8];   // inclusive prefix up to i
        offs[i + 1] = o;
        cursor[i] = o - deg[i];               // exclusive prefix = offs[i]
        dinv[i] = rsqrtf((float)deg[i]);
        int b = batch[i];
        atomicMin(&gstart[b], i);
        atomicMax(&gend[b], i + 1);
    }
    if (i == 0) offs[0] = 0;
}

__global__ void k_fill(const int* __restrict__ ei, int* __restrict__ cursor, int* __restrict__ csr) {
    int i = blockIdx.x * blockDim.x + threadIdx.x;
    if (i < EPRIME) {
        int s, d;
        if (i < EE) { s = ei[i]; d = ei[EE + i]; }
        else        { s = i - EE; d = s; }
        int pos = atomicAdd(&cursor[d], 1);
        csr[pos] = s;
    }
}

// ---------------- bf16 conversions ----------------

// x [NN,FF] fp32 -> xb [NN,128] bf16 (zero pad)
__global__ void k_split_x(const float* __restrict__ x, ushort_t* __restrict__ xb) {
    int idx = blockIdx.x * 256 + threadIdx.x;
    if (idx >= NN * 128) return;
    int n = idx >> 7, k = idx & 127;
    float v = (k < FF) ? x[(size_t)n * FF + k] : 0.f;
    xb[idx] = f2bf(v);
}

// W [K,Nc] -> T[n][k]=W[k][n], bf16 single plane, zero pad. Coalesced via LDS 64x64 tiles.
__global__ __launch_bounds__(256) void k_tbf(const float* __restrict__ W, int K, int Nc,
                                             int Kpad, ushort_t* __restrict__ T) {
    __shared__ float tile[64][65];
    int kb = blockIdx.x * 64;
    int nb = blockIdx.y * 64;
    int c = threadIdx.x & 63, r4 = threadIdx.x >> 6;
#pragma unroll
    for (int rr = 0; rr < 16; ++rr) {
        int r = r4 * 16 + rr;
        int gk = kb + r, gn = nb + c;
        tile[r][c] = (gk < K && gn < Nc) ? W[(size_t)gk * Nc + gn] : 0.f;
    }
    __syncthreads();
#pragma unroll
    for (int rr = 0; rr < 16; ++rr) {
        int r = r4 * 16 + rr;
        int gn = nb + r, gk = kb + c;
        T[(size_t)gn * Kpad + gk] = f2bf(tile[c][r]);
    }
}

// ---------------- full-bf16 MFMA GEMM, 2-phase dbuf + ROW-MAJOR XCD swizzle ----------------
// A bf16 [M][lda], Bt bf16 [Npad][ldb] (row n = col n of W). 1 MFMA term, 2 staged planes
// (16KB/stage, 32KB LDS -> 5 blocks/CU). B panel (2.65MB total) is XCD-L2-resident.
// Output: bf16 single plane [M][ldcs], zero-padded cols >= Nreal.

__global__ __launch_bounds__(256) void mfma_gemm(
    const ushort_t* __restrict__ A, const ushort_t* __restrict__ Bt,
    int lda, int ldb, int M, int Nreal, int ksteps, int ncb,
    ushort_t* __restrict__ Cb, int ldcs) {
    __shared__ __align__(16) ushort_t lds[2 * 8192];   // [buf][plane A|B][4 kg][128 row][8]
    const int tid = threadIdx.x;
    const int lane = tid & 63;
    const int w = tid >> 6;
    const int wr = w >> 1, wc = w & 1;

    // bijective XCD-chunked swizzle (m204), row-major block decode
    int nwg = gridDim.x;
    int q = nwg >> 3, r8 = nwg & 7;
    int xcd = blockIdx.x & 7, sidx = blockIdx.x >> 3;
    int wg = (xcd < r8 ? xcd * (q + 1) : r8 * (q + 1) + (xcd - r8) * q) + sidx;
    int brow = wg / ncb, bcol = wg - brow * ncb;

    int row0 = brow * 128; if (row0 > M - 128) row0 = M - 128;   // overlap trick, idempotent writes
    const int col0 = bcol * 128;

    f32x4 acc[4][4];
#pragma unroll
    for (int i = 0; i < 4; ++i)
#pragma unroll
        for (int j = 0; j < 4; ++j) acc[i][j] = (f32x4){0.f, 0.f, 0.f, 0.f};

    const size_t ldaB = (size_t)lda * 2, ldbB = (size_t)ldb * 2;
    const char* pA[2]; const char* pB[2];
    unsigned ldsoff[2];
#pragma unroll
    for (int i = 0; i < 2; ++i) {
        int c = (w * 2 + i) * 64 + lane;
        int kg = c >> 7, r = c & 127;
        pA[i] = (const char*)A + (size_t)(row0 + r) * ldaB + kg * 16;
        pB[i] = (const char*)Bt + (size_t)(col0 + r) * ldbB + kg * 16;
        ldsoff[i] = (w * 2 + i) * 512;
    }
    const int kgf = lane >> 4, r15 = lane & 15;

    auto STAGE = [&](int buf, int ks) {
        size_t kb = (size_t)ks * 64;
        unsigned bo = buf ? 8192u : 0u;
#pragma unroll
        for (int i = 0; i < 2; ++i) {
            gload16(pA[i] + kb, lds + bo + 0 + ldsoff[i]);
            gload16(pB[i] + kb, lds + bo + 4096 + ldsoff[i]);
        }
    };

    STAGE(0, 0);
    asm volatile("s_waitcnt vmcnt(0)" ::: "memory");
    __syncthreads();
    int cur = 0;

    for (int ks = 0; ks < ksteps; ++ks) {
        if (ks + 1 < ksteps) STAGE(cur ^ 1, ks + 1);   // prefetch flies during MFMA
        const ushort_t* lb = lds + (cur ? 8192u : 0u);
        bf16x8 ah[4], bh[4];
#pragma unroll
        for (int i = 0; i < 4; ++i) {
            int ra = wr * 64 + i * 16 + r15;
            int rb = wc * 64 + i * 16 + r15;
            ah[i] = *(const bf16x8*)(lb + 0 + kgf * 1024 + ra * 8);
            bh[i] = *(const bf16x8*)(lb + 4096 + kgf * 1024 + rb * 8);
        }
#pragma unroll
        for (int i = 0; i < 4; ++i)
#pragma unroll
            for (int j = 0; j < 4; ++j)
                acc[i][j] = __builtin_amdgcn_mfma_f32_16x16x32_bf16(ah[i], bh[j], acc[i][j], 0, 0, 0);
        asm volatile("s_waitcnt vmcnt(0)" ::: "memory");
        __syncthreads();
        cur ^= 1;
    }

    const int g4 = lane >> 4;
#pragma unroll
    for (int i = 0; i < 4; ++i)
#pragma unroll
        for (int j = 0; j < 4; ++j) {
            int c = col0 + wc * 64 + j * 16 + r15;
#pragma unroll
            for (int reg = 0; reg < 4; ++reg) {
                int r = row0 + wr * 64 + i * 16 + g4 * 4 + reg;
                if (r < M) {
                    float v = (c < Nreal) ? acc[i][j][reg] : 0.f;
                    Cb[(size_t)r * ldcs + c] = f2bf(v);
                }
            }
        }
}

// ---------------- attention logits from bf16 h0 ----------------

__global__ void k_att(const ushort_t* __restrict__ h0b,
                      const float* __restrict__ att_src, const float* __restrict__ att_dst,
                      float* __restrict__ as_, float* __restrict__ ad_) {
    int id = blockIdx.x * blockDim.x + threadIdx.x;
    if (id >= NN * HH) return;
    int n = id / HH, h = id % HH;
    const ushort_t* row = h0b + (size_t)n * KP + h * FF;
    const float* ws = att_src + h * FF;
    const float* wd = att_dst + h * FF;
    float as = 0.f, ad = 0.f;
    for (int f = 0; f < FF; f += 2) {
        unsigned qq = *(const unsigned*)(row + f);
        float v0 = bf2f((ushort_t)(qq & 0xffffu));
        float v1 = bf2f((ushort_t)(qq >> 16));
        as += v0 * ws[f] + v1 * ws[f + 1];
        ad += v0 * wd[f] + v1 * wd[f + 1];
    }
    as_[id] = as;
    ad_[id] = ad;
}

// ---------------- GAT aggregation: wave-PAIR per node (feature split), bf16 gathers ----------------
// half 0: k in [0,512) U [1024,1152) (lanes<16); half 1: k in [512,1024).
// softmax WITHOUT max-subtraction (shift-invariant; logits are O(1)).

template <int NU, int HASB>
__device__ __forceinline__ void gat_grp(
    int eg, int end, int lane, float my_ad,
    const int* __restrict__ csr, const float* __restrict__ as_,
    const ushort_t* __restrict__ h0b,
    int kbA, int hAA, int hBA, int crA,
    int kbB, int hAB, int hBB, int crB,
    float& den, float* accA, float* accB) {
    int s[NU]; float ex[NU];
#pragma unroll
    for (int u = 0; u < NU; ++u) {
        int idx = eg + u; if (idx > end - 1) idx = end - 1;   // clamp (weight zeroed below)
        s[u] = csr[idx];
    }
#pragma unroll
    for (int u = 0; u < NU; ++u) {
        float e = 0.f;
        if (lane < HH) {
            float t = as_[s[u] * HH + lane] + my_ad;
            t = (t >= 0.f) ? t : 0.2f * t;
            e = __expf(t);
            if (eg + u >= end) e = 0.f;
        }
        ex[u] = e;
        den += e;
    }
    bf16x8 qv[NU];
#pragma unroll
    for (int u = 0; u < NU; ++u) qv[u] = *(const bf16x8*)(h0b + (size_t)s[u] * KP + kbA);
#pragma unroll
    for (int u = 0; u < NU; ++u) {
        float wA = __shfl(ex[u], hAA, 64), wB = __shfl(ex[u], hBA, 64);
#pragma unroll
        for (int e = 0; e < 8; ++e)
            accA[e] += ((e >= crA) ? wB : wA) * bf2f((ushort_t)qv[u][e]);
    }
    if (HASB && lane < 16) {
#pragma unroll
        for (int u = 0; u < NU; ++u) qv[u] = *(const bf16x8*)(h0b + (size_t)s[u] * KP + kbB);
#pragma unroll
        for (int u = 0; u < NU; ++u) {
            float wA = __shfl(ex[u], hAB, 64), wB = __shfl(ex[u], hBB, 64);
#pragma unroll
            for (int e = 0; e < 8; ++e)
                accB[e] += ((e >= crB) ? wB : wA) * bf2f((ushort_t)qv[u][e]);
        }
    }
}

__global__ __launch_bounds__(256) void gat_agg(
    const ushort_t* __restrict__ h0b,
    const float* __restrict__ as_, const float* __restrict__ ad_,
    const int* __restrict__ offs, const int* __restrict__ csr,
    const float* __restrict__ bias,
    ushort_t* __restrict__ outb) {
    int lane = threadIdx.x & 63;
    int wid = threadIdx.x >> 6;
    int n = blockIdx.x * 2 + (wid >> 1);   // 2 nodes per block, wave-pair per node
    int half = wid & 1;
    if (n >= NN) return;
    int beg = offs[n], end = offs[n + 1];
    float my_ad = (lane < HH) ? ad_[n * HH + lane] : 0.f;

    // column groups for this wave
    const int kbA = (half ? 512 : 0) + 8 * lane;
    const int kbB = 1024 + 8 * lane;                 // only half==0, lanes<16
    int hAA = min(kbA / FF, HH - 1), hBA = min(hAA + 1, HH - 1);
    int crA = (kbA / FF + 1) * FF - kbA;
    int hAB = min(kbB / FF, HH - 1), hBB = min(hAB + 1, HH - 1);
    int crB = (kbB / FF + 1) * FF - kbB;

    float den = 0.f;
    float accA[8] = {}, accB[8] = {};

    int eg = beg;
    if (half == 0) {
        for (; eg + 8 <= end; eg += 8)
            gat_grp<8, 1>(eg, end, lane, my_ad, csr, as_, h0b,
                          kbA, hAA, hBA, crA, kbB, hAB, hBB, crB, den, accA, accB);
        for (; eg < end; eg += 4)
            gat_grp<4, 1>(eg, end, lane, my_ad, csr, as_, h0b,
                          kbA, hAA, hBA, crA, kbB, hAB, hBB, crB, den, accA, accB);
    } else {
        for (; eg + 8 <= end; eg += 8)
            gat_grp<8, 0>(eg, end, lane, my_ad, csr, as_, h0b,
                          kbA, hAA, hBA, crA, kbB, hAB, hBB, crB, den, accA, accB);
        for (; eg < end; eg += 4)
            gat_grp<4, 0>(eg, end, lane, my_ad, csr, as_, h0b,
                          kbA, hAA, hBA, crA, kbB, hAB, hBB, crB, den, accA, accB);
    }

    // write-out: alpha = acc/den, + bias, lrelu -> bf16 single plane
    {
        bf16x8 vb;
#pragma unroll
        for (int e = 0; e < 8; ++e) {
            int k = kbA + e;
            float d = __shfl(den, (e >= crA) ? hBA : hAA, 64);
            float v = accA[e] / d + bias[k];
            v = (v >= 0.f) ? v : 0.01f * v;
            vb[e] = (short)f2bf(v);
        }
        *(bf16x8*)(outb + (size_t)n * KP + kbA) = vb;
    }
    if (half == 0 && lane < 16) {
        bf16x8 vb;
#pragma unroll
        for (int e = 0; e < 8; ++e) {
            int k = kbB + e;
            float v = 0.f;
            if (k < HFD) {
                float d = __shfl(den, (e >= crB) ? hBB : hAB, 64);
                v = accB[e] / d + bias[k];
                v = (v >= 0.f) ? v : 0.01f * v;
            } else {
                (void)__shfl(den, hAB, 64);   // keep shfl uniform within branch
            }
            vb[e] = (short)f2bf(v);
        }
        *(bf16x8*)(outb + (size_t)n * KP + kbB) = vb;
    }
}

// ---------------- GCN aggregation: wave-PAIR per node (feature split), bf16 gathers ----------------

template <int NU, int HASB>
__device__ __forceinline__ void gcn_grp(
    int eg, int end, int lane, float di,
    const int* __restrict__ csr, const float* __restrict__ dinv,
    const ushort_t* __restrict__ h2b, int kbA, int kbB,
    float* accA, float* accB) {
    int s[NU]; float w[NU];
#pragma unroll
    for (int u = 0; u < NU; ++u) {
        int idx = eg + u; if (idx > end - 1) idx = end - 1;
        s[u] = csr[idx];
    }
#pragma unroll
    for (int u = 0; u < NU; ++u) {
        float ww = dinv[s[u]] * di;
        w[u] = (eg + u < end) ? ww : 0.f;
    }
    bf16x8 qv[NU];
#pragma unroll
    for (int u = 0; u < NU; ++u) qv[u] = *(const bf16x8*)(h2b + (size_t)s[u] * KP + kbA);
#pragma unroll
    for (int u = 0; u < NU; ++u)
#pragma unroll
        for (int e = 0; e < 8; ++e) accA[e] += w[u] * bf2f((ushort_t)qv[u][e]);
    if (HASB && lane < 16) {
#pragma unroll
        for (int u = 0; u < NU; ++u) qv[u] = *(const bf16x8*)(h2b + (size_t)s[u] * KP + kbB);
#pragma unroll
        for (int u = 0; u < NU; ++u)
#pragma unroll
            for (int e = 0; e < 8; ++e) accB[e] += w[u] * bf2f((ushort_t)qv[u][e]);
    }
}

__global__ __launch_bounds__(256) void gcn_agg(
    const ushort_t* __restrict__ h2b, const int* __restrict__ offs, const int* __restrict__ csr,
    const float* __restrict__ dinv, const float* __restrict__ bias, float* __restrict__ out) {
    int lane = threadIdx.x & 63;
    int wid = threadIdx.x >> 6;
    int n = blockIdx.x * 2 + (wid >> 1);
    int half = wid & 1;
    if (n >= NN) return;
    int beg = offs[n], end = offs[n + 1];
    float di = dinv[n];
    const int kbA = (half ? 512 : 0) + 8 * lane;
    const int kbB = 1024 + 8 * lane;
    float accA[8] = {}, accB[8] = {};

    int eg = beg;
    if (half == 0) {
        for (; eg + 8 <= end; eg += 8)
            gcn_grp<8, 1>(eg, end, lane, di, csr, dinv, h2b, kbA, kbB, accA, accB);
        for (; eg < end; eg += 4)
            gcn_grp<4, 1>(eg, end, lane, di, csr, dinv, h2b, kbA, kbB, accA, accB);
    } else {
        for (; eg + 8 <= end; eg += 8)
            gcn_grp<8, 0>(eg, end, lane, di, csr, dinv, h2b, kbA, kbB, accA, accB);
        for (; eg < end; eg += 4)
            gcn_grp<4, 0>(eg, end, lane, di, csr, dinv, h2b, kbA, kbB, accA, accB);
    }

    {
        float4 o1, o2;
        float v;
        v = accA[0] + bias[kbA + 0]; o1.x = (v >= 0.f) ? v : 0.01f * v;
        v = accA[1] + bias[kbA + 1]; o1.y = (v >= 0.f) ? v : 0.01f * v;
        v = accA[2] + bias[kbA + 2]; o1.z = (v >= 0.f) ? v : 0.01f * v;
        v = accA[3] + bias[kbA + 3]; o1.w = (v >= 0.f) ? v : 0.01f * v;
        v = accA[4] + bias[kbA + 4]; o2.x = (v >= 0.f) ? v : 0.01f * v;
        v = accA[5] + bias[kbA + 5]; o2.y = (v >= 0.f) ? v : 0.01f * v;
        v = accA[6] + bias[kbA + 6]; o2.z = (v >= 0.f) ? v : 0.01f * v;
        v = accA[7] + bias[kbA + 7]; o2.w = (v >= 0.f) ? v : 0.01f * v;
        *(float4*)(out + (size_t)n * HFD + kbA) = o1;
        *(float4*)(out + (size_t)n * HFD + kbA + 4) = o2;
    }
    if (half == 0 && lane < 16) {
#pragma unroll
        for (int e = 0; e < 8; ++e) {
            int k = kbB + e;
            if (k < HFD) {
                float v = accB[e] + bias[k];
                out[(size_t)n * HFD + k] = (v >= 0.f) ? v : 0.01f * v;
            }
        }
    }
}

// ---------------- graph pooling (max + mean), float4 ----------------

__global__ void k_pool(const float* __restrict__ hfeat, const int* __restrict__ gs,
                       const int* __restrict__ ge, float* __restrict__ gout) {
    int g = blockIdx.x;
    if (threadIdx.x >= 57) return;
    int m = blockIdx.y * 57 + threadIdx.x;
    int s = gs[g], e = ge[g];
    int cnt = e - s;
    float4 mx = make_float4(-1e30f, -1e30f, -1e30f, -1e30f);
    float4 sm = make_float4(0.f, 0.f, 0.f, 0.f);
    for (int r = s; r < e; ++r) {
        float4 v = *(const float4*)(hfeat + (size_t)r * HFD + 4 * m);
        mx.x = fmaxf(mx.x, v.x); mx.y = fmaxf(mx.y, v.y);
        mx.z = fmaxf(mx.z, v.z); mx.w = fmaxf(mx.w, v.w);
        sm.x += v.x; sm.y += v.y; sm.z += v.z; sm.w += v.w;
    }
    float4 mean;
    if (cnt <= 0) {
        mx = make_float4(0.f, 0.f, 0.f, 0.f);
        mean = make_float4(0.f, 0.f, 0.f, 0.f);
    } else {
        float inv = 1.f / (float)cnt;
        mean = make_float4(sm.x * inv, sm.y * inv, sm.z * inv, sm.w * inv);
    }
    *(float4*)(gout + (size_t)g * (2 * HFD) + 4 * m) = mx;
    *(float4*)(gout + (size_t)g * (2 * HFD) + HFD + 4 * m) = mean;
}

// ---------------- fcg1 split-K (kt loop MUST stay rolled — round-3 spill regression) ----------------

__global__ __launch_bounds__(256) void k_fcg1_part(
    const float* __restrict__ A, const float* __restrict__ B, float* __restrict__ part) {
    __shared__ float As[16][64 + 4];
    __shared__ float Bs[16][64 + 4];
    int tid = threadIdx.x;
    int tx = tid & 15, ty = tid >> 4;
    int row0 = blockIdx.y * 64, col0 = blockIdx.x * 64;
    int kbeg = blockIdx.z * F1KC;
    float acc[4][4] = {};
#pragma unroll 1
    for (int kt = 0; kt < F1KC / 16; ++kt) {
        int kk = kbeg + kt * 16;
#pragma unroll
        for (int l = 0; l < 4; ++l) {
            int idx = tid + 256 * l;
            int m = idx >> 4, k = idx & 15;
            int gr = row0 + m, gk = kk + k;
            As[k][m] = (gk < F1K) ? A[(size_t)gr * F1K + gk] : 0.f;
        }
#pragma unroll
        for (int l = 0; l < 4; ++l) {
            int idx = tid + 256 * l;
            int nn = idx & 63, k = idx >> 6;
            int gc = col0 + nn, gk = kk + k;
            Bs[k][nn] = (gc < 1000 && gk < F1K) ? B[(size_t)gk * 1000 + gc] : 0.f;
        }
        __syncthreads();
#pragma unroll
        for (int k = 0; k < 16; ++k) {
            float4 av = *(const float4*)&As[k][ty * 4];
            float4 bv = *(const float4*)&Bs[k][tx * 4];
            float a[4] = {av.x, av.y, av.z, av.w};
            float b[4] = {bv.x, bv.y, bv.z, bv.w};
#pragma unroll
            for (int i = 0; i < 4; ++i)
#pragma unroll
                for (int j = 0; j < 4; ++j) acc[i][j] += a[i] * b[j];
        }
        __syncthreads();
    }
    float* pc = part + (size_t)blockIdx.z * GG * 1000;
#pragma unroll
    for (int i = 0; i < 4; ++i) {
        int r = row0 + ty * 4 + i;
#pragma unroll
        for (int j = 0; j < 4; ++j) {
            int c = col0 + tx * 4 + j;
            if (c < 1000) pc[(size_t)r * 1000 + c] = acc[i][j];
        }
    }
}

__global__ void k_fcg1_red(const float* __restrict__ part, const float* __restrict__ bias,
                           float* __restrict__ out) {
    int idx = blockIdx.x * 256 + threadIdx.x;
    if (idx >= GG * 1000) return;
    float s = 0.f;
#pragma unroll
    for (int k = 0; k < F1KS; ++k) s += part[(size_t)k * GG * 1000 + idx];
    int n = idx % 1000;
    float v = s + bias[n];
    out[idx] = (v >= 0.f) ? v : 0.01f * v;
}

// ---------------- fcg2 ----------------

__global__ __launch_bounds__(256) void k_fcg2(const float* __restrict__ in, const float* __restrict__ W,
                                              const float* __restrict__ b, float* __restrict__ out) {
    __shared__ float part[4][64];
    int g = blockIdx.x;
    int o = threadIdx.x & 63, p = threadIdx.x >> 6;
    const float* row = in + (size_t)g * 1000;
    float acc = 0.f;
    for (int k = p * 250; k < (p + 1) * 250; ++k) acc += row[k] * W[k * 64 + o];
    part[p][o] = acc;
    __syncthreads();
    if (p == 0) out[(size_t)g * 64 + o] = part[0][o] + part[1][o] + part[2][o] + part[3][o] + b[o];
}

// ---------------- final head ----------------

__global__ __launch_bounds__(256) void k_final(
    const float* __restrict__ b1, const float* __restrict__ b2, const float* __restrict__ target,
    const float* __restrict__ fcxtW, const float* __restrict__ fcxtb,
    const float* __restrict__ fc1W, const float* __restrict__ fc1b,
    const float* __restrict__ fc2W, const float* __restrict__ fc2b,
    const float* __restrict__ outW, const float* __restrict__ outb,
    float* __restrict__ out) {
    __shared__ float xc[256];
    __shared__ float xt2[128];
    __shared__ float y1[128];
    __shared__ float y2[32];
    int g = blockIdx.x, t = threadIdx.x;
    if (t < 64) xc[t] = b1[(size_t)g * 64 + t];
    else if (t < 128) xc[t] = b2[(size_t)g * 64 + (t - 64)];
    {
        int c = t & 127, p = t >> 7;
        float acc = 0.f;
        const float* trow = target + (size_t)g * 1000;
        for (int k = p * 500; k < (p + 1) * 500; ++k) acc += trow[k] * fcxtW[k * 128 + c];
        if (p == 1) xt2[c] = acc;
        __syncthreads();
        if (p == 0) xc[128 + c] = acc + xt2[c] + fcxtb[c];
    }
    __syncthreads();
    if (t < 128) {
        float acc = 0.f;
        for (int k = 0; k < 256; ++k) acc += xc[k] * fc1W[k * 128 + t];
        acc += fc1b[t];
        y1[t] = (acc >= 0.f) ? acc : 0.01f * acc;
    }
    __syncthreads();
    if (t < 32) {
        float acc = 0.f;
        for (int k = 0; k < 128; ++k) acc += y1[k] * fc2W[k * 32 + t];
        acc += fc2b[t];
        y2[t] = (acc >= 0.f) ? acc : 0.01f * acc;
    }
    __syncthreads();
    if (t == 0) {
        float acc = 0.f;
        for (int k = 0; k < 32; ++k) acc += y2[k] * outW[k];
        out[g] = acc + outb[0];
    }
}

// ---------------- host launch ----------------

extern "C" void kernel_launch(void* const* d_in, const int* in_sizes, int n_in,
                              void* d_out, int out_size, void* d_ws, size_t ws_size,
                              hipStream_t stream) {
    (void)in_sizes; (void)n_in; (void)out_size; (void)ws_size;

    size_t off = 0;
    auto alloc = [&](size_t bytes) -> void* {
        void* p = (char*)d_ws + off;
        off += (bytes + 255) & ~(size_t)255;
        return p;
    };
    char* regionA = (char*)alloc((size_t)2 * NN * KP * 2);
    char* regionB = (char*)alloc((size_t)2 * NN * KP * 2);
    ushort_t* Bt   = (ushort_t*)alloc((size_t)KP * KP * 2);
    float* a_s    = (float*)alloc((size_t)NN * HH * 4);
    float* a_d    = (float*)alloc((size_t)NN * HH * 4);
    int*   deg    = (int*)alloc((size_t)NN * 4);
    int*   offs   = (int*)alloc((size_t)(NN + 1) * 4);
    int*   cursor = (int*)alloc((size_t)NN * 4);
    int*   csr    = (int*)alloc((size_t)EPRIME * 4);
    float* dinv   = (float*)alloc((size_t)NN * 4);
    int*   gstart = (int*)alloc((size_t)GG * 4);
    int*   gend   = (int*)alloc((size_t)GG * 4);
    int*   bsum   = (int*)alloc((size_t)128 * 4);
    float* gpool  = (float*)alloc((size_t)GG * 2 * HFD * 4);
    float* fc1out = (float*)alloc((size_t)GG * 1000 * 4);
    float* bout   = (float*)alloc((size_t)2 * GG * 64 * 4);

    // overlays
    ushort_t* h0b  = (ushort_t*)regionA;                     // bf16 [NN][KP], zero-padded
    ushort_t* h2b  = (ushort_t*)regionA;                     // after h0b dead (post gat_agg)
    float*    f1part = (float*)regionA;                      // after h2b dead (post gcn_agg)
    ushort_t* xb   = (ushort_t*)regionB;                     // bf16 [NN][128]
    ushort_t* h1b  = (ushort_t*)regionB;                     // bf16 [NN][KP], after x is dead
    float*    hgcn = (float*)regionB;                        // after h1 is dead

    const float* target = (const float*)d_in[6];
    const int NRB = cdiv(NN, 128);        // 157 row blocks
    const int NCB = KP / 128;             // 9 col blocks

    for (int b = 0; b < 2; ++b) {
        const float* x     = (const float*)d_in[b ? 3 : 0];
        const int*   ei    = (const int*)d_in[b ? 4 : 1];
        const int*   batch = (const int*)d_in[b ? 5 : 2];
        int pb = 7 + b * 10;
        const float* gatW    = (const float*)d_in[pb + 0];
        const float* att_src = (const float*)d_in[pb + 1];
        const float* att_dst = (const float*)d_in[pb + 2];
        const float* gatb    = (const float*)d_in[pb + 3];
        const float* gcnW    = (const float*)d_in[pb + 4];
        const float* gcnb    = (const float*)d_in[pb + 5];
        const float* f1W     = (const float*)d_in[pb + 6];
        const float* f1b     = (const float*)d_in[pb + 7];
        const float* f2W     = (const float*)d_in[pb + 8];
        const float* f2b     = (const float*)d_in[pb + 9];

        // CSR
        hipLaunchKernelGGL(k_init, dim3(cdiv(NN, 256)), dim3(256), 0, stream, deg, gstart, gend);
        hipLaunchKernelGGL(k_count, dim3(cdiv(EE, 256)), dim3(256), 0, stream, ei, deg);
        hipLaunchKernelGGL(k_scan1, dim3(NSCB), dim3(256), 0, stream, deg, offs, bsum);
        hipLaunchKernelGGL(k_scan2, dim3(1), dim3(128), 0, stream, bsum);
        hipLaunchKernelGGL(k_scan3prep, dim3(NSCB), dim3(256), 0, stream,
                           offs, bsum, cursor, deg, dinv, batch, gstart, gend);
        hipLaunchKernelGGL(k_fill, dim3(cdiv(EPRIME, 256)), dim3(256), 0, stream, ei, cursor, csr);

        // x -> bf16 (regionB), gatW -> transpose bf16
        hipLaunchKernelGGL(k_split_x, dim3(cdiv(NN * 128, 256)), dim3(256), 0, stream, x, xb);
        hipLaunchKernelGGL(k_tbf, dim3(128 / 64, KP / 64), dim3(256), 0, stream,
                           gatW, FF, HFD, 128, Bt);

        // h0 = x @ gatW -> bf16 (regionA). ksteps=4 (Kpad=128)
        hipLaunchKernelGGL(mfma_gemm, dim3(NRB * NCB), dim3(256), 0, stream,
                           xb, Bt, 128, 128, NN, HFD, 4, NCB, h0b, KP);

        // attention logits
        hipLaunchKernelGGL(k_att, dim3(cdiv(NN * HH, 256)), dim3(256), 0, stream,
                           h0b, att_src, att_dst, a_s, a_d);

        // GAT aggregate -> h1 bf16 single plane (regionB), wave-pair per node
        hipLaunchKernelGGL(gat_agg, dim3(cdiv(NN, 2)), dim3(256), 0, stream,
                           h0b, a_s, a_d, offs, csr, gatb, h1b);

        // gcnW -> transpose bf16
        hipLaunchKernelGGL(k_tbf, dim3(KP / 64, KP / 64), dim3(256), 0, stream,
                           gcnW, HFD, HFD, KP, Bt);

        // h2 = h1 @ gcnW -> bf16 (regionA). ksteps=36
        hipLaunchKernelGGL(mfma_gemm, dim3(NRB * NCB), dim3(256), 0, stream,
                           h1b, Bt, KP, KP, NN, HFD, KP / 32, NCB, h2b, KP);

        // GCN aggregate -> hgcn fp32 (regionB), wave-pair per node
        hipLaunchKernelGGL(gcn_agg, dim3(cdiv(NN, 2)), dim3(256), 0, stream,
                           h2b, offs, csr, dinv, gcnb, hgcn);

        // pooling
        hipLaunchKernelGGL(k_pool, dim3(GG, 5), dim3(64), 0, stream, hgcn, gstart, gend, gpool);

        // fcg1 split-K
        hipLaunchKernelGGL(k_fcg1_part, dim3(16, 2, F1KS), dim3(256), 0, stream,
                           gpool, f1W, f1part);
        hipLaunchKernelGGL(k_fcg1_red, dim3(cdiv(GG * 1000, 256)), dim3(256), 0, stream,
                           f1part, f1b, fc1out);

        // fcg2
        hipLaunchKernelGGL(k_fcg2, dim3(GG), dim3(256), 0, stream,
                           fc1out, f2W, f2b, bout + (size_t)b * GG * 64);
    }

    hipLaunchKernelGGL(k_final, dim3(GG), dim3(256), 0, stream,
                       bout, bout + (size_t)GG * 64, target,
                       (const float*)d_in[27], (const float*)d_in[28],
                       (const float*)d_in[29], (const float*)d_in[30],
                       (const float*)d_in[31], (const float*)d_in[32],
                       (const float*)d_in[33], (const float*)d_in[34],
                       (float*)d_out);
}

// Round 14
// 1098.736 us; speedup vs baseline: 1.4862x; 1.1637x over previous
//
#include <hip/hip_runtime.h>
#include <cstddef>
#include <cstdint>

#define NN 20000
#define EE 160000
#define EPRIME 180000   // EE + NN (self loops)
#define GG 128
#define FF 114
#define HH 10
#define HFD 1140        // FF*HH
#define KP 1152         // padded feature dim
#define F1K 2280        // fcg1 K
#define F1KS 18         // split-K chunks
#define F1KC 128        // chunk size
#define NSCB 79         // scan blocks = cdiv(NN,256)

typedef unsigned short ushort_t;
typedef __attribute__((ext_vector_type(8))) short bf16x8;
typedef __attribute__((ext_vector_type(4))) float f32x4;

static constexpr size_t REL = (size_t)NN * KP;   // per-branch region stride (ushorts)

static inline int cdiv(int a, int b) { return (a + b - 1) / b; }

// ---------------- bf16 helpers ----------------

__device__ __forceinline__ ushort_t f2bf(float v) {
    union { float f; unsigned u; } c; c.f = v;
    unsigned u = c.u;
    unsigned r = (u + 0x7fffu + ((u >> 16) & 1u)) >> 16;   // RNE
    return (ushort_t)r;
}
__device__ __forceinline__ float bf2f(ushort_t h) {
    union { unsigned u; float f; } c; c.u = ((unsigned)h) << 16;
    return c.f;
}

__device__ __forceinline__ void gload16(const void* g, const ushort_t* l) {
    __builtin_amdgcn_global_load_lds(
        (const __attribute__((address_space(1))) unsigned int*)g,
        (__attribute__((address_space(3))) unsigned int*)l, 16, 0, 0);
}

// ---------------- CSR construction (branch = blockIdx.y) ----------------

__global__ void k_init(int* __restrict__ deg, int* __restrict__ gstart, int* __restrict__ gend) {
    int br = blockIdx.y;
    int i = blockIdx.x * blockDim.x + threadIdx.x;
    if (i < NN) deg[br * NN + i] = 1;               // self loop
    if (i < GG) { gstart[br * GG + i] = NN; gend[br * GG + i] = 0; }
}

__global__ void k_count(const int* __restrict__ ei0, const int* __restrict__ ei1,
                        int* __restrict__ deg) {
    int br = blockIdx.y;
    const int* ei = br ? ei1 : ei0;
    int i = blockIdx.x * blockDim.x + threadIdx.x;
    if (i < EE) atomicAdd(&deg[br * NN + ei[EE + i]], 1);
}

__global__ void k_scan1(const int* __restrict__ deg, int* __restrict__ offs, int* __restrict__ bsum) {
    __shared__ int tmp[256];
    int br = blockIdx.y;
    deg += br * NN; offs += br * (NN + 1); bsum += br * 128;
    int b = blockIdx.x, tid = threadIdx.x;
    int i = b * 256 + tid;
    int v = (i < NN) ? deg[i] : 0;
    tmp[tid] = v;
    __syncthreads();
#pragma unroll
    for (int off = 1; off < 256; off <<= 1) {
        int t = (tid >= off) ? tmp[tid - off] : 0;
        __syncthreads();
        tmp[tid] += t;
        __syncthreads();
    }
    if (i < NN) offs[i + 1] = tmp[tid];
    if (tid == 255) bsum[b] = tmp[255];
}

__global__ void k_scan2(int* __restrict__ bsum) {
    __shared__ int tmp[128];
    bsum += blockIdx.y * 128;
    int tid = threadIdx.x;
    int v = (tid < NSCB) ? bsum[tid] : 0;
    tmp[tid] = v;
    __syncthreads();
#pragma unroll
    for (int off = 1; off < 128; off <<= 1) {
        int t = (tid >= off) ? tmp[tid - off] : 0;
        __syncthreads();
        tmp[tid] += t;
        __syncthreads();
    }
    if (tid < NSCB) bsum[tid] = tmp[tid] - v;   // exclusive prefix
}

__global__ void k_scan3prep(int* __restrict__ offs, const int* __restrict__ bsum,
                            int* __restrict__ cursor, const int* __restrict__ deg,
                            float* __restrict__ dinv,
                            const int* __restrict__ batch0, const int* __restrict__ batch1,
                            int* __restrict__ gstart, int* __restrict__ gend) {
    int br = blockIdx.y;
    offs += br * (NN + 1); bsum += br * 128; cursor += br * NN;
    deg += br * NN; dinv += br * NN;
    const int* batch = br ? batch1 : batch0;
    gstart += br * GG; gend += br * GG;
    int i = blockIdx.x * 256 + threadIdx.x;
    if (i < NN) {
        int o = offs[i + 1] + bsum[i >> 8];
        offs[i + 1] = o;
        cursor[i] = o - deg[i];
        dinv[i] = rsqrtf((float)deg[i]);
        int b = batch[i];
        atomicMin(&gstart[b], i);
        atomicMax(&gend[b], i + 1);
    }
    if (i == 0) offs[0] = 0;
}

__global__ void k_fill(const int* __restrict__ ei0, const int* __restrict__ ei1,
                       int* __restrict__ cursor, int* __restrict__ csr) {
    int br = blockIdx.y;
    const int* ei = br ? ei1 : ei0;
    cursor += br * NN; csr += (size_t)br * EPRIME;
    int i = blockIdx.x * blockDim.x + threadIdx.x;
    if (i < EPRIME) {
        int s, d;
        if (i < EE) { s = ei[i]; d = ei[EE + i]; }
        else        { s = i - EE; d = s; }
        int pos = atomicAdd(&cursor[d], 1);
        csr[pos] = s;
    }
}

// ---------------- bf16 conversions ----------------

__global__ void k_split_x(const float* __restrict__ x0, const float* __restrict__ x1,
                          ushort_t* __restrict__ xb) {
    int br = blockIdx.y;
    const float* x = br ? x1 : x0;
    xb += (size_t)br * REL;
    int idx = blockIdx.x * 256 + threadIdx.x;
    if (idx >= NN * 128) return;
    int n = idx >> 7, k = idx & 127;
    float v = (k < FF) ? x[(size_t)n * FF + k] : 0.f;
    xb[idx] = f2bf(v);
}

// W [K,Nc] -> T[n][k]=W[k][n], bf16, zero pad. branch = blockIdx.z
__global__ __launch_bounds__(256) void k_tbf(const float* __restrict__ W0, const float* __restrict__ W1,
                                             int K, int Nc, int Kpad, ushort_t* __restrict__ T) {
    __shared__ float tile[64][65];
    int br = blockIdx.z;
    const float* W = br ? W1 : W0;
    T += (size_t)br * KP * KP;
    int kb = blockIdx.x * 64;
    int nb = blockIdx.y * 64;
    int c = threadIdx.x & 63, r4 = threadIdx.x >> 6;
#pragma unroll
    for (int rr = 0; rr < 16; ++rr) {
        int r = r4 * 16 + rr;
        int gk = kb + r, gn = nb + c;
        tile[r][c] = (gk < K && gn < Nc) ? W[(size_t)gk * Nc + gn] : 0.f;
    }
    __syncthreads();
#pragma unroll
    for (int rr = 0; rr < 16; ++rr) {
        int r = r4 * 16 + rr;
        int gn = nb + r, gk = kb + c;
        T[(size_t)gn * Kpad + gk] = f2bf(tile[c][r]);
    }
}

// ---------------- full-bf16 MFMA GEMM, 2-phase dbuf + XCD swizzle, batched branches ----------------

__global__ __launch_bounds__(256) void mfma_gemm(
    const ushort_t* __restrict__ Abase, const ushort_t* __restrict__ Btbase,
    int lda, int ldb, int M, int Nreal, int ksteps, int ncb,
    ushort_t* __restrict__ Cbase, int ldcs) {
    __shared__ __align__(16) ushort_t lds[2 * 8192];
    const int br = blockIdx.y;
    const ushort_t* A = Abase + (size_t)br * REL;
    const ushort_t* Bt = Btbase + (size_t)br * KP * KP;
    ushort_t* Cb = Cbase + (size_t)br * REL;

    const int tid = threadIdx.x;
    const int lane = tid & 63;
    const int w = tid >> 6;
    const int wr = w >> 1, wc = w & 1;

    // bijective XCD-chunked swizzle (m204), row-major block decode
    int nwg = gridDim.x;
    int q = nwg >> 3, r8 = nwg & 7;
    int xcd = blockIdx.x & 7, sidx = blockIdx.x >> 3;
    int wg = (xcd < r8 ? xcd * (q + 1) : r8 * (q + 1) + (xcd - r8) * q) + sidx;
    int brow = wg / ncb, bcol = wg - brow * ncb;

    int row0 = brow * 128; if (row0 > M - 128) row0 = M - 128;   // overlap trick
    const int col0 = bcol * 128;

    f32x4 acc[4][4];
#pragma unroll
    for (int i = 0; i < 4; ++i)
#pragma unroll
        for (int j = 0; j < 4; ++j) acc[i][j] = (f32x4){0.f, 0.f, 0.f, 0.f};

    const size_t ldaB = (size_t)lda * 2, ldbB = (size_t)ldb * 2;
    const char* pA[2]; const char* pB[2];
    unsigned ldsoff[2];
#pragma unroll
    for (int i = 0; i < 2; ++i) {
        int c = (w * 2 + i) * 64 + lane;
        int kg = c >> 7, r = c & 127;
        pA[i] = (const char*)A + (size_t)(row0 + r) * ldaB + kg * 16;
        pB[i] = (const char*)Bt + (size_t)(col0 + r) * ldbB + kg * 16;
        ldsoff[i] = (w * 2 + i) * 512;
    }
    const int kgf = lane >> 4, r15 = lane & 15;

    auto STAGE = [&](int buf, int ks) {
        size_t kb = (size_t)ks * 64;
        unsigned bo = buf ? 8192u : 0u;
#pragma unroll
        for (int i = 0; i < 2; ++i) {
            gload16(pA[i] + kb, lds + bo + 0 + ldsoff[i]);
            gload16(pB[i] + kb, lds + bo + 4096 + ldsoff[i]);
        }
    };

    STAGE(0, 0);
    asm volatile("s_waitcnt vmcnt(0)" ::: "memory");
    __syncthreads();
    int cur = 0;

    for (int ks = 0; ks < ksteps; ++ks) {
        if (ks + 1 < ksteps) STAGE(cur ^ 1, ks + 1);
        const ushort_t* lb = lds + (cur ? 8192u : 0u);
        bf16x8 ah[4], bh[4];
#pragma unroll
        for (int i = 0; i < 4; ++i) {
            int ra = wr * 64 + i * 16 + r15;
            int rb = wc * 64 + i * 16 + r15;
            ah[i] = *(const bf16x8*)(lb + 0 + kgf * 1024 + ra * 8);
            bh[i] = *(const bf16x8*)(lb + 4096 + kgf * 1024 + rb * 8);
        }
#pragma unroll
        for (int i = 0; i < 4; ++i)
#pragma unroll
            for (int j = 0; j < 4; ++j)
                acc[i][j] = __builtin_amdgcn_mfma_f32_16x16x32_bf16(ah[i], bh[j], acc[i][j], 0, 0, 0);
        asm volatile("s_waitcnt vmcnt(0)" ::: "memory");
        __syncthreads();
        cur ^= 1;
    }

    const int g4 = lane >> 4;
#pragma unroll
    for (int i = 0; i < 4; ++i)
#pragma unroll
        for (int j = 0; j < 4; ++j) {
            int c = col0 + wc * 64 + j * 16 + r15;
#pragma unroll
            for (int reg = 0; reg < 4; ++reg) {
                int r = row0 + wr * 64 + i * 16 + g4 * 4 + reg;
                if (r < M) {
                    float v = (c < Nreal) ? acc[i][j][reg] : 0.f;
                    Cb[(size_t)r * ldcs + c] = f2bf(v);
                }
            }
        }
}

// ---------------- attention logits ----------------

__global__ void k_att(const ushort_t* __restrict__ h0base,
                      const float* __restrict__ as0, const float* __restrict__ as1,
                      const float* __restrict__ ad0, const float* __restrict__ ad1,
                      float* __restrict__ as_, float* __restrict__ ad_) {
    int br = blockIdx.y;
    const ushort_t* h0b = h0base + (size_t)br * REL;
    const float* att_src = br ? as1 : as0;
    const float* att_dst = br ? ad1 : ad0;
    as_ += (size_t)br * NN * HH; ad_ += (size_t)br * NN * HH;
    int id = blockIdx.x * blockDim.x + threadIdx.x;
    if (id >= NN * HH) return;
    int n = id / HH, h = id % HH;
    const ushort_t* row = h0b + (size_t)n * KP + h * FF;
    const float* ws = att_src + h * FF;
    const float* wd = att_dst + h * FF;
    float as = 0.f, ad = 0.f;
    for (int f = 0; f < FF; f += 2) {
        unsigned qq = *(const unsigned*)(row + f);
        float v0 = bf2f((ushort_t)(qq & 0xffffu));
        float v1 = bf2f((ushort_t)(qq >> 16));
        as += v0 * ws[f] + v1 * ws[f + 1];
        ad += v0 * wd[f] + v1 * wd[f + 1];
    }
    as_[id] = as;
    ad_[id] = ad;
}

// ---------------- GAT aggregation: wave-PAIR per node, bf16 gathers, batched branches ----------------
// softmax WITHOUT max-subtraction (shift-invariant; logits are O(1)).

template <int NU, int HASB>
__device__ __forceinline__ void gat_grp(
    int eg, int end, int lane, float my_ad,
    const int* __restrict__ csr, const float* __restrict__ as_,
    const ushort_t* __restrict__ h0b,
    int kbA, int hAA, int hBA, int crA,
    int kbB, int hAB, int hBB, int crB,
    float& den, float* accA, float* accB) {
    int s[NU]; float ex[NU];
#pragma unroll
    for (int u = 0; u < NU; ++u) {
        int idx = eg + u; if (idx > end - 1) idx = end - 1;   // clamp (weight zeroed below)
        s[u] = csr[idx];
    }
#pragma unroll
    for (int u = 0; u < NU; ++u) {
        float e = 0.f;
        if (lane < HH) {
            float t = as_[s[u] * HH + lane] + my_ad;
            t = (t >= 0.f) ? t : 0.2f * t;
            e = __expf(t);
            if (eg + u >= end) e = 0.f;
        }
        ex[u] = e;
        den += e;
    }
    bf16x8 qv[NU];
#pragma unroll
    for (int u = 0; u < NU; ++u) qv[u] = *(const bf16x8*)(h0b + (size_t)s[u] * KP + kbA);
#pragma unroll
    for (int u = 0; u < NU; ++u) {
        float wA = __shfl(ex[u], hAA, 64), wB = __shfl(ex[u], hBA, 64);
#pragma unroll
        for (int e = 0; e < 8; ++e)
            accA[e] += ((e >= crA) ? wB : wA) * bf2f((ushort_t)qv[u][e]);
    }
    if (HASB && lane < 16) {
#pragma unroll
        for (int u = 0; u < NU; ++u) qv[u] = *(const bf16x8*)(h0b + (size_t)s[u] * KP + kbB);
#pragma unroll
        for (int u = 0; u < NU; ++u) {
            float wA = __shfl(ex[u], hAB, 64), wB = __shfl(ex[u], hBB, 64);
#pragma unroll
            for (int e = 0; e < 8; ++e)
                accB[e] += ((e >= crB) ? wB : wA) * bf2f((ushort_t)qv[u][e]);
        }
    }
}

__global__ __launch_bounds__(256) void gat_agg(
    const ushort_t* __restrict__ h0base,
    const float* __restrict__ as_, const float* __restrict__ ad_,
    const int* __restrict__ offs, const int* __restrict__ csr,
    const float* __restrict__ b0, const float* __restrict__ b1,
    ushort_t* __restrict__ outbase) {
    int br = blockIdx.y;
    const ushort_t* h0b = h0base + (size_t)br * REL;
    as_ += (size_t)br * NN * HH; ad_ += (size_t)br * NN * HH;
    offs += br * (NN + 1); csr += (size_t)br * EPRIME;
    const float* bias = br ? b1 : b0;
    ushort_t* outb = outbase + (size_t)br * REL;

    int lane = threadIdx.x & 63;
    int wid = threadIdx.x >> 6;
    int n = blockIdx.x * 2 + (wid >> 1);
    int half = wid & 1;
    if (n >= NN) return;
    int beg = offs[n], end = offs[n + 1];
    float my_ad = (lane < HH) ? ad_[n * HH + lane] : 0.f;

    const int kbA = (half ? 512 : 0) + 8 * lane;
    const int kbB = 1024 + 8 * lane;                 // only half==0, lanes<16
    int hAA = min(kbA / FF, HH - 1), hBA = min(hAA + 1, HH - 1);
    int crA = (kbA / FF + 1) * FF - kbA;
    int hAB = min(kbB / FF, HH - 1), hBB = min(hAB + 1, HH - 1);
    int crB = (kbB / FF + 1) * FF - kbB;

    float den = 0.f;
    float accA[8] = {}, accB[8] = {};

    int eg = beg;
    if (half == 0) {
        for (; eg + 8 <= end; eg += 8)
            gat_grp<8, 1>(eg, end, lane, my_ad, csr, as_, h0b,
                          kbA, hAA, hBA, crA, kbB, hAB, hBB, crB, den, accA, accB);
        for (; eg < end; eg += 4)
            gat_grp<4, 1>(eg, end, lane, my_ad, csr, as_, h0b,
                          kbA, hAA, hBA, crA, kbB, hAB, hBB, crB, den, accA, accB);
    } else {
        for (; eg + 8 <= end; eg += 8)
            gat_grp<8, 0>(eg, end, lane, my_ad, csr, as_, h0b,
                          kbA, hAA, hBA, crA, kbB, hAB, hBB, crB, den, accA, accB);
        for (; eg < end; eg += 4)
            gat_grp<4, 0>(eg, end, lane, my_ad, csr, as_, h0b,
                          kbA, hAA, hBA, crA, kbB, hAB, hBB, crB, den, accA, accB);
    }

    {
        bf16x8 vb;
#pragma unroll
        for (int e = 0; e < 8; ++e) {
            int k = kbA + e;
            float d = __shfl(den, (e >= crA) ? hBA : hAA, 64);
            float v = accA[e] / d + bias[k];
            v = (v >= 0.f) ? v : 0.01f * v;
            vb[e] = (short)f2bf(v);
        }
        *(bf16x8*)(outb + (size_t)n * KP + kbA) = vb;
    }
    if (half == 0 && lane < 16) {
        bf16x8 vb;
#pragma unroll
        for (int e = 0; e < 8; ++e) {
            int k = kbB + e;
            float v = 0.f;
            if (k < HFD) {
                float d = __shfl(den, (e >= crB) ? hBB : hAB, 64);
                v = accB[e] / d + bias[k];
                v = (v >= 0.f) ? v : 0.01f * v;
            } else {
                (void)__shfl(den, hAB, 64);
            }
            vb[e] = (short)f2bf(v);
        }
        *(bf16x8*)(outb + (size_t)n * KP + kbB) = vb;
    }
}

// ---------------- GCN aggregation: wave-PAIR per node, bf16 in AND out, batched ----------------

template <int NU, int HASB>
__device__ __forceinline__ void gcn_grp(
    int eg, int end, int lane, float di,
    const int* __restrict__ csr, const float* __restrict__ dinv,
    const ushort_t* __restrict__ h2b, int kbA, int kbB,
    float* accA, float* accB) {
    int s[NU]; float w[NU];
#pragma unroll
    for (int u = 0; u < NU; ++u) {
        int idx = eg + u; if (idx > end - 1) idx = end - 1;
        s[u] = csr[idx];
    }
#pragma unroll
    for (int u = 0; u < NU; ++u) {
        float ww = dinv[s[u]] * di;
        w[u] = (eg + u < end) ? ww : 0.f;
    }
    bf16x8 qv[NU];
#pragma unroll
    for (int u = 0; u < NU; ++u) qv[u] = *(const bf16x8*)(h2b + (size_t)s[u] * KP + kbA);
#pragma unroll
    for (int u = 0; u < NU; ++u)
#pragma unroll
        for (int e = 0; e < 8; ++e) accA[e] += w[u] * bf2f((ushort_t)qv[u][e]);
    if (HASB && lane < 16) {
#pragma unroll
        for (int u = 0; u < NU; ++u) qv[u] = *(const bf16x8*)(h2b + (size_t)s[u] * KP + kbB);
#pragma unroll
        for (int u = 0; u < NU; ++u)
#pragma unroll
            for (int e = 0; e < 8; ++e) accB[e] += w[u] * bf2f((ushort_t)qv[u][e]);
    }
}

__global__ __launch_bounds__(256) void gcn_agg(
    const ushort_t* __restrict__ h2base, const int* __restrict__ offs, const int* __restrict__ csr,
    const float* __restrict__ dinv,
    const float* __restrict__ b0, const float* __restrict__ b1,
    ushort_t* __restrict__ outbase) {
    int br = blockIdx.y;
    const ushort_t* h2b = h2base + (size_t)br * REL;
    offs += br * (NN + 1); csr += (size_t)br * EPRIME; dinv += br * NN;
    const float* bias = br ? b1 : b0;
    ushort_t* outb = outbase + (size_t)br * REL;

    int lane = threadIdx.x & 63;
    int wid = threadIdx.x >> 6;
    int n = blockIdx.x * 2 + (wid >> 1);
    int half = wid & 1;
    if (n >= NN) return;
    int beg = offs[n], end = offs[n + 1];
    float di = dinv[n];
    const int kbA = (half ? 512 : 0) + 8 * lane;
    const int kbB = 1024 + 8 * lane;
    float accA[8] = {}, accB[8] = {};

    int eg = beg;
    if (half == 0) {
        for (; eg + 8 <= end; eg += 8)
            gcn_grp<8, 1>(eg, end, lane, di, csr, dinv, h2b, kbA, kbB, accA, accB);
        for (; eg < end; eg += 4)
            gcn_grp<4, 1>(eg, end, lane, di, csr, dinv, h2b, kbA, kbB, accA, accB);
    } else {
        for (; eg + 8 <= end; eg += 8)
            gcn_grp<8, 0>(eg, end, lane, di, csr, dinv, h2b, kbA, kbB, accA, accB);
        for (; eg < end; eg += 4)
            gcn_grp<4, 0>(eg, end, lane, di, csr, dinv, h2b, kbA, kbB, accA, accB);
    }

    {
        bf16x8 vb;
#pragma unroll
        for (int e = 0; e < 8; ++e) {
            float v = accA[e] + bias[kbA + e];
            v = (v >= 0.f) ? v : 0.01f * v;
            vb[e] = (short)f2bf(v);
        }
        *(bf16x8*)(outb + (size_t)n * KP + kbA) = vb;
    }
    if (half == 0 && lane < 16) {
        bf16x8 vb;
#pragma unroll
        for (int e = 0; e < 8; ++e) {
            int k = kbB + e;
            float v = 0.f;
            if (k < HFD) {
                v = accB[e] + bias[k];
                v = (v >= 0.f) ? v : 0.01f * v;
            }
            vb[e] = (short)f2bf(v);
        }
        *(bf16x8*)(outb + (size_t)n * KP + kbB) = vb;
    }
}

// ---------------- graph pooling (max + mean), bf16 input, batched ----------------

__global__ void k_pool(const ushort_t* __restrict__ hbase, const int* __restrict__ gs,
                       const int* __restrict__ ge, float* __restrict__ gpool) {
    int br = blockIdx.z;
    const ushort_t* hfeat = hbase + (size_t)br * REL;   // [NN][KP] bf16
    gs += br * GG; ge += br * GG;
    float* gout = gpool + (size_t)br * GG * 2 * HFD;
    if (threadIdx.x >= 48) return;
    int g = blockIdx.x;
    int mg = blockIdx.y * 48 + threadIdx.x;   // 0..143 (8-col groups)
    int s = gs[g], e = ge[g];
    int cnt = e - s;
    float mx[8], sm[8];
#pragma unroll
    for (int j = 0; j < 8; ++j) { mx[j] = -1e30f; sm[j] = 0.f; }
    for (int r = s; r < e; ++r) {
        bf16x8 q = *(const bf16x8*)(hfeat + (size_t)r * KP + 8 * mg);
#pragma unroll
        for (int j = 0; j < 8; ++j) {
            float v = bf2f((ushort_t)q[j]);
            mx[j] = fmaxf(mx[j], v);
            sm[j] += v;
        }
    }
    float inv = (cnt > 0) ? 1.f / (float)cnt : 0.f;
#pragma unroll
    for (int j = 0; j < 8; ++j) {
        int k = 8 * mg + j;
        if (k < HFD) {
            float m = (cnt > 0) ? mx[j] : 0.f;
            gout[(size_t)g * (2 * HFD) + k] = m;
            gout[(size_t)g * (2 * HFD) + HFD + k] = sm[j] * inv;
        }
    }
}

// ---------------- fcg1 split-K (kt loop MUST stay rolled — round-3 spill regression) ----------------
// blockIdx.y: [0,4) -> br = y>>1, rowblk = y&1

__global__ __launch_bounds__(256) void k_fcg1_part(
    const float* __restrict__ gpool, const float* __restrict__ B0, const float* __restrict__ B1,
    float* __restrict__ p0, float* __restrict__ p1) {
    __shared__ float As[16][64 + 4];
    __shared__ float Bs[16][64 + 4];
    int br = blockIdx.y >> 1, rowblk = blockIdx.y & 1;
    const float* A = gpool + (size_t)br * GG * F1K;
    const float* B = br ? B1 : B0;
    float* part = br ? p1 : p0;
    int tid = threadIdx.x;
    int tx = tid & 15, ty = tid >> 4;
    int row0 = rowblk * 64, col0 = blockIdx.x * 64;
    int kbeg = blockIdx.z * F1KC;
    float acc[4][4] = {};
#pragma unroll 1
    for (int kt = 0; kt < F1KC / 16; ++kt) {
        int kk = kbeg + kt * 16;
#pragma unroll
        for (int l = 0; l < 4; ++l) {
            int idx = tid + 256 * l;
            int m = idx >> 4, k = idx & 15;
            int gr = row0 + m, gk = kk + k;
            As[k][m] = (gk < F1K) ? A[(size_t)gr * F1K + gk] : 0.f;
        }
#pragma unroll
        for (int l = 0; l < 4; ++l) {
            int idx = tid + 256 * l;
            int nn = idx & 63, k = idx >> 6;
            int gc = col0 + nn, gk = kk + k;
            Bs[k][nn] = (gc < 1000 && gk < F1K) ? B[(size_t)gk * 1000 + gc] : 0.f;
        }
        __syncthreads();
#pragma unroll
        for (int k = 0; k < 16; ++k) {
            float4 av = *(const float4*)&As[k][ty * 4];
            float4 bv = *(const float4*)&Bs[k][tx * 4];
            float a[4] = {av.x, av.y, av.z, av.w};
            float b[4] = {bv.x, bv.y, bv.z, bv.w};
#pragma unroll
            for (int i = 0; i < 4; ++i)
#pragma unroll
                for (int j = 0; j < 4; ++j) acc[i][j] += a[i] * b[j];
        }
        __syncthreads();
    }
    float* pc = part + (size_t)blockIdx.z * GG * 1000;
#pragma unroll
    for (int i = 0; i < 4; ++i) {
        int r = row0 + ty * 4 + i;
#pragma unroll
        for (int j = 0; j < 4; ++j) {
            int c = col0 + tx * 4 + j;
            if (c < 1000) pc[(size_t)r * 1000 + c] = acc[i][j];
        }
    }
}

__global__ void k_fcg1_red(const float* __restrict__ p0, const float* __restrict__ p1,
                           const float* __restrict__ b0, const float* __restrict__ b1,
                           float* __restrict__ fc1out) {
    int br = blockIdx.y;
    const float* part = br ? p1 : p0;
    const float* bias = br ? b1 : b0;
    float* out = fc1out + (size_t)br * GG * 1000;
    int idx = blockIdx.x * 256 + threadIdx.x;
    if (idx >= GG * 1000) return;
    float s = 0.f;
#pragma unroll
    for (int k = 0; k < F1KS; ++k) s += part[(size_t)k * GG * 1000 + idx];
    int n = idx % 1000;
    float v = s + bias[n];
    out[idx] = (v >= 0.f) ? v : 0.01f * v;
}

// ---------------- fcg2, batched ----------------

__global__ __launch_bounds__(256) void k_fcg2(const float* __restrict__ fc1out,
                                              const float* __restrict__ W0, const float* __restrict__ W1,
                                              const float* __restrict__ b0, const float* __restrict__ b1,
                                              float* __restrict__ bout) {
    __shared__ float part[4][64];
    int br = blockIdx.y;
    const float* in = fc1out + (size_t)br * GG * 1000;
    const float* W = br ? W1 : W0;
    const float* b = br ? b1 : b0;
    float* out = bout + (size_t)br * GG * 64;
    int g = blockIdx.x;
    int o = threadIdx.x & 63, p = threadIdx.x >> 6;
    const float* row = in + (size_t)g * 1000;
    float acc = 0.f;
    for (int k = p * 250; k < (p + 1) * 250; ++k) acc += row[k] * W[k * 64 + o];
    part[p][o] = acc;
    __syncthreads();
    if (p == 0) out[(size_t)g * 64 + o] = part[0][o] + part[1][o] + part[2][o] + part[3][o] + b[o];
}

// ---------------- final head ----------------

__global__ __launch_bounds__(256) void k_final(
    const float* __restrict__ b1, const float* __restrict__ b2, const float* __restrict__ target,
    const float* __restrict__ fcxtW, const float* __restrict__ fcxtb,
    const float* __restrict__ fc1W, const float* __restrict__ fc1b,
    const float* __restrict__ fc2W, const float* __restrict__ fc2b,
    const float* __restrict__ outW, const float* __restrict__ outb,
    float* __restrict__ out) {
    __shared__ float xc[256];
    __shared__ float xt2[128];
    __shared__ float y1[128];
    __shared__ float y2[32];
    int g = blockIdx.x, t = threadIdx.x;
    if (t < 64) xc[t] = b1[(size_t)g * 64 + t];
    else if (t < 128) xc[t] = b2[(size_t)g * 64 + (t - 64)];
    {
        int c = t & 127, p = t >> 7;
        float acc = 0.f;
        const float* trow = target + (size_t)g * 1000;
        for (int k = p * 500; k < (p + 1) * 500; ++k) acc += trow[k] * fcxtW[k * 128 + c];
        if (p == 1) xt2[c] = acc;
        __syncthreads();
        if (p == 0) xc[128 + c] = acc + xt2[c] + fcxtb[c];
    }
    __syncthreads();
    if (t < 128) {
        float acc = 0.f;
        for (int k = 0; k < 256; ++k) acc += xc[k] * fc1W[k * 128 + t];
        acc += fc1b[t];
        y1[t] = (acc >= 0.f) ? acc : 0.01f * acc;
    }
    __syncthreads();
    if (t < 32) {
        float acc = 0.f;
        for (int k = 0; k < 128; ++k) acc += y1[k] * fc2W[k * 32 + t];
        acc += fc2b[t];
        y2[t] = (acc >= 0.f) ? acc : 0.01f * acc;
    }
    __syncthreads();
    if (t == 0) {
        float acc = 0.f;
        for (int k = 0; k < 32; ++k) acc += y2[k] * outW[k];
        out[g] = acc + outb[0];
    }
}

// ---------------- host launch ----------------

extern "C" void kernel_launch(void* const* d_in, const int* in_sizes, int n_in,
                              void* d_out, int out_size, void* d_ws, size_t ws_size,
                              hipStream_t stream) {
    (void)in_sizes; (void)n_in; (void)out_size; (void)ws_size;

    size_t off = 0;
    auto alloc = [&](size_t bytes) -> void* {
        void* p = (char*)d_ws + off;
        off += (bytes + 255) & ~(size_t)255;
        return p;
    };
    char* brA = (char*)alloc(2 * REL * 2);   // per-branch: h0b -> h2b -> f1part overlays
    char* brB = (char*)alloc(2 * REL * 2);   // per-branch: xb -> h1b -> hgcnb overlays
    ushort_t* Bt = (ushort_t*)alloc(2 * (size_t)KP * KP * 2);
    float* a_s    = (float*)alloc(2 * (size_t)NN * HH * 4);
    float* a_d    = (float*)alloc(2 * (size_t)NN * HH * 4);
    int*   deg    = (int*)alloc(2 * (size_t)NN * 4);
    int*   offs   = (int*)alloc(2 * (size_t)(NN + 1) * 4);
    int*   cursor = (int*)alloc(2 * (size_t)NN * 4);
    int*   csr    = (int*)alloc(2 * (size_t)EPRIME * 4);
    float* dinv   = (float*)alloc(2 * (size_t)NN * 4);
    int*   gstart = (int*)alloc(2 * (size_t)GG * 4);
    int*   gend   = (int*)alloc(2 * (size_t)GG * 4);
    int*   bsum   = (int*)alloc(2 * (size_t)128 * 4);
    float* gpool  = (float*)alloc(2 * (size_t)GG * 2 * HFD * 4);
    float* fc1out = (float*)alloc(2 * (size_t)GG * 1000 * 4);
    float* bout   = (float*)alloc(2 * (size_t)GG * 64 * 4);

    ushort_t* h0b = (ushort_t*)brA;               // + br*REL (overlay: h2b, f1part)
    float* f1p0 = (float*)brA;
    float* f1p1 = (float*)(brA + REL * 2);
    ushort_t* xb  = (ushort_t*)brB;               // + br*REL (overlay: h1b, hgcnb)

    const float* target = (const float*)d_in[6];
    const int NRB = cdiv(NN, 128);        // 157 row blocks
    const int NCB = KP / 128;             // 9 col blocks

    // per-branch input pointers
    const float* x0 = (const float*)d_in[0];
    const float* x1 = (const float*)d_in[3];
    const int* ei0 = (const int*)d_in[1];
    const int* ei1 = (const int*)d_in[4];
    const int* batch0 = (const int*)d_in[2];
    const int* batch1 = (const int*)d_in[5];
    const float *gatW0 = (const float*)d_in[7],  *gatW1 = (const float*)d_in[17];
    const float *asrc0 = (const float*)d_in[8],  *asrc1 = (const float*)d_in[18];
    const float *adst0 = (const float*)d_in[9],  *adst1 = (const float*)d_in[19];
    const float *gatb0 = (const float*)d_in[10], *gatb1 = (const float*)d_in[20];
    const float *gcnW0 = (const float*)d_in[11], *gcnW1 = (const float*)d_in[21];
    const float *gcnb0 = (const float*)d_in[12], *gcnb1 = (const float*)d_in[22];
    const float *f1W0  = (const float*)d_in[13], *f1W1  = (const float*)d_in[23];
    const float *f1b0  = (const float*)d_in[14], *f1b1  = (const float*)d_in[24];
    const float *f2W0  = (const float*)d_in[15], *f2W1  = (const float*)d_in[25];
    const float *f2b0  = (const float*)d_in[16], *f2b1  = (const float*)d_in[26];

    // CSR (both branches batched)
    hipLaunchKernelGGL(k_init, dim3(cdiv(NN, 256), 2), dim3(256), 0, stream, deg, gstart, gend);
    hipLaunchKernelGGL(k_count, dim3(cdiv(EE, 256), 2), dim3(256), 0, stream, ei0, ei1, deg);
    hipLaunchKernelGGL(k_scan1, dim3(NSCB, 2), dim3(256), 0, stream, deg, offs, bsum);
    hipLaunchKernelGGL(k_scan2, dim3(1, 2), dim3(128), 0, stream, bsum);
    hipLaunchKernelGGL(k_scan3prep, dim3(NSCB, 2), dim3(256), 0, stream,
                       offs, bsum, cursor, deg, dinv, batch0, batch1, gstart, gend);
    hipLaunchKernelGGL(k_fill, dim3(cdiv(EPRIME, 256), 2), dim3(256), 0, stream, ei0, ei1, cursor, csr);

    // x -> bf16, gatW -> transpose bf16
    hipLaunchKernelGGL(k_split_x, dim3(cdiv(NN * 128, 256), 2), dim3(256), 0, stream, x0, x1, xb);
    hipLaunchKernelGGL(k_tbf, dim3(128 / 64, KP / 64, 2), dim3(256), 0, stream,
                       gatW0, gatW1, FF, HFD, 128, Bt);

    // h0 = x @ gatW (both branches)
    hipLaunchKernelGGL(mfma_gemm, dim3(NRB * NCB, 2), dim3(256), 0, stream,
                       xb, Bt, 128, 128, NN, HFD, 4, NCB, h0b, KP);

    // attention logits
    hipLaunchKernelGGL(k_att, dim3(cdiv(NN * HH, 256), 2), dim3(256), 0, stream,
                       h0b, asrc0, asrc1, adst0, adst1, a_s, a_d);

    // GAT aggregate -> h1 (brB)
    hipLaunchKernelGGL(gat_agg, dim3(cdiv(NN, 2), 2), dim3(256), 0, stream,
                       h0b, a_s, a_d, offs, csr, gatb0, gatb1, xb);

    // gcnW -> transpose bf16
    hipLaunchKernelGGL(k_tbf, dim3(KP / 64, KP / 64, 2), dim3(256), 0, stream,
                       gcnW0, gcnW1, HFD, HFD, KP, Bt);

    // h2 = h1 @ gcnW (A = h1b in brB, C = h2b in brA)
    hipLaunchKernelGGL(mfma_gemm, dim3(NRB * NCB, 2), dim3(256), 0, stream,
                       xb, Bt, KP, KP, NN, HFD, KP / 32, NCB, h0b, KP);

    // GCN aggregate -> hgcn bf16 (brB)
    hipLaunchKernelGGL(gcn_agg, dim3(cdiv(NN, 2), 2), dim3(256), 0, stream,
                       h0b, offs, csr, dinv, gcnb0, gcnb1, xb);

    // pooling (bf16 input)
    hipLaunchKernelGGL(k_pool, dim3(GG, 3, 2), dim3(64), 0, stream, xb, gstart, gend, gpool);

    // fcg1 split-K
    hipLaunchKernelGGL(k_fcg1_part, dim3(16, 4, F1KS), dim3(256), 0, stream,
                       gpool, f1W0, f1W1, f1p0, f1p1);
    hipLaunchKernelGGL(k_fcg1_red, dim3(cdiv(GG * 1000, 256), 2), dim3(256), 0, stream,
                       f1p0, f1p1, f1b0, f1b1, fc1out);

    // fcg2
    hipLaunchKernelGGL(k_fcg2, dim3(GG, 2), dim3(256), 0, stream,
                       fc1out, f2W0, f2W1, f2b0, f2b1, bout);

    hipLaunchKernelGGL(k_final, dim3(GG), dim3(256), 0, stream,
                       bout, bout + (size_t)GG * 64, target,
                       (const float*)d_in[27], (const float*)d_in[28],
                       (const float*)d_in[29], (const float*)d_in[30],
                       (const float*)d_in[31], (const float*)d_in[32],
                       (const float*)d_in[33], (const float*)d_in[34],
                       (float*)d_out);
}

// Round 15
// 847.766 us; speedup vs baseline: 1.9262x; 1.2960x over previous
//
#include <hip/hip_runtime.h>
#include <cstddef>
#include <cstdint>

#define NN 20000
#define EE 160000
#define EPRIME 180000   // EE + NN (self loops)
#define GG 128
#define FF 114
#define HH 10
#define HFD 1140        // FF*HH
#define KP 1152         // padded feature dim
#define F1K 2280        // fcg1 K
#define F1KS 18         // split-K chunks
#define F1KC 128        // chunk size
#define NSCB 79         // scan blocks = cdiv(NN,256)

typedef unsigned short ushort_t;
typedef __attribute__((ext_vector_type(8))) short bf16x8;
typedef __attribute__((ext_vector_type(4))) float f32x4;

static constexpr size_t REL  = (size_t)NN * KP;      // [N][KP] region stride (ushorts)
static constexpr size_t ZREL = (size_t)10 * NN * 128; // Z region stride per branch (ushorts)

static inline int cdiv(int a, int b) { return (a + b - 1) / b; }

// ---------------- bf16 helpers ----------------

__device__ __forceinline__ ushort_t f2bf(float v) {
    union { float f; unsigned u; } c; c.f = v;
    unsigned u = c.u;
    unsigned r = (u + 0x7fffu + ((u >> 16) & 1u)) >> 16;   // RNE
    return (ushort_t)r;
}
__device__ __forceinline__ float bf2f(ushort_t h) {
    union { unsigned u; float f; } c; c.u = ((unsigned)h) << 16;
    return c.f;
}

__device__ __forceinline__ void gload16(const void* g, const ushort_t* l) {
    __builtin_amdgcn_global_load_lds(
        (const __attribute__((address_space(1))) unsigned int*)g,
        (__attribute__((address_space(3))) unsigned int*)l, 16, 0, 0);
}

// ---------------- CSR construction (branch = blockIdx.y) ----------------

__global__ void k_init(int* __restrict__ deg, int* __restrict__ gstart, int* __restrict__ gend) {
    int br = blockIdx.y;
    int i = blockIdx.x * blockDim.x + threadIdx.x;
    if (i < NN) deg[br * NN + i] = 1;               // self loop
    if (i < GG) { gstart[br * GG + i] = NN; gend[br * GG + i] = 0; }
}

__global__ void k_count(const int* __restrict__ ei0, const int* __restrict__ ei1,
                        int* __restrict__ deg) {
    int br = blockIdx.y;
    const int* ei = br ? ei1 : ei0;
    int i = blockIdx.x * blockDim.x + threadIdx.x;
    if (i < EE) atomicAdd(&deg[br * NN + ei[EE + i]], 1);
}

__global__ void k_scan1(const int* __restrict__ deg, int* __restrict__ offs, int* __restrict__ bsum) {
    __shared__ int tmp[256];
    int br = blockIdx.y;
    deg += br * NN; offs += br * (NN + 1); bsum += br * 128;
    int b = blockIdx.x, tid = threadIdx.x;
    int i = b * 256 + tid;
    int v = (i < NN) ? deg[i] : 0;
    tmp[tid] = v;
    __syncthreads();
#pragma unroll
    for (int off = 1; off < 256; off <<= 1) {
        int t = (tid >= off) ? tmp[tid - off] : 0;
        __syncthreads();
        tmp[tid] += t;
        __syncthreads();
    }
    if (i < NN) offs[i + 1] = tmp[tid];
    if (tid == 255) bsum[b] = tmp[255];
}

__global__ void k_scan2(int* __restrict__ bsum) {
    __shared__ int tmp[128];
    bsum += blockIdx.y * 128;
    int tid = threadIdx.x;
    int v = (tid < NSCB) ? bsum[tid] : 0;
    tmp[tid] = v;
    __syncthreads();
#pragma unroll
    for (int off = 1; off < 128; off <<= 1) {
        int t = (tid >= off) ? tmp[tid - off] : 0;
        __syncthreads();
        tmp[tid] += t;
        __syncthreads();
    }
    if (tid < NSCB) bsum[tid] = tmp[tid] - v;   // exclusive prefix
}

__global__ void k_scan3prep(int* __restrict__ offs, const int* __restrict__ bsum,
                            int* __restrict__ cursor, const int* __restrict__ deg,
                            float* __restrict__ dinv,
                            const int* __restrict__ batch0, const int* __restrict__ batch1,
                            int* __restrict__ gstart, int* __restrict__ gend) {
    int br = blockIdx.y;
    offs += br * (NN + 1); bsum += br * 128; cursor += br * NN;
    deg += br * NN; dinv += br * NN;
    const int* batch = br ? batch1 : batch0;
    gstart += br * GG; gend += br * GG;
    int i = blockIdx.x * 256 + threadIdx.x;
    if (i < NN) {
        int o = offs[i + 1] + bsum[i >> 8];
        offs[i + 1] = o;
        cursor[i] = o - deg[i];
        dinv[i] = rsqrtf((float)deg[i]);
        int b = batch[i];
        atomicMin(&gstart[b], i);
        atomicMax(&gend[b], i + 1);
    }
    if (i == 0) offs[0] = 0;
}

__global__ void k_fill(const int* __restrict__ ei0, const int* __restrict__ ei1,
                       int* __restrict__ cursor, int* __restrict__ csr) {
    int br = blockIdx.y;
    const int* ei = br ? ei1 : ei0;
    cursor += br * NN; csr += (size_t)br * EPRIME;
    int i = blockIdx.x * blockDim.x + threadIdx.x;
    if (i < EPRIME) {
        int s, d;
        if (i < EE) { s = ei[i]; d = ei[EE + i]; }
        else        { s = i - EE; d = s; }
        int pos = atomicAdd(&cursor[d], 1);
        csr[pos] = s;
    }
}

// ---------------- bf16 conversions ----------------

__global__ void k_split_x(const float* __restrict__ x0, const float* __restrict__ x1,
                          ushort_t* __restrict__ xb) {
    int br = blockIdx.y;
    const float* x = br ? x1 : x0;
    xb += (size_t)br * REL;
    int idx = blockIdx.x * 256 + threadIdx.x;
    if (idx >= NN * 128) return;
    int n = idx >> 7, k = idx & 127;
    float v = (k < FF) ? x[(size_t)n * FF + k] : 0.f;
    xb[idx] = f2bf(v);
}

// gcnW [K,Nc] -> T[n][k]=W[k][n], bf16, zero pad. branch = blockIdx.z
__global__ __launch_bounds__(256) void k_tbf(const float* __restrict__ W0, const float* __restrict__ W1,
                                             int K, int Nc, int Kpad, ushort_t* __restrict__ T) {
    __shared__ float tile[64][65];
    int br = blockIdx.z;
    const float* W = br ? W1 : W0;
    T += (size_t)br * KP * KP;
    int kb = blockIdx.x * 64;
    int nb = blockIdx.y * 64;
    int c = threadIdx.x & 63, r4 = threadIdx.x >> 6;
#pragma unroll
    for (int rr = 0; rr < 16; ++rr) {
        int r = r4 * 16 + rr;
        int gk = kb + r, gn = nb + c;
        tile[r][c] = (gk < K && gn < Nc) ? W[(size_t)gk * Nc + gn] : 0.f;
    }
    __syncthreads();
#pragma unroll
    for (int rr = 0; rr < 16; ++rr) {
        int r = r4 * 16 + rr;
        int gn = nb + r, gk = kb + c;
        T[(size_t)gn * Kpad + gk] = f2bf(tile[c][r]);
    }
}

// per-head gatW block transpose: WgT[br][h][c][k] = gatW[k][h*FF+c], 128x128 bf16, zero pad.
__global__ __launch_bounds__(256) void k_wgtT(const float* __restrict__ W0, const float* __restrict__ W1,
                                              ushort_t* __restrict__ WgT) {
    __shared__ float tile[64][65];
    int y = blockIdx.z;
    int br = y / 10, h = y - 10 * br;
    const float* W = br ? W1 : W0;
    ushort_t* T = WgT + ((size_t)br * 10 + h) * 128 * 128;
    int kb = blockIdx.x * 64, cb = blockIdx.y * 64;
    int c = threadIdx.x & 63, r4 = threadIdx.x >> 6;
#pragma unroll
    for (int rr = 0; rr < 16; ++rr) {
        int r = r4 * 16 + rr;
        int gk = kb + r, gc = cb + c;
        tile[r][c] = (gk < FF && gc < FF) ? W[(size_t)gk * HFD + h * FF + gc] : 0.f;
    }
    __syncthreads();
#pragma unroll
    for (int rr = 0; rr < 16; ++rr) {
        int r = r4 * 16 + rr;
        int gc2 = cb + r, gk2 = kb + c;
        T[(size_t)gc2 * 128 + gk2] = f2bf(tile[c][r]);
    }
}

// Vs/Vd [br][128][10] fp32: Vs[k][h] = sum_f gatW[k][h*FF+f]*att_src[h][f]
__global__ void k_vsd(const float* __restrict__ W0, const float* __restrict__ W1,
                      const float* __restrict__ as0, const float* __restrict__ as1,
                      const float* __restrict__ ad0, const float* __restrict__ ad1,
                      float* __restrict__ Vs, float* __restrict__ Vd) {
    int br = blockIdx.y;
    const float* W = br ? W1 : W0;
    const float* asrc = br ? as1 : as0;
    const float* adst = br ? ad1 : ad0;
    int idx = blockIdx.x * 256 + threadIdx.x;   // k*10+h
    if (idx >= 1280) return;
    int k = idx / 10, h = idx - 10 * (idx / 10);
    float vs = 0.f, vd = 0.f;
    if (k < FF) {
        const float* wrow = W + (size_t)k * HFD + h * FF;
        const float* s = asrc + h * FF;
        const float* d = adst + h * FF;
        for (int f = 0; f < FF; ++f) { vs += wrow[f] * s[f]; vd += wrow[f] * d[f]; }
    }
    Vs[br * 1280 + idx] = vs;
    Vd[br * 1280 + idx] = vd;
}

// attention logits from xb: a_s[n,h] = x[n,:] . Vs[:,h]
__global__ void k_att2(const ushort_t* __restrict__ xbase,
                       const float* __restrict__ Vs, const float* __restrict__ Vd,
                       float* __restrict__ as_, float* __restrict__ ad_) {
    int br = blockIdx.y;
    const ushort_t* xb = xbase + (size_t)br * REL;
    const float* vs = Vs + br * 1280;
    const float* vd = Vd + br * 1280;
    as_ += (size_t)br * NN * HH; ad_ += (size_t)br * NN * HH;
    int id = blockIdx.x * blockDim.x + threadIdx.x;
    if (id >= NN * HH) return;
    int n = id / HH, h = id - HH * (id / HH);
    const ushort_t* row = xb + (size_t)n * 128;
    float as = 0.f, ad = 0.f;
    for (int k = 0; k < FF; k += 2) {
        unsigned qq = *(const unsigned*)(row + k);
        float v0 = bf2f((ushort_t)(qq & 0xffffu));
        float v1 = bf2f((ushort_t)(qq >> 16));
        as += v0 * vs[k * 10 + h] + v1 * vs[(k + 1) * 10 + h];
        ad += v0 * vd[k * 10 + h] + v1 * vd[(k + 1) * 10 + h];
    }
    as_[id] = as;
    ad_[id] = ad;
}

// ---------------- x-domain GAT aggregation: Z[br][h][n][128] bf16 ----------------
// Z_h[d,:] = (1/den_h) * sum_s exp_h(s,d) * x[s,:]   (x row = 256B, L2-resident)

template <int NU>
__device__ __forceinline__ void gax_grp(
    int eg, int end, int lane, float my_ad,
    const int* __restrict__ csr, const float* __restrict__ as_,
    const ushort_t* __restrict__ xb,
    float& den, float acc[HH][2]) {
    int s[NU]; float ex[NU];
#pragma unroll
    for (int u = 0; u < NU; ++u) {
        int idx = eg + u; if (idx > end - 1) idx = end - 1;   // clamp (weight zeroed)
        s[u] = csr[idx];
    }
#pragma unroll
    for (int u = 0; u < NU; ++u) {
        float e = 0.f;
        if (lane < HH) {
            float t = as_[s[u] * HH + lane] + my_ad;
            t = (t >= 0.f) ? t : 0.2f * t;
            e = __expf(t);
            if (eg + u >= end) e = 0.f;
        }
        ex[u] = e;
        den += e;
    }
    unsigned xv[NU];
#pragma unroll
    for (int u = 0; u < NU; ++u)
        xv[u] = *(const unsigned*)(xb + (size_t)s[u] * 128 + 2 * lane);
#pragma unroll
    for (int u = 0; u < NU; ++u) {
        float x0 = bf2f((ushort_t)(xv[u] & 0xffffu));
        float x1 = bf2f((ushort_t)(xv[u] >> 16));
#pragma unroll
        for (int h = 0; h < HH; ++h) {
            float w = __shfl(ex[u], h, 64);
            acc[h][0] += w * x0;
            acc[h][1] += w * x1;
        }
    }
}

__global__ __launch_bounds__(256) void gat_aggx(
    const ushort_t* __restrict__ xbase,
    const float* __restrict__ as_, const float* __restrict__ ad_,
    const int* __restrict__ offs, const int* __restrict__ csr,
    ushort_t* __restrict__ Z) {
    int br = blockIdx.y;
    const ushort_t* xb = xbase + (size_t)br * REL;
    as_ += (size_t)br * NN * HH; ad_ += (size_t)br * NN * HH;
    offs += br * (NN + 1); csr += (size_t)br * EPRIME;
    ushort_t* Zb = Z + (size_t)br * ZREL;

    int lane = threadIdx.x & 63;
    int n = blockIdx.x * 4 + (threadIdx.x >> 6);
    if (n >= NN) return;
    int beg = offs[n], end = offs[n + 1];
    float my_ad = (lane < HH) ? ad_[n * HH + lane] : 0.f;

    float den = 0.f;
    float acc[HH][2];
#pragma unroll
    for (int h = 0; h < HH; ++h) { acc[h][0] = 0.f; acc[h][1] = 0.f; }

    int eg = beg;
    for (; eg + 8 <= end; eg += 8)
        gax_grp<8>(eg, end, lane, my_ad, csr, as_, xb, den, acc);
    for (; eg < end; eg += 4)
        gax_grp<4>(eg, end, lane, my_ad, csr, as_, xb, den, acc);

#pragma unroll
    for (int h = 0; h < HH; ++h) {
        float d = __shfl(den, h, 64);
        float inv = 1.f / d;                    // den >= exp(self-loop) > 0
        unsigned pk = (unsigned)f2bf(acc[h][0] * inv)
                    | ((unsigned)f2bf(acc[h][1] * inv) << 16);
        *(unsigned*)(Zb + ((size_t)h * NN + n) * 128 + 2 * lane) = pk;
    }
}

// ---------------- per-head GEMM: h1[:, hFF..hFF+113] = lrelu(Z_h @ WgT_h^T + b) ----------------
// blockIdx.y in [0,20): br = y/10, h = y%10. M=NN, K=128(pad114), N=114(pad128).

__global__ __launch_bounds__(256) void mfma_hgemm(
    const ushort_t* __restrict__ Zbase, const ushort_t* __restrict__ WgT,
    const float* __restrict__ b0, const float* __restrict__ b1,
    ushort_t* __restrict__ Cbase) {
    __shared__ __align__(16) ushort_t lds[2 * 8192];
    int y = blockIdx.y;
    int br = y / 10, h = y - 10 * br;
    const ushort_t* A = Zbase + (size_t)br * ZREL + (size_t)h * NN * 128;
    const ushort_t* Bt = WgT + ((size_t)br * 10 + h) * 128 * 128;
    const float* bias = (br ? b1 : b0) + h * FF;
    ushort_t* Cb = Cbase + (size_t)br * REL;

    const int tid = threadIdx.x;
    const int lane = tid & 63;
    const int w = tid >> 6;
    const int wr = w >> 1, wc = w & 1;

    // bijective XCD-chunked swizzle
    int nwg = gridDim.x;
    int q = nwg >> 3, r8 = nwg & 7;
    int xcd = blockIdx.x & 7, sidx = blockIdx.x >> 3;
    int wg = (xcd < r8 ? xcd * (q + 1) : r8 * (q + 1) + (xcd - r8) * q) + sidx;

    int row0 = wg * 128; if (row0 > NN - 128) row0 = NN - 128;   // overlap trick

    f32x4 acc[4][4];
#pragma unroll
    for (int i = 0; i < 4; ++i)
#pragma unroll
        for (int j = 0; j < 4; ++j) acc[i][j] = (f32x4){0.f, 0.f, 0.f, 0.f};

    const char* pA[2]; const char* pB[2];
    unsigned ldsoff[2];
#pragma unroll
    for (int i = 0; i < 2; ++i) {
        int c = (w * 2 + i) * 64 + lane;
        int kg = c >> 7, r = c & 127;
        pA[i] = (const char*)A + (size_t)(row0 + r) * 256 + kg * 16;
        pB[i] = (const char*)Bt + (size_t)r * 256 + kg * 16;
        ldsoff[i] = (w * 2 + i) * 512;
    }
    const int kgf = lane >> 4, r15 = lane & 15;

    auto STAGE = [&](int buf, int ks) {
        size_t kb = (size_t)ks * 64;
        unsigned bo = buf ? 8192u : 0u;
#pragma unroll
        for (int i = 0; i < 2; ++i) {
            gload16(pA[i] + kb, lds + bo + 0 + ldsoff[i]);
            gload16(pB[i] + kb, lds + bo + 4096 + ldsoff[i]);
        }
    };

    STAGE(0, 0);
    asm volatile("s_waitcnt vmcnt(0)" ::: "memory");
    __syncthreads();
    int cur = 0;

    for (int ks = 0; ks < 4; ++ks) {
        if (ks + 1 < 4) STAGE(cur ^ 1, ks + 1);
        const ushort_t* lb = lds + (cur ? 8192u : 0u);
        bf16x8 ah[4], bh[4];
#pragma unroll
        for (int i = 0; i < 4; ++i) {
            int ra = wr * 64 + i * 16 + r15;
            int rb = wc * 64 + i * 16 + r15;
            ah[i] = *(const bf16x8*)(lb + 0 + kgf * 1024 + ra * 8);
            bh[i] = *(const bf16x8*)(lb + 4096 + kgf * 1024 + rb * 8);
        }
#pragma unroll
        for (int i = 0; i < 4; ++i)
#pragma unroll
            for (int j = 0; j < 4; ++j)
                acc[i][j] = __builtin_amdgcn_mfma_f32_16x16x32_bf16(ah[i], bh[j], acc[i][j], 0, 0, 0);
        asm volatile("s_waitcnt vmcnt(0)" ::: "memory");
        __syncthreads();
        cur ^= 1;
    }

    const int g4 = lane >> 4;
#pragma unroll
    for (int i = 0; i < 4; ++i)
#pragma unroll
        for (int j = 0; j < 4; ++j) {
            int c = wc * 64 + j * 16 + r15;
#pragma unroll
            for (int reg = 0; reg < 4; ++reg) {
                int r = row0 + wr * 64 + i * 16 + g4 * 4 + reg;
                int gc = h * FF + c;
                if (c < FF) {
                    float v = acc[i][j][reg] + bias[c];
                    v = (v >= 0.f) ? v : 0.01f * v;
                    Cb[(size_t)r * KP + gc] = f2bf(v);
                } else if (h == 9 && gc < KP) {
                    Cb[(size_t)r * KP + gc] = 0;   // zero pad cols 1140..1151
                }
            }
        }
}

// ---------------- full-bf16 MFMA GEMM (h2 = h1 @ gcnW), strides parameterized ----------------

__global__ __launch_bounds__(256) void mfma_gemm(
    const ushort_t* __restrict__ Abase, const ushort_t* __restrict__ Btbase,
    int lda, int ldb, int M, int Nreal, int ksteps, int ncb,
    ushort_t* __restrict__ Cbase, int ldcs) {
    __shared__ __align__(16) ushort_t lds[2 * 8192];
    const int br = blockIdx.y;
    const ushort_t* A = Abase + (size_t)br * REL;
    const ushort_t* Bt = Btbase + (size_t)br * KP * KP;
    ushort_t* Cb = Cbase + (size_t)br * ZREL;          // C lives in brA (Z region)

    const int tid = threadIdx.x;
    const int lane = tid & 63;
    const int w = tid >> 6;
    const int wr = w >> 1, wc = w & 1;

    int nwg = gridDim.x;
    int q = nwg >> 3, r8 = nwg & 7;
    int xcd = blockIdx.x & 7, sidx = blockIdx.x >> 3;
    int wg = (xcd < r8 ? xcd * (q + 1) : r8 * (q + 1) + (xcd - r8) * q) + sidx;
    int brow = wg / ncb, bcol = wg - brow * ncb;

    int row0 = brow * 128; if (row0 > M - 128) row0 = M - 128;
    const int col0 = bcol * 128;

    f32x4 acc[4][4];
#pragma unroll
    for (int i = 0; i < 4; ++i)
#pragma unroll
        for (int j = 0; j < 4; ++j) acc[i][j] = (f32x4){0.f, 0.f, 0.f, 0.f};

    const size_t ldaB = (size_t)lda * 2, ldbB = (size_t)ldb * 2;
    const char* pA[2]; const char* pB[2];
    unsigned ldsoff[2];
#pragma unroll
    for (int i = 0; i < 2; ++i) {
        int c = (w * 2 + i) * 64 + lane;
        int kg = c >> 7, r = c & 127;
        pA[i] = (const char*)A + (size_t)(row0 + r) * ldaB + kg * 16;
        pB[i] = (const char*)Bt + (size_t)(col0 + r) * ldbB + kg * 16;
        ldsoff[i] = (w * 2 + i) * 512;
    }
    const int kgf = lane >> 4, r15 = lane & 15;

    auto STAGE = [&](int buf, int ks) {
        size_t kb = (size_t)ks * 64;
        unsigned bo = buf ? 8192u : 0u;
#pragma unroll
        for (int i = 0; i < 2; ++i) {
            gload16(pA[i] + kb, lds + bo + 0 + ldsoff[i]);
            gload16(pB[i] + kb, lds + bo + 4096 + ldsoff[i]);
        }
    };

    STAGE(0, 0);
    asm volatile("s_waitcnt vmcnt(0)" ::: "memory");
    __syncthreads();
    int cur = 0;

    for (int ks = 0; ks < ksteps; ++ks) {
        if (ks + 1 < ksteps) STAGE(cur ^ 1, ks + 1);
        const ushort_t* lb = lds + (cur ? 8192u : 0u);
        bf16x8 ah[4], bh[4];
#pragma unroll
        for (int i = 0; i < 4; ++i) {
            int ra = wr * 64 + i * 16 + r15;
            int rb = wc * 64 + i * 16 + r15;
            ah[i] = *(const bf16x8*)(lb + 0 + kgf * 1024 + ra * 8);
            bh[i] = *(const bf16x8*)(lb + 4096 + kgf * 1024 + rb * 8);
        }
#pragma unroll
        for (int i = 0; i < 4; ++i)
#pragma unroll
            for (int j = 0; j < 4; ++j)
                acc[i][j] = __builtin_amdgcn_mfma_f32_16x16x32_bf16(ah[i], bh[j], acc[i][j], 0, 0, 0);
        asm volatile("s_waitcnt vmcnt(0)" ::: "memory");
        __syncthreads();
        cur ^= 1;
    }

    const int g4 = lane >> 4;
#pragma unroll
    for (int i = 0; i < 4; ++i)
#pragma unroll
        for (int j = 0; j < 4; ++j) {
            int c = col0 + wc * 64 + j * 16 + r15;
#pragma unroll
            for (int reg = 0; reg < 4; ++reg) {
                int r = row0 + wr * 64 + i * 16 + g4 * 4 + reg;
                if (r < M) {
                    float v = (c < Nreal) ? acc[i][j][reg] : 0.f;
                    Cb[(size_t)r * ldcs + c] = f2bf(v);
                }
            }
        }
}

// ---------------- GCN aggregation: wave-PAIR per node, bf16 in/out ----------------

template <int NU, int HASB>
__device__ __forceinline__ void gcn_grp(
    int eg, int end, int lane, float di,
    const int* __restrict__ csr, const float* __restrict__ dinv,
    const ushort_t* __restrict__ h2b, int kbA, int kbB,
    float* accA, float* accB) {
    int s[NU]; float w[NU];
#pragma unroll
    for (int u = 0; u < NU; ++u) {
        int idx = eg + u; if (idx > end - 1) idx = end - 1;
        s[u] = csr[idx];
    }
#pragma unroll
    for (int u = 0; u < NU; ++u) {
        float ww = dinv[s[u]] * di;
        w[u] = (eg + u < end) ? ww : 0.f;
    }
    bf16x8 qv[NU];
#pragma unroll
    for (int u = 0; u < NU; ++u) qv[u] = *(const bf16x8*)(h2b + (size_t)s[u] * KP + kbA);
#pragma unroll
    for (int u = 0; u < NU; ++u)
#pragma unroll
        for (int e = 0; e < 8; ++e) accA[e] += w[u] * bf2f((ushort_t)qv[u][e]);
    if (HASB && lane < 16) {
#pragma unroll
        for (int u = 0; u < NU; ++u) qv[u] = *(const bf16x8*)(h2b + (size_t)s[u] * KP + kbB);
#pragma unroll
        for (int u = 0; u < NU; ++u)
#pragma unroll
            for (int e = 0; e < 8; ++e) accB[e] += w[u] * bf2f((ushort_t)qv[u][e]);
    }
}

__global__ __launch_bounds__(256) void gcn_agg(
    const ushort_t* __restrict__ h2base, const int* __restrict__ offs, const int* __restrict__ csr,
    const float* __restrict__ dinv,
    const float* __restrict__ b0, const float* __restrict__ b1,
    ushort_t* __restrict__ outbase) {
    int br = blockIdx.y;
    const ushort_t* h2b = h2base + (size_t)br * ZREL;   // h2 lives in brA (Z region)
    offs += br * (NN + 1); csr += (size_t)br * EPRIME; dinv += br * NN;
    const float* bias = br ? b1 : b0;
    ushort_t* outb = outbase + (size_t)br * REL;

    int lane = threadIdx.x & 63;
    int wid = threadIdx.x >> 6;
    int n = blockIdx.x * 2 + (wid >> 1);
    int half = wid & 1;
    if (n >= NN) return;
    int beg = offs[n], end = offs[n + 1];
    float di = dinv[n];
    const int kbA = (half ? 512 : 0) + 8 * lane;
    const int kbB = 1024 + 8 * lane;
    float accA[8] = {}, accB[8] = {};

    int eg = beg;
    if (half == 0) {
        for (; eg + 8 <= end; eg += 8)
            gcn_grp<8, 1>(eg, end, lane, di, csr, dinv, h2b, kbA, kbB, accA, accB);
        for (; eg < end; eg += 4)
            gcn_grp<4, 1>(eg, end, lane, di, csr, dinv, h2b, kbA, kbB, accA, accB);
    } else {
        for (; eg + 8 <= end; eg += 8)
            gcn_grp<8, 0>(eg, end, lane, di, csr, dinv, h2b, kbA, kbB, accA, accB);
        for (; eg < end; eg += 4)
            gcn_grp<4, 0>(eg, end, lane, di, csr, dinv, h2b, kbA, kbB, accA, accB);
    }

    {
        bf16x8 vb;
#pragma unroll
        for (int e = 0; e < 8; ++e) {
            float v = accA[e] + bias[kbA + e];
            v = (v >= 0.f) ? v : 0.01f * v;
            vb[e] = (short)f2bf(v);
        }
        *(bf16x8*)(outb + (size_t)n * KP + kbA) = vb;
    }
    if (half == 0 && lane < 16) {
        bf16x8 vb;
#pragma unroll
        for (int e = 0; e < 8; ++e) {
            int k = kbB + e;
            float v = 0.f;
            if (k < HFD) {
                v = accB[e] + bias[k];
                v = (v >= 0.f) ? v : 0.01f * v;
            }
            vb[e] = (short)f2bf(v);
        }
        *(bf16x8*)(outb + (size_t)n * KP + kbB) = vb;
    }
}

// ---------------- graph pooling (max + mean), bf16 input ----------------

__global__ void k_pool(const ushort_t* __restrict__ hbase, const int* __restrict__ gs,
                       const int* __restrict__ ge, float* __restrict__ gpool) {
    int br = blockIdx.z;
    const ushort_t* hfeat = hbase + (size_t)br * REL;
    gs += br * GG; ge += br * GG;
    float* gout = gpool + (size_t)br * GG * 2 * HFD;
    if (threadIdx.x >= 48) return;
    int g = blockIdx.x;
    int mg = blockIdx.y * 48 + threadIdx.x;
    int s = gs[g], e = ge[g];
    int cnt = e - s;
    float mx[8], sm[8];
#pragma unroll
    for (int j = 0; j < 8; ++j) { mx[j] = -1e30f; sm[j] = 0.f; }
    for (int r = s; r < e; ++r) {
        bf16x8 qv = *(const bf16x8*)(hfeat + (size_t)r * KP + 8 * mg);
#pragma unroll
        for (int j = 0; j < 8; ++j) {
            float v = bf2f((ushort_t)qv[j]);
            mx[j] = fmaxf(mx[j], v);
            sm[j] += v;
        }
    }
    float inv = (cnt > 0) ? 1.f / (float)cnt : 0.f;
#pragma unroll
    for (int j = 0; j < 8; ++j) {
        int k = 8 * mg + j;
        if (k < HFD) {
            float m = (cnt > 0) ? mx[j] : 0.f;
            gout[(size_t)g * (2 * HFD) + k] = m;
            gout[(size_t)g * (2 * HFD) + HFD + k] = sm[j] * inv;
        }
    }
}

// ---------------- fcg1 split-K (kt loop MUST stay rolled — round-3 spill regression) ----------------

__global__ __launch_bounds__(256) void k_fcg1_part(
    const float* __restrict__ gpool, const float* __restrict__ B0, const float* __restrict__ B1,
    float* __restrict__ p0, float* __restrict__ p1) {
    __shared__ float As[16][64 + 4];
    __shared__ float Bs[16][64 + 4];
    int br = blockIdx.y >> 1, rowblk = blockIdx.y & 1;
    const float* A = gpool + (size_t)br * GG * F1K;
    const float* B = br ? B1 : B0;
    float* part = br ? p1 : p0;
    int tid = threadIdx.x;
    int tx = tid & 15, ty = tid >> 4;
    int row0 = rowblk * 64, col0 = blockIdx.x * 64;
    int kbeg = blockIdx.z * F1KC;
    float acc[4][4] = {};
#pragma unroll 1
    for (int kt = 0; kt < F1KC / 16; ++kt) {
        int kk = kbeg + kt * 16;
#pragma unroll
        for (int l = 0; l < 4; ++l) {
            int idx = tid + 256 * l;
            int m = idx >> 4, k = idx & 15;
            int gr = row0 + m, gk = kk + k;
            As[k][m] = (gk < F1K) ? A[(size_t)gr * F1K + gk] : 0.f;
        }
#pragma unroll
        for (int l = 0; l < 4; ++l) {
            int idx = tid + 256 * l;
            int nn = idx & 63, k = idx >> 6;
            int gc = col0 + nn, gk = kk + k;
            Bs[k][nn] = (gc < 1000 && gk < F1K) ? B[(size_t)gk * 1000 + gc] : 0.f;
        }
        __syncthreads();
#pragma unroll
        for (int k = 0; k < 16; ++k) {
            float4 av = *(const float4*)&As[k][ty * 4];
            float4 bv = *(const float4*)&Bs[k][tx * 4];
            float a[4] = {av.x, av.y, av.z, av.w};
            float b[4] = {bv.x, bv.y, bv.z, bv.w};
#pragma unroll
            for (int i = 0; i < 4; ++i)
#pragma unroll
                for (int j = 0; j < 4; ++j) acc[i][j] += a[i] * b[j];
        }
        __syncthreads();
    }
    float* pc = part + (size_t)blockIdx.z * GG * 1000;
#pragma unroll
    for (int i = 0; i < 4; ++i) {
        int r = row0 + ty * 4 + i;
#pragma unroll
        for (int j = 0; j < 4; ++j) {
            int c = col0 + tx * 4 + j;
            if (c < 1000) pc[(size_t)r * 1000 + c] = acc[i][j];
        }
    }
}

__global__ void k_fcg1_red(const float* __restrict__ p0, const float* __restrict__ p1,
                           const float* __restrict__ b0, const float* __restrict__ b1,
                           float* __restrict__ fc1out) {
    int br = blockIdx.y;
    const float* part = br ? p1 : p0;
    const float* bias = br ? b1 : b0;
    float* out = fc1out + (size_t)br * GG * 1000;
    int idx = blockIdx.x * 256 + threadIdx.x;
    if (idx >= GG * 1000) return;
    float s = 0.f;
#pragma unroll
    for (int k = 0; k < F1KS; ++k) s += part[(size_t)k * GG * 1000 + idx];
    int n = idx % 1000;
    float v = s + bias[n];
    out[idx] = (v >= 0.f) ? v : 0.01f * v;
}

// ---------------- fcg2 ----------------

__global__ __launch_bounds__(256) void k_fcg2(const float* __restrict__ fc1out,
                                              const float* __restrict__ W0, const float* __restrict__ W1,
                                              const float* __restrict__ b0, const float* __restrict__ b1,
                                              float* __restrict__ bout) {
    __shared__ float part[4][64];
    int br = blockIdx.y;
    const float* in = fc1out + (size_t)br * GG * 1000;
    const float* W = br ? W1 : W0;
    const float* b = br ? b1 : b0;
    float* out = bout + (size_t)br * GG * 64;
    int g = blockIdx.x;
    int o = threadIdx.x & 63, p = threadIdx.x >> 6;
    const float* row = in + (size_t)g * 1000;
    float acc = 0.f;
    for (int k = p * 250; k < (p + 1) * 250; ++k) acc += row[k] * W[k * 64 + o];
    part[p][o] = acc;
    __syncthreads();
    if (p == 0) out[(size_t)g * 64 + o] = part[0][o] + part[1][o] + part[2][o] + part[3][o] + b[o];
}

// ---------------- final head ----------------

__global__ __launch_bounds__(256) void k_final(
    const float* __restrict__ b1, const float* __restrict__ b2, const float* __restrict__ target,
    const float* __restrict__ fcxtW, const float* __restrict__ fcxtb,
    const float* __restrict__ fc1W, const float* __restrict__ fc1b,
    const float* __restrict__ fc2W, const float* __restrict__ fc2b,
    const float* __restrict__ outW, const float* __restrict__ outb,
    float* __restrict__ out) {
    __shared__ float xc[256];
    __shared__ float xt2[128];
    __shared__ float y1[128];
    __shared__ float y2[32];
    int g = blockIdx.x, t = threadIdx.x;
    if (t < 64) xc[t] = b1[(size_t)g * 64 + t];
    else if (t < 128) xc[t] = b2[(size_t)g * 64 + (t - 64)];
    {
        int c = t & 127, p = t >> 7;
        float acc = 0.f;
        const float* trow = target + (size_t)g * 1000;
        for (int k = p * 500; k < (p + 1) * 500; ++k) acc += trow[k] * fcxtW[k * 128 + c];
        if (p == 1) xt2[c] = acc;
        __syncthreads();
        if (p == 0) xc[128 + c] = acc + xt2[c] + fcxtb[c];
    }
    __syncthreads();
    if (t < 128) {
        float acc = 0.f;
        for (int k = 0; k < 256; ++k) acc += xc[k] * fc1W[k * 128 + t];
        acc += fc1b[t];
        y1[t] = (acc >= 0.f) ? acc : 0.01f * acc;
    }
    __syncthreads();
    if (t < 32) {
        float acc = 0.f;
        for (int k = 0; k < 128; ++k) acc += y1[k] * fc2W[k * 32 + t];
        acc += fc2b[t];
        y2[t] = (acc >= 0.f) ? acc : 0.01f * acc;
    }
    __syncthreads();
    if (t == 0) {
        float acc = 0.f;
        for (int k = 0; k < 32; ++k) acc += y2[k] * outW[k];
        out[g] = acc + outb[0];
    }
}

// ---------------- host launch ----------------

extern "C" void kernel_launch(void* const* d_in, const int* in_sizes, int n_in,
                              void* d_out, int out_size, void* d_ws, size_t ws_size,
                              hipStream_t stream) {
    (void)in_sizes; (void)n_in; (void)out_size; (void)ws_size;

    size_t off = 0;
    auto alloc = [&](size_t bytes) -> void* {
        void* p = (char*)d_ws + off;
        off += (bytes + 255) & ~(size_t)255;
        return p;
    };
    char* brA = (char*)alloc(2 * ZREL * 2);   // per-branch: Z -> h2b -> f1part overlays
    char* brB = (char*)alloc(2 * REL * 2);    // per-branch: xb -> h1b -> hgcnb overlays
    ushort_t* Bt  = (ushort_t*)alloc(2 * (size_t)KP * KP * 2);
    ushort_t* WgT = (ushort_t*)alloc(20 * (size_t)128 * 128 * 2);
    float* Vs     = (float*)alloc(2 * 1280 * 4);
    float* Vd     = (float*)alloc(2 * 1280 * 4);
    float* a_s    = (float*)alloc(2 * (size_t)NN * HH * 4);
    float* a_d    = (float*)alloc(2 * (size_t)NN * HH * 4);
    int*   deg    = (int*)alloc(2 * (size_t)NN * 4);
    int*   offs   = (int*)alloc(2 * (size_t)(NN + 1) * 4);
    int*   cursor = (int*)alloc(2 * (size_t)NN * 4);
    int*   csr    = (int*)alloc(2 * (size_t)EPRIME * 4);
    float* dinv   = (float*)alloc(2 * (size_t)NN * 4);
    int*   gstart = (int*)alloc(2 * (size_t)GG * 4);
    int*   gend   = (int*)alloc(2 * (size_t)GG * 4);
    int*   bsum   = (int*)alloc(2 * (size_t)128 * 4);
    float* gpool  = (float*)alloc(2 * (size_t)GG * 2 * HFD * 4);
    float* fc1out = (float*)alloc(2 * (size_t)GG * 1000 * 4);
    float* bout   = (float*)alloc(2 * (size_t)GG * 64 * 4);

    ushort_t* Zb  = (ushort_t*)brA;               // + br*ZREL (overlay: h2b, f1part)
    float* f1p0 = (float*)brA;
    float* f1p1 = (float*)(brA + (size_t)F1KS * GG * 1000 * 4);
    ushort_t* xb  = (ushort_t*)brB;               // + br*REL (overlay: h1b, hgcnb)

    const float* target = (const float*)d_in[6];
    const int NRB = cdiv(NN, 128);        // 157 row blocks
    const int NCB = KP / 128;             // 9 col blocks

    const float* x0 = (const float*)d_in[0];
    const float* x1 = (const float*)d_in[3];
    const int* ei0 = (const int*)d_in[1];
    const int* ei1 = (const int*)d_in[4];
    const int* batch0 = (const int*)d_in[2];
    const int* batch1 = (const int*)d_in[5];
    const float *gatW0 = (const float*)d_in[7],  *gatW1 = (const float*)d_in[17];
    const float *asrc0 = (const float*)d_in[8],  *asrc1 = (const float*)d_in[18];
    const float *adst0 = (const float*)d_in[9],  *adst1 = (const float*)d_in[19];
    const float *gatb0 = (const float*)d_in[10], *gatb1 = (const float*)d_in[20];
    const float *gcnW0 = (const float*)d_in[11], *gcnW1 = (const float*)d_in[21];
    const float *gcnb0 = (const float*)d_in[12], *gcnb1 = (const float*)d_in[22];
    const float *f1W0  = (const float*)d_in[13], *f1W1  = (const float*)d_in[23];
    const float *f1b0  = (const float*)d_in[14], *f1b1  = (const float*)d_in[24];
    const float *f2W0  = (const float*)d_in[15], *f2W1  = (const float*)d_in[25];
    const float *f2b0  = (const float*)d_in[16], *f2b1  = (const float*)d_in[26];

    // CSR (both branches batched)
    hipLaunchKernelGGL(k_init, dim3(cdiv(NN, 256), 2), dim3(256), 0, stream, deg, gstart, gend);
    hipLaunchKernelGGL(k_count, dim3(cdiv(EE, 256), 2), dim3(256), 0, stream, ei0, ei1, deg);
    hipLaunchKernelGGL(k_scan1, dim3(NSCB, 2), dim3(256), 0, stream, deg, offs, bsum);
    hipLaunchKernelGGL(k_scan2, dim3(1, 2), dim3(128), 0, stream, bsum);
    hipLaunchKernelGGL(k_scan3prep, dim3(NSCB, 2), dim3(256), 0, stream,
                       offs, bsum, cursor, deg, dinv, batch0, batch1, gstart, gend);
    hipLaunchKernelGGL(k_fill, dim3(cdiv(EPRIME, 256), 2), dim3(256), 0, stream, ei0, ei1, cursor, csr);

    // conversions: x -> bf16; per-head gatW^T; Vs/Vd
    hipLaunchKernelGGL(k_split_x, dim3(cdiv(NN * 128, 256), 2), dim3(256), 0, stream, x0, x1, xb);
    hipLaunchKernelGGL(k_wgtT, dim3(2, 2, 20), dim3(256), 0, stream, gatW0, gatW1, WgT);
    hipLaunchKernelGGL(k_vsd, dim3(5, 2), dim3(256), 0, stream,
                       gatW0, gatW1, asrc0, asrc1, adst0, adst1, Vs, Vd);

    // attention logits directly from x
    hipLaunchKernelGGL(k_att2, dim3(cdiv(NN * HH, 256), 2), dim3(256), 0, stream,
                       xb, Vs, Vd, a_s, a_d);

    // x-domain GAT aggregation -> Z (brA)
    hipLaunchKernelGGL(gat_aggx, dim3(cdiv(NN, 4), 2), dim3(256), 0, stream,
                       xb, a_s, a_d, offs, csr, Zb);

    // per-head GEMM: h1 = lrelu(Z_h @ W_h + b)  (writes brB, overwriting xb)
    hipLaunchKernelGGL(mfma_hgemm, dim3(NRB, 20), dim3(256), 0, stream,
                       Zb, WgT, gatb0, gatb1, xb);

    // gcnW -> transpose bf16
    hipLaunchKernelGGL(k_tbf, dim3(KP / 64, KP / 64, 2), dim3(256), 0, stream,
                       gcnW0, gcnW1, HFD, HFD, KP, Bt);

    // h2 = h1 @ gcnW (A = h1b in brB; C = h2b in brA over Z)
    hipLaunchKernelGGL(mfma_gemm, dim3(NRB * NCB, 2), dim3(256), 0, stream,
                       xb, Bt, KP, KP, NN, HFD, KP / 32, NCB, Zb, KP);

    // GCN aggregate -> hgcn bf16 (brB)
    hipLaunchKernelGGL(gcn_agg, dim3(cdiv(NN, 2), 2), dim3(256), 0, stream,
                       Zb, offs, csr, dinv, gcnb0, gcnb1, xb);

    // pooling (bf16 input)
    hipLaunchKernelGGL(k_pool, dim3(GG, 3, 2), dim3(64), 0, stream, xb, gstart, gend, gpool);

    // fcg1 split-K (partials into brA; h2 dead)
    hipLaunchKernelGGL(k_fcg1_part, dim3(16, 4, F1KS), dim3(256), 0, stream,
                       gpool, f1W0, f1W1, f1p0, f1p1);
    hipLaunchKernelGGL(k_fcg1_red, dim3(cdiv(GG * 1000, 256), 2), dim3(256), 0, stream,
                       f1p0, f1p1, f1b0, f1b1, fc1out);

    // fcg2
    hipLaunchKernelGGL(k_fcg2, dim3(GG, 2), dim3(256), 0, stream,
                       fc1out, f2W0, f2W1, f2b0, f2b1, bout);

    hipLaunchKernelGGL(k_final, dim3(GG), dim3(256), 0, stream,
                       bout, bout + (size_t)GG * 64, target,
                       (const float*)d_in[27], (const float*)d_in[28],
                       (const float*)d_in[29], (const float*)d_in[30],
                       (const float*)d_in[31], (const float*)d_in[32],
                       (const float*)d_in[33], (const float*)d_in[34],
                       (float*)d_out);
}

// Round 16
// 847.631 us; speedup vs baseline: 1.9265x; 1.0002x over previous
//
#include <hip/hip_runtime.h>
#include <cstddef>
#include <cstdint>

#define NN 20000
#define EE 160000
#define EPRIME 180000   // EE + NN (self loops)
#define GG 128
#define FF 114
#define HH 10
#define HFD 1140        // FF*HH
#define KP 1152         // padded feature dim
#define F1K 2280        // fcg1 K
#define F1KS 18         // split-K chunks
#define F1KC 128        // chunk size
#define NSCB 79         // scan blocks = cdiv(NN,256)

typedef unsigned short ushort_t;
typedef __attribute__((ext_vector_type(8))) short bf16x8;
typedef __attribute__((ext_vector_type(4))) float f32x4;

static constexpr size_t REL  = (size_t)NN * KP;      // [N][KP] region stride (ushorts)
static constexpr size_t ZREL = (size_t)10 * NN * 128; // Z region stride per branch (ushorts)

static inline int cdiv(int a, int b) { return (a + b - 1) / b; }

// ---------------- bf16 helpers ----------------

__device__ __forceinline__ ushort_t f2bf(float v) {
    union { float f; unsigned u; } c; c.f = v;
    unsigned u = c.u;
    unsigned r = (u + 0x7fffu + ((u >> 16) & 1u)) >> 16;   // RNE
    return (ushort_t)r;
}
__device__ __forceinline__ float bf2f(ushort_t h) {
    union { unsigned u; float f; } c; c.u = ((unsigned)h) << 16;
    return c.f;
}

__device__ __forceinline__ void gload16(const void* g, const ushort_t* l) {
    __builtin_amdgcn_global_load_lds(
        (const __attribute__((address_space(1))) unsigned int*)g,
        (__attribute__((address_space(3))) unsigned int*)l, 16, 0, 0);
}

// ---------------- CSR construction (branch = blockIdx.y) ----------------

__global__ void k_init(int* __restrict__ deg, int* __restrict__ gstart, int* __restrict__ gend) {
    int br = blockIdx.y;
    int i = blockIdx.x * blockDim.x + threadIdx.x;
    if (i < NN) deg[br * NN + i] = 1;               // self loop
    if (i < GG) { gstart[br * GG + i] = NN; gend[br * GG + i] = 0; }
}

__global__ void k_count(const int* __restrict__ ei0, const int* __restrict__ ei1,
                        int* __restrict__ deg) {
    int br = blockIdx.y;
    const int* ei = br ? ei1 : ei0;
    int i = blockIdx.x * blockDim.x + threadIdx.x;
    if (i < EE) atomicAdd(&deg[br * NN + ei[EE + i]], 1);
}

__global__ void k_scan1(const int* __restrict__ deg, int* __restrict__ offs, int* __restrict__ bsum) {
    __shared__ int tmp[256];
    int br = blockIdx.y;
    deg += br * NN; offs += br * (NN + 1); bsum += br * 128;
    int b = blockIdx.x, tid = threadIdx.x;
    int i = b * 256 + tid;
    int v = (i < NN) ? deg[i] : 0;
    tmp[tid] = v;
    __syncthreads();
#pragma unroll
    for (int off = 1; off < 256; off <<= 1) {
        int t = (tid >= off) ? tmp[tid - off] : 0;
        __syncthreads();
        tmp[tid] += t;
        __syncthreads();
    }
    if (i < NN) offs[i + 1] = tmp[tid];
    if (tid == 255) bsum[b] = tmp[255];
}

__global__ void k_scan2(int* __restrict__ bsum) {
    __shared__ int tmp[128];
    bsum += blockIdx.y * 128;
    int tid = threadIdx.x;
    int v = (tid < NSCB) ? bsum[tid] : 0;
    tmp[tid] = v;
    __syncthreads();
#pragma unroll
    for (int off = 1; off < 128; off <<= 1) {
        int t = (tid >= off) ? tmp[tid - off] : 0;
        __syncthreads();
        tmp[tid] += t;
        __syncthreads();
    }
    if (tid < NSCB) bsum[tid] = tmp[tid] - v;   // exclusive prefix
}

__global__ void k_scan3prep(int* __restrict__ offs, const int* __restrict__ bsum,
                            int* __restrict__ cursor, const int* __restrict__ deg,
                            float* __restrict__ dinv,
                            const int* __restrict__ batch0, const int* __restrict__ batch1,
                            int* __restrict__ gstart, int* __restrict__ gend) {
    int br = blockIdx.y;
    offs += br * (NN + 1); bsum += br * 128; cursor += br * NN;
    deg += br * NN; dinv += br * NN;
    const int* batch = br ? batch1 : batch0;
    gstart += br * GG; gend += br * GG;
    int i = blockIdx.x * 256 + threadIdx.x;
    if (i < NN) {
        int o = offs[i + 1] + bsum[i >> 8];
        offs[i + 1] = o;
        cursor[i] = o - deg[i];
        dinv[i] = rsqrtf((float)deg[i]);
        int b = batch[i];
        atomicMin(&gstart[b], i);
        atomicMax(&gend[b], i + 1);
    }
    if (i == 0) offs[0] = 0;
}

__global__ void k_fill(const int* __restrict__ ei0, const int* __restrict__ ei1,
                       int* __restrict__ cursor, int* __restrict__ csr) {
    int br = blockIdx.y;
    const int* ei = br ? ei1 : ei0;
    cursor += br * NN; csr += (size_t)br * EPRIME;
    int i = blockIdx.x * blockDim.x + threadIdx.x;
    if (i < EPRIME) {
        int s, d;
        if (i < EE) { s = ei[i]; d = ei[EE + i]; }
        else        { s = i - EE; d = s; }
        int pos = atomicAdd(&cursor[d], 1);
        csr[pos] = s;
    }
}

// ---------------- bf16 conversions ----------------

__global__ void k_split_x(const float* __restrict__ x0, const float* __restrict__ x1,
                          ushort_t* __restrict__ xb) {
    int br = blockIdx.y;
    const float* x = br ? x1 : x0;
    xb += (size_t)br * REL;
    int idx = blockIdx.x * 256 + threadIdx.x;
    if (idx >= NN * 128) return;
    int n = idx >> 7, k = idx & 127;
    float v = (k < FF) ? x[(size_t)n * FF + k] : 0.f;
    xb[idx] = f2bf(v);
}

// gcnW [K,Nc] -> T[n][k]=W[k][n], bf16, zero pad. branch = blockIdx.z
__global__ __launch_bounds__(256) void k_tbf(const float* __restrict__ W0, const float* __restrict__ W1,
                                             int K, int Nc, int Kpad, ushort_t* __restrict__ T) {
    __shared__ float tile[64][65];
    int br = blockIdx.z;
    const float* W = br ? W1 : W0;
    T += (size_t)br * KP * KP;
    int kb = blockIdx.x * 64;
    int nb = blockIdx.y * 64;
    int c = threadIdx.x & 63, r4 = threadIdx.x >> 6;
#pragma unroll
    for (int rr = 0; rr < 16; ++rr) {
        int r = r4 * 16 + rr;
        int gk = kb + r, gn = nb + c;
        tile[r][c] = (gk < K && gn < Nc) ? W[(size_t)gk * Nc + gn] : 0.f;
    }
    __syncthreads();
#pragma unroll
    for (int rr = 0; rr < 16; ++rr) {
        int r = r4 * 16 + rr;
        int gn = nb + r, gk = kb + c;
        T[(size_t)gn * Kpad + gk] = f2bf(tile[c][r]);
    }
}

// per-head gatW block transpose: WgT[br][h][c][k] = gatW[k][h*FF+c], 128x128 bf16, zero pad.
__global__ __launch_bounds__(256) void k_wgtT(const float* __restrict__ W0, const float* __restrict__ W1,
                                              ushort_t* __restrict__ WgT) {
    __shared__ float tile[64][65];
    int y = blockIdx.z;
    int br = y / 10, h = y - 10 * br;
    const float* W = br ? W1 : W0;
    ushort_t* T = WgT + ((size_t)br * 10 + h) * 128 * 128;
    int kb = blockIdx.x * 64, cb = blockIdx.y * 64;
    int c = threadIdx.x & 63, r4 = threadIdx.x >> 6;
#pragma unroll
    for (int rr = 0; rr < 16; ++rr) {
        int r = r4 * 16 + rr;
        int gk = kb + r, gc = cb + c;
        tile[r][c] = (gk < FF && gc < FF) ? W[(size_t)gk * HFD + h * FF + gc] : 0.f;
    }
    __syncthreads();
#pragma unroll
    for (int rr = 0; rr < 16; ++rr) {
        int r = r4 * 16 + rr;
        int gc2 = cb + r, gk2 = kb + c;
        T[(size_t)gc2 * 128 + gk2] = f2bf(tile[c][r]);
    }
}

// Vs/Vd [br][128][10] fp32: Vs[k][h] = sum_f gatW[k][h*FF+f]*att_src[h][f]
__global__ void k_vsd(const float* __restrict__ W0, const float* __restrict__ W1,
                      const float* __restrict__ as0, const float* __restrict__ as1,
                      const float* __restrict__ ad0, const float* __restrict__ ad1,
                      float* __restrict__ Vs, float* __restrict__ Vd) {
    int br = blockIdx.y;
    const float* W = br ? W1 : W0;
    const float* asrc = br ? as1 : as0;
    const float* adst = br ? ad1 : ad0;
    int idx = blockIdx.x * 256 + threadIdx.x;   // k*10+h
    if (idx >= 1280) return;
    int k = idx / 10, h = idx - 10 * (idx / 10);
    float vs = 0.f, vd = 0.f;
    if (k < FF) {
        const float* wrow = W + (size_t)k * HFD + h * FF;
        const float* s = asrc + h * FF;
        const float* d = adst + h * FF;
        for (int f = 0; f < FF; ++f) { vs += wrow[f] * s[f]; vd += wrow[f] * d[f]; }
    }
    Vs[br * 1280 + idx] = vs;
    Vd[br * 1280 + idx] = vd;
}

// attention logits from xb: a_s[n,h] = x[n,:] . Vs[:,h]
__global__ void k_att2(const ushort_t* __restrict__ xbase,
                       const float* __restrict__ Vs, const float* __restrict__ Vd,
                       float* __restrict__ as_, float* __restrict__ ad_) {
    int br = blockIdx.y;
    const ushort_t* xb = xbase + (size_t)br * REL;
    const float* vs = Vs + br * 1280;
    const float* vd = Vd + br * 1280;
    as_ += (size_t)br * NN * HH; ad_ += (size_t)br * NN * HH;
    int id = blockIdx.x * blockDim.x + threadIdx.x;
    if (id >= NN * HH) return;
    int n = id / HH, h = id - HH * (id / HH);
    const ushort_t* row = xb + (size_t)n * 128;
    float as = 0.f, ad = 0.f;
    for (int k = 0; k < FF; k += 2) {
        unsigned qq = *(const unsigned*)(row + k);
        float v0 = bf2f((ushort_t)(qq & 0xffffu));
        float v1 = bf2f((ushort_t)(qq >> 16));
        as += v0 * vs[k * 10 + h] + v1 * vs[(k + 1) * 10 + h];
        ad += v0 * vd[k * 10 + h] + v1 * vd[(k + 1) * 10 + h];
    }
    as_[id] = as;
    ad_[id] = ad;
}

// ---------------- x-domain GAT aggregation: Z[br][h][n][128] bf16 ----------------

template <int NU>
__device__ __forceinline__ void gax_grp(
    int eg, int end, int lane, float my_ad,
    const int* __restrict__ csr, const float* __restrict__ as_,
    const ushort_t* __restrict__ xb,
    float& den, float acc[HH][2]) {
    int s[NU]; float ex[NU];
#pragma unroll
    for (int u = 0; u < NU; ++u) {
        int idx = eg + u; if (idx > end - 1) idx = end - 1;   // clamp (weight zeroed)
        s[u] = csr[idx];
    }
#pragma unroll
    for (int u = 0; u < NU; ++u) {
        float e = 0.f;
        if (lane < HH) {
            float t = as_[s[u] * HH + lane] + my_ad;
            t = (t >= 0.f) ? t : 0.2f * t;
            e = __expf(t);
            if (eg + u >= end) e = 0.f;
        }
        ex[u] = e;
        den += e;
    }
    unsigned xv[NU];
#pragma unroll
    for (int u = 0; u < NU; ++u)
        xv[u] = *(const unsigned*)(xb + (size_t)s[u] * 128 + 2 * lane);
#pragma unroll
    for (int u = 0; u < NU; ++u) {
        float x0 = bf2f((ushort_t)(xv[u] & 0xffffu));
        float x1 = bf2f((ushort_t)(xv[u] >> 16));
#pragma unroll
        for (int h = 0; h < HH; ++h) {
            float w = __shfl(ex[u], h, 64);
            acc[h][0] += w * x0;
            acc[h][1] += w * x1;
        }
    }
}

__global__ __launch_bounds__(256) void gat_aggx(
    const ushort_t* __restrict__ xbase,
    const float* __restrict__ as_, const float* __restrict__ ad_,
    const int* __restrict__ offs, const int* __restrict__ csr,
    ushort_t* __restrict__ Z) {
    int br = blockIdx.y;
    const ushort_t* xb = xbase + (size_t)br * REL;
    as_ += (size_t)br * NN * HH; ad_ += (size_t)br * NN * HH;
    offs += br * (NN + 1); csr += (size_t)br * EPRIME;
    ushort_t* Zb = Z + (size_t)br * ZREL;

    int lane = threadIdx.x & 63;
    int n = blockIdx.x * 4 + (threadIdx.x >> 6);
    if (n >= NN) return;
    int beg = offs[n], end = offs[n + 1];
    float my_ad = (lane < HH) ? ad_[n * HH + lane] : 0.f;

    float den = 0.f;
    float acc[HH][2];
#pragma unroll
    for (int h = 0; h < HH; ++h) { acc[h][0] = 0.f; acc[h][1] = 0.f; }

    int eg = beg;
    for (; eg + 8 <= end; eg += 8)
        gax_grp<8>(eg, end, lane, my_ad, csr, as_, xb, den, acc);
    for (; eg < end; eg += 4)
        gax_grp<4>(eg, end, lane, my_ad, csr, as_, xb, den, acc);

#pragma unroll
    for (int h = 0; h < HH; ++h) {
        float d = __shfl(den, h, 64);
        float inv = 1.f / d;                    // den >= exp(self-loop) > 0
        unsigned pk = (unsigned)f2bf(acc[h][0] * inv)
                    | ((unsigned)f2bf(acc[h][1] * inv) << 16);
        *(unsigned*)(Zb + ((size_t)h * NN + n) * 128 + 2 * lane) = pk;
    }
}

// ---------------- per-head GEMM: h1[:, hFF..hFF+113] = lrelu(Z_h @ WgT_h^T + b) ----------------

__global__ __launch_bounds__(256) void mfma_hgemm(
    const ushort_t* __restrict__ Zbase, const ushort_t* __restrict__ WgT,
    const float* __restrict__ b0, const float* __restrict__ b1,
    ushort_t* __restrict__ Cbase) {
    __shared__ __align__(16) ushort_t lds[2 * 8192];
    int y = blockIdx.y;
    int br = y / 10, h = y - 10 * br;
    const ushort_t* A = Zbase + (size_t)br * ZREL + (size_t)h * NN * 128;
    const ushort_t* Bt = WgT + ((size_t)br * 10 + h) * 128 * 128;
    const float* bias = (br ? b1 : b0) + h * FF;
    ushort_t* Cb = Cbase + (size_t)br * REL;

    const int tid = threadIdx.x;
    const int lane = tid & 63;
    const int w = tid >> 6;
    const int wr = w >> 1, wc = w & 1;

    int nwg = gridDim.x;
    int q = nwg >> 3, r8 = nwg & 7;
    int xcd = blockIdx.x & 7, sidx = blockIdx.x >> 3;
    int wg = (xcd < r8 ? xcd * (q + 1) : r8 * (q + 1) + (xcd - r8) * q) + sidx;

    int row0 = wg * 128; if (row0 > NN - 128) row0 = NN - 128;   // overlap trick

    f32x4 acc[4][4];
#pragma unroll
    for (int i = 0; i < 4; ++i)
#pragma unroll
        for (int j = 0; j < 4; ++j) acc[i][j] = (f32x4){0.f, 0.f, 0.f, 0.f};

    const char* pA[2]; const char* pB[2];
    unsigned ldsoff[2];
#pragma unroll
    for (int i = 0; i < 2; ++i) {
        int c = (w * 2 + i) * 64 + lane;
        int kg = c >> 7, r = c & 127;
        pA[i] = (const char*)A + (size_t)(row0 + r) * 256 + kg * 16;
        pB[i] = (const char*)Bt + (size_t)r * 256 + kg * 16;
        ldsoff[i] = (w * 2 + i) * 512;
    }
    const int kgf = lane >> 4, r15 = lane & 15;

    auto STAGE = [&](int buf, int ks) {
        size_t kb = (size_t)ks * 64;
        unsigned bo = buf ? 8192u : 0u;
#pragma unroll
        for (int i = 0; i < 2; ++i) {
            gload16(pA[i] + kb, lds + bo + 0 + ldsoff[i]);
            gload16(pB[i] + kb, lds + bo + 4096 + ldsoff[i]);
        }
    };

    STAGE(0, 0);
    asm volatile("s_waitcnt vmcnt(0)" ::: "memory");
    __syncthreads();
    int cur = 0;

    for (int ks = 0; ks < 4; ++ks) {
        if (ks + 1 < 4) STAGE(cur ^ 1, ks + 1);
        const ushort_t* lb = lds + (cur ? 8192u : 0u);
        bf16x8 ah[4], bh[4];
#pragma unroll
        for (int i = 0; i < 4; ++i) {
            int ra = wr * 64 + i * 16 + r15;
            int rb = wc * 64 + i * 16 + r15;
            ah[i] = *(const bf16x8*)(lb + 0 + kgf * 1024 + ra * 8);
            bh[i] = *(const bf16x8*)(lb + 4096 + kgf * 1024 + rb * 8);
        }
#pragma unroll
        for (int i = 0; i < 4; ++i)
#pragma unroll
            for (int j = 0; j < 4; ++j)
                acc[i][j] = __builtin_amdgcn_mfma_f32_16x16x32_bf16(ah[i], bh[j], acc[i][j], 0, 0, 0);
        asm volatile("s_waitcnt vmcnt(0)" ::: "memory");
        __syncthreads();
        cur ^= 1;
    }

    const int g4 = lane >> 4;
#pragma unroll
    for (int i = 0; i < 4; ++i)
#pragma unroll
        for (int j = 0; j < 4; ++j) {
            int c = wc * 64 + j * 16 + r15;
#pragma unroll
            for (int reg = 0; reg < 4; ++reg) {
                int r = row0 + wr * 64 + i * 16 + g4 * 4 + reg;
                int gc = h * FF + c;
                if (c < FF) {
                    float v = acc[i][j][reg] + bias[c];
                    v = (v >= 0.f) ? v : 0.01f * v;
                    Cb[(size_t)r * KP + gc] = f2bf(v);
                } else if (h == 9 && gc < KP) {
                    Cb[(size_t)r * KP + gc] = 0;   // zero pad cols 1140..1151
                }
            }
        }
}

// ---------------- full-bf16 MFMA GEMM (h2 = h1 @ gcnW): 3-stage counted-vmcnt ----------------
// T4-minimum: 48KB LDS (3 stages), raw s_barrier with vmcnt(4) — one stage (4 loads/thread)
// stays in flight ACROSS each barrier (r6's failure was 1 block/CU at BM=256; here 3 blocks/CU).
// Ledger: iter k issues STAGE(k+2) into buf last read at k-1 (barrier-protected); end-of-iter
// vmcnt(4) retires stage k+1; tail drains vmcnt(0) for final 2 iters. ksteps>=2 required.

__global__ __launch_bounds__(256) void mfma_gemm(
    const ushort_t* __restrict__ Abase, const ushort_t* __restrict__ Btbase,
    int lda, int ldb, int M, int Nreal, int ksteps, int ncb,
    ushort_t* __restrict__ Cbase, int ldcs) {
    __shared__ __align__(16) ushort_t lds[3 * 8192];
    const int br = blockIdx.y;
    const ushort_t* A = Abase + (size_t)br * REL;
    const ushort_t* Bt = Btbase + (size_t)br * KP * KP;
    ushort_t* Cb = Cbase + (size_t)br * ZREL;          // C lives in brA (Z region)

    const int tid = threadIdx.x;
    const int lane = tid & 63;
    const int w = tid >> 6;
    const int wr = w >> 1, wc = w & 1;

    int nwg = gridDim.x;
    int q = nwg >> 3, r8 = nwg & 7;
    int xcd = blockIdx.x & 7, sidx = blockIdx.x >> 3;
    int wg = (xcd < r8 ? xcd * (q + 1) : r8 * (q + 1) + (xcd - r8) * q) + sidx;
    int brow = wg / ncb, bcol = wg - brow * ncb;

    int row0 = brow * 128; if (row0 > M - 128) row0 = M - 128;
    const int col0 = bcol * 128;

    f32x4 acc[4][4];
#pragma unroll
    for (int i = 0; i < 4; ++i)
#pragma unroll
        for (int j = 0; j < 4; ++j) acc[i][j] = (f32x4){0.f, 0.f, 0.f, 0.f};

    const size_t ldaB = (size_t)lda * 2, ldbB = (size_t)ldb * 2;
    const char* pA[2]; const char* pB[2];
    unsigned ldsoff[2];
#pragma unroll
    for (int i = 0; i < 2; ++i) {
        int c = (w * 2 + i) * 64 + lane;
        int kg = c >> 7, r = c & 127;
        pA[i] = (const char*)A + (size_t)(row0 + r) * ldaB + kg * 16;
        pB[i] = (const char*)Bt + (size_t)(col0 + r) * ldbB + kg * 16;
        ldsoff[i] = (w * 2 + i) * 512;
    }
    const int kgf = lane >> 4, r15 = lane & 15;

    auto STAGE = [&](int stg, int ks) {
        size_t kb = (size_t)ks * 64;
        unsigned bo = (unsigned)stg * 8192u;
#pragma unroll
        for (int i = 0; i < 2; ++i) {
            gload16(pA[i] + kb, lds + bo + 0 + ldsoff[i]);
            gload16(pB[i] + kb, lds + bo + 4096 + ldsoff[i]);
        }
    };

    // prologue: two stages in flight, wait for stage 0 only (vmcnt counts 4 loads/stage)
    STAGE(0, 0);
    STAGE(1, 1);
    asm volatile("s_waitcnt vmcnt(4)" ::: "memory");
    __builtin_amdgcn_s_barrier();
    __builtin_amdgcn_sched_barrier(0);

    for (int ks = 0; ks < ksteps; ++ks) {
        if (ks + 2 < ksteps) STAGE((ks + 2) % 3, ks + 2);
        const ushort_t* lb = lds + (ks % 3) * 8192;
        bf16x8 ah[4], bh[4];
#pragma unroll
        for (int i = 0; i < 4; ++i) {
            int ra = wr * 64 + i * 16 + r15;
            int rb = wc * 64 + i * 16 + r15;
            ah[i] = *(const bf16x8*)(lb + 0 + kgf * 1024 + ra * 8);
            bh[i] = *(const bf16x8*)(lb + 4096 + kgf * 1024 + rb * 8);
        }
#pragma unroll
        for (int i = 0; i < 4; ++i)
#pragma unroll
            for (int j = 0; j < 4; ++j)
                acc[i][j] = __builtin_amdgcn_mfma_f32_16x16x32_bf16(ah[i], bh[j], acc[i][j], 0, 0, 0);
        if (ks + 2 < ksteps) { asm volatile("s_waitcnt vmcnt(4)" ::: "memory"); }
        else                 { asm volatile("s_waitcnt vmcnt(0)" ::: "memory"); }
        __builtin_amdgcn_s_barrier();
        __builtin_amdgcn_sched_barrier(0);
    }

    const int g4 = lane >> 4;
#pragma unroll
    for (int i = 0; i < 4; ++i)
#pragma unroll
        for (int j = 0; j < 4; ++j) {
            int c = col0 + wc * 64 + j * 16 + r15;
#pragma unroll
            for (int reg = 0; reg < 4; ++reg) {
                int r = row0 + wr * 64 + i * 16 + g4 * 4 + reg;
                if (r < M) {
                    float v = (c < Nreal) ? acc[i][j][reg] : 0.f;
                    Cb[(size_t)r * ldcs + c] = f2bf(v);
                }
            }
        }
}

// ---------------- GCN aggregation: wave-PAIR per node, bf16 in/out ----------------

template <int NU, int HASB>
__device__ __forceinline__ void gcn_grp(
    int eg, int end, int lane, float di,
    const int* __restrict__ csr, const float* __restrict__ dinv,
    const ushort_t* __restrict__ h2b, int kbA, int kbB,
    float* accA, float* accB) {
    int s[NU]; float w[NU];
#pragma unroll
    for (int u = 0; u < NU; ++u) {
        int idx = eg + u; if (idx > end - 1) idx = end - 1;
        s[u] = csr[idx];
    }
#pragma unroll
    for (int u = 0; u < NU; ++u) {
        float ww = dinv[s[u]] * di;
        w[u] = (eg + u < end) ? ww : 0.f;
    }
    bf16x8 qv[NU];
#pragma unroll
    for (int u = 0; u < NU; ++u) qv[u] = *(const bf16x8*)(h2b + (size_t)s[u] * KP + kbA);
#pragma unroll
    for (int u = 0; u < NU; ++u)
#pragma unroll
        for (int e = 0; e < 8; ++e) accA[e] += w[u] * bf2f((ushort_t)qv[u][e]);
    if (HASB && lane < 16) {
#pragma unroll
        for (int u = 0; u < NU; ++u) qv[u] = *(const bf16x8*)(h2b + (size_t)s[u] * KP + kbB);
#pragma unroll
        for (int u = 0; u < NU; ++u)
#pragma unroll
            for (int e = 0; e < 8; ++e) accB[e] += w[u] * bf2f((ushort_t)qv[u][e]);
    }
}

__global__ __launch_bounds__(256) void gcn_agg(
    const ushort_t* __restrict__ h2base, const int* __restrict__ offs, const int* __restrict__ csr,
    const float* __restrict__ dinv,
    const float* __restrict__ b0, const float* __restrict__ b1,
    ushort_t* __restrict__ outbase) {
    int br = blockIdx.y;
    const ushort_t* h2b = h2base + (size_t)br * ZREL;   // h2 lives in brA (Z region)
    offs += br * (NN + 1); csr += (size_t)br * EPRIME; dinv += br * NN;
    const float* bias = br ? b1 : b0;
    ushort_t* outb = outbase + (size_t)br * REL;

    int lane = threadIdx.x & 63;
    int wid = threadIdx.x >> 6;
    int n = blockIdx.x * 2 + (wid >> 1);
    int half = wid & 1;
    if (n >= NN) return;
    int beg = offs[n], end = offs[n + 1];
    float di = dinv[n];
    const int kbA = (half ? 512 : 0) + 8 * lane;
    const int kbB = 1024 + 8 * lane;
    float accA[8] = {}, accB[8] = {};

    int eg = beg;
    if (half == 0) {
        for (; eg + 8 <= end; eg += 8)
            gcn_grp<8, 1>(eg, end, lane, di, csr, dinv, h2b, kbA, kbB, accA, accB);
        for (; eg < end; eg += 4)
            gcn_grp<4, 1>(eg, end, lane, di, csr, dinv, h2b, kbA, kbB, accA, accB);
    } else {
        for (; eg + 8 <= end; eg += 8)
            gcn_grp<8, 0>(eg, end, lane, di, csr, dinv, h2b, kbA, kbB, accA, accB);
        for (; eg < end; eg += 4)
            gcn_grp<4, 0>(eg, end, lane, di, csr, dinv, h2b, kbA, kbB, accA, accB);
    }

    {
        bf16x8 vb;
#pragma unroll
        for (int e = 0; e < 8; ++e) {
            float v = accA[e] + bias[kbA + e];
            v = (v >= 0.f) ? v : 0.01f * v;
            vb[e] = (short)f2bf(v);
        }
        *(bf16x8*)(outb + (size_t)n * KP + kbA) = vb;
    }
    if (half == 0 && lane < 16) {
        bf16x8 vb;
#pragma unroll
        for (int e = 0; e < 8; ++e) {
            int k = kbB + e;
            float v = 0.f;
            if (k < HFD) {
                v = accB[e] + bias[k];
                v = (v >= 0.f) ? v : 0.01f * v;
            }
            vb[e] = (short)f2bf(v);
        }
        *(bf16x8*)(outb + (size_t)n * KP + kbB) = vb;
    }
}

// ---------------- graph pooling (max + mean), bf16 input ----------------

__global__ void k_pool(const ushort_t* __restrict__ hbase, const int* __restrict__ gs,
                       const int* __restrict__ ge, float* __restrict__ gpool) {
    int br = blockIdx.z;
    const ushort_t* hfeat = hbase + (size_t)br * REL;
    gs += br * GG; ge += br * GG;
    float* gout = gpool + (size_t)br * GG * 2 * HFD;
    if (threadIdx.x >= 48) return;
    int g = blockIdx.x;
    int mg = blockIdx.y * 48 + threadIdx.x;
    int s = gs[g], e = ge[g];
    int cnt = e - s;
    float mx[8], sm[8];
#pragma unroll
    for (int j = 0; j < 8; ++j) { mx[j] = -1e30f; sm[j] = 0.f; }
    for (int r = s; r < e; ++r) {
        bf16x8 qv = *(const bf16x8*)(hfeat + (size_t)r * KP + 8 * mg);
#pragma unroll
        for (int j = 0; j < 8; ++j) {
            float v = bf2f((ushort_t)qv[j]);
            mx[j] = fmaxf(mx[j], v);
            sm[j] += v;
        }
    }
    float inv = (cnt > 0) ? 1.f / (float)cnt : 0.f;
#pragma unroll
    for (int j = 0; j < 8; ++j) {
        int k = 8 * mg + j;
        if (k < HFD) {
            float m = (cnt > 0) ? mx[j] : 0.f;
            gout[(size_t)g * (2 * HFD) + k] = m;
            gout[(size_t)g * (2 * HFD) + HFD + k] = sm[j] * inv;
        }
    }
}

// ---------------- fcg1 split-K (kt loop MUST stay rolled — round-3 spill regression) ----------------

__global__ __launch_bounds__(256) void k_fcg1_part(
    const float* __restrict__ gpool, const float* __restrict__ B0, const float* __restrict__ B1,
    float* __restrict__ p0, float* __restrict__ p1) {
    __shared__ float As[16][64 + 4];
    __shared__ float Bs[16][64 + 4];
    int br = blockIdx.y >> 1, rowblk = blockIdx.y & 1;
    const float* A = gpool + (size_t)br * GG * F1K;
    const float* B = br ? B1 : B0;
    float* part = br ? p1 : p0;
    int tid = threadIdx.x;
    int tx = tid & 15, ty = tid >> 4;
    int row0 = rowblk * 64, col0 = blockIdx.x * 64;
    int kbeg = blockIdx.z * F1KC;
    float acc[4][4] = {};
#pragma unroll 1
    for (int kt = 0; kt < F1KC / 16; ++kt) {
        int kk = kbeg + kt * 16;
#pragma unroll
        for (int l = 0; l < 4; ++l) {
            int idx = tid + 256 * l;
            int m = idx >> 4, k = idx & 15;
            int gr = row0 + m, gk = kk + k;
            As[k][m] = (gk < F1K) ? A[(size_t)gr * F1K + gk] : 0.f;
        }
#pragma unroll
        for (int l = 0; l < 4; ++l) {
            int idx = tid + 256 * l;
            int nn = idx & 63, k = idx >> 6;
            int gc = col0 + nn, gk = kk + k;
            Bs[k][nn] = (gc < 1000 && gk < F1K) ? B[(size_t)gk * 1000 + gc] : 0.f;
        }
        __syncthreads();
#pragma unroll
        for (int k = 0; k < 16; ++k) {
            float4 av = *(const float4*)&As[k][ty * 4];
            float4 bv = *(const float4*)&Bs[k][tx * 4];
            float a[4] = {av.x, av.y, av.z, av.w};
            float b[4] = {bv.x, bv.y, bv.z, bv.w};
#pragma unroll
            for (int i = 0; i < 4; ++i)
#pragma unroll
                for (int j = 0; j < 4; ++j) acc[i][j] += a[i] * b[j];
        }
        __syncthreads();
    }
    float* pc = part + (size_t)blockIdx.z * GG * 1000;
#pragma unroll
    for (int i = 0; i < 4; ++i) {
        int r = row0 + ty * 4 + i;
#pragma unroll
        for (int j = 0; j < 4; ++j) {
            int c = col0 + tx * 4 + j;
            if (c < 1000) pc[(size_t)r * 1000 + c] = acc[i][j];
        }
    }
}

__global__ void k_fcg1_red(const float* __restrict__ p0, const float* __restrict__ p1,
                           const float* __restrict__ b0, const float* __restrict__ b1,
                           float* __restrict__ fc1out) {
    int br = blockIdx.y;
    const float* part = br ? p1 : p0;
    const float* bias = br ? b1 : b0;
    float* out = fc1out + (size_t)br * GG * 1000;
    int idx = blockIdx.x * 256 + threadIdx.x;
    if (idx >= GG * 1000) return;
    float s = 0.f;
#pragma unroll
    for (int k = 0; k < F1KS; ++k) s += part[(size_t)k * GG * 1000 + idx];
    int n = idx % 1000;
    float v = s + bias[n];
    out[idx] = (v >= 0.f) ? v : 0.01f * v;
}

// ---------------- fcg2 ----------------

__global__ __launch_bounds__(256) void k_fcg2(const float* __restrict__ fc1out,
                                              const float* __restrict__ W0, const float* __restrict__ W1,
                                              const float* __restrict__ b0, const float* __restrict__ b1,
                                              float* __restrict__ bout) {
    __shared__ float part[4][64];
    int br = blockIdx.y;
    const float* in = fc1out + (size_t)br * GG * 1000;
    const float* W = br ? W1 : W0;
    const float* b = br ? b1 : b0;
    float* out = bout + (size_t)br * GG * 64;
    int g = blockIdx.x;
    int o = threadIdx.x & 63, p = threadIdx.x >> 6;
    const float* row = in + (size_t)g * 1000;
    float acc = 0.f;
    for (int k = p * 250; k < (p + 1) * 250; ++k) acc += row[k] * W[k * 64 + o];
    part[p][o] = acc;
    __syncthreads();
    if (p == 0) out[(size_t)g * 64 + o] = part[0][o] + part[1][o] + part[2][o] + part[3][o] + b[o];
}

// ---------------- final head ----------------

__global__ __launch_bounds__(256) void k_final(
    const float* __restrict__ b1, const float* __restrict__ b2, const float* __restrict__ target,
    const float* __restrict__ fcxtW, const float* __restrict__ fcxtb,
    const float* __restrict__ fc1W, const float* __restrict__ fc1b,
    const float* __restrict__ fc2W, const float* __restrict__ fc2b,
    const float* __restrict__ outW, const float* __restrict__ outb,
    float* __restrict__ out) {
    __shared__ float xc[256];
    __shared__ float xt2[128];
    __shared__ float y1[128];
    __shared__ float y2[32];
    int g = blockIdx.x, t = threadIdx.x;
    if (t < 64) xc[t] = b1[(size_t)g * 64 + t];
    else if (t < 128) xc[t] = b2[(size_t)g * 64 + (t - 64)];
    {
        int c = t & 127, p = t >> 7;
        float acc = 0.f;
        const float* trow = target + (size_t)g * 1000;
        for (int k = p * 500; k < (p + 1) * 500; ++k) acc += trow[k] * fcxtW[k * 128 + c];
        if (p == 1) xt2[c] = acc;
        __syncthreads();
        if (p == 0) xc[128 + c] = acc + xt2[c] + fcxtb[c];
    }
    __syncthreads();
    if (t < 128) {
        float acc = 0.f;
        for (int k = 0; k < 256; ++k) acc += xc[k] * fc1W[k * 128 + t];
        acc += fc1b[t];
        y1[t] = (acc >= 0.f) ? acc : 0.01f * acc;
    }
    __syncthreads();
    if (t < 32) {
        float acc = 0.f;
        for (int k = 0; k < 128; ++k) acc += y1[k] * fc2W[k * 32 + t];
        acc += fc2b[t];
        y2[t] = (acc >= 0.f) ? acc : 0.01f * acc;
    }
    __syncthreads();
    if (t == 0) {
        float acc = 0.f;
        for (int k = 0; k < 32; ++k) acc += y2[k] * outW[k];
        out[g] = acc + outb[0];
    }
}

// ---------------- host launch ----------------

extern "C" void kernel_launch(void* const* d_in, const int* in_sizes, int n_in,
                              void* d_out, int out_size, void* d_ws, size_t ws_size,
                              hipStream_t stream) {
    (void)in_sizes; (void)n_in; (void)out_size; (void)ws_size;

    size_t off = 0;
    auto alloc = [&](size_t bytes) -> void* {
        void* p = (char*)d_ws + off;
        off += (bytes + 255) & ~(size_t)255;
        return p;
    };
    char* brA = (char*)alloc(2 * ZREL * 2);   // per-branch: Z -> h2b -> f1part overlays
    char* brB = (char*)alloc(2 * REL * 2);    // per-branch: xb -> h1b -> hgcnb overlays
    ushort_t* Bt  = (ushort_t*)alloc(2 * (size_t)KP * KP * 2);
    ushort_t* WgT = (ushort_t*)alloc(20 * (size_t)128 * 128 * 2);
    float* Vs     = (float*)alloc(2 * 1280 * 4);
    float* Vd     = (float*)alloc(2 * 1280 * 4);
    float* a_s    = (float*)alloc(2 * (size_t)NN * HH * 4);
    float* a_d    = (float*)alloc(2 * (size_t)NN * HH * 4);
    int*   deg    = (int*)alloc(2 * (size_t)NN * 4);
    int*   offs   = (int*)alloc(2 * (size_t)(NN + 1) * 4);
    int*   cursor = (int*)alloc(2 * (size_t)NN * 4);
    int*   csr    = (int*)alloc(2 * (size_t)EPRIME * 4);
    float* dinv   = (float*)alloc(2 * (size_t)NN * 4);
    int*   gstart = (int*)alloc(2 * (size_t)GG * 4);
    int*   gend   = (int*)alloc(2 * (size_t)GG * 4);
    int*   bsum   = (int*)alloc(2 * (size_t)128 * 4);
    float* gpool  = (float*)alloc(2 * (size_t)GG * 2 * HFD * 4);
    float* fc1out = (float*)alloc(2 * (size_t)GG * 1000 * 4);
    float* bout   = (float*)alloc(2 * (size_t)GG * 64 * 4);

    ushort_t* Zb  = (ushort_t*)brA;               // + br*ZREL (overlay: h2b, f1part)
    float* f1p0 = (float*)brA;
    float* f1p1 = (float*)(brA + (size_t)F1KS * GG * 1000 * 4);
    ushort_t* xb  = (ushort_t*)brB;               // + br*REL (overlay: h1b, hgcnb)

    const float* target = (const float*)d_in[6];
    const int NRB = cdiv(NN, 128);        // 157 row blocks
    const int NCB = KP / 128;             // 9 col blocks

    const float* x0 = (const float*)d_in[0];
    const float* x1 = (const float*)d_in[3];
    const int* ei0 = (const int*)d_in[1];
    const int* ei1 = (const int*)d_in[4];
    const int* batch0 = (const int*)d_in[2];
    const int* batch1 = (const int*)d_in[5];
    const float *gatW0 = (const float*)d_in[7],  *gatW1 = (const float*)d_in[17];
    const float *asrc0 = (const float*)d_in[8],  *asrc1 = (const float*)d_in[18];
    const float *adst0 = (const float*)d_in[9],  *adst1 = (const float*)d_in[19];
    const float *gatb0 = (const float*)d_in[10], *gatb1 = (const float*)d_in[20];
    const float *gcnW0 = (const float*)d_in[11], *gcnW1 = (const float*)d_in[21];
    const float *gcnb0 = (const float*)d_in[12], *gcnb1 = (const float*)d_in[22];
    const float *f1W0  = (const float*)d_in[13], *f1W1  = (const float*)d_in[23];
    const float *f1b0  = (const float*)d_in[14], *f1b1  = (const float*)d_in[24];
    const float *f2W0  = (const float*)d_in[15], *f2W1  = (const float*)d_in[25];
    const float *f2b0  = (const float*)d_in[16], *f2b1  = (const float*)d_in[26];

    // CSR (both branches batched)
    hipLaunchKernelGGL(k_init, dim3(cdiv(NN, 256), 2), dim3(256), 0, stream, deg, gstart, gend);
    hipLaunchKernelGGL(k_count, dim3(cdiv(EE, 256), 2), dim3(256), 0, stream, ei0, ei1, deg);
    hipLaunchKernelGGL(k_scan1, dim3(NSCB, 2), dim3(256), 0, stream, deg, offs, bsum);
    hipLaunchKernelGGL(k_scan2, dim3(1, 2), dim3(128), 0, stream, bsum);
    hipLaunchKernelGGL(k_scan3prep, dim3(NSCB, 2), dim3(256), 0, stream,
                       offs, bsum, cursor, deg, dinv, batch0, batch1, gstart, gend);
    hipLaunchKernelGGL(k_fill, dim3(cdiv(EPRIME, 256), 2), dim3(256), 0, stream, ei0, ei1, cursor, csr);

    // conversions: x -> bf16; per-head gatW^T; Vs/Vd
    hipLaunchKernelGGL(k_split_x, dim3(cdiv(NN * 128, 256), 2), dim3(256), 0, stream, x0, x1, xb);
    hipLaunchKernelGGL(k_wgtT, dim3(2, 2, 20), dim3(256), 0, stream, gatW0, gatW1, WgT);
    hipLaunchKernelGGL(k_vsd, dim3(5, 2), dim3(256), 0, stream,
                       gatW0, gatW1, asrc0, asrc1, adst0, adst1, Vs, Vd);

    // attention logits directly from x
    hipLaunchKernelGGL(k_att2, dim3(cdiv(NN * HH, 256), 2), dim3(256), 0, stream,
                       xb, Vs, Vd, a_s, a_d);

    // x-domain GAT aggregation -> Z (brA)
    hipLaunchKernelGGL(gat_aggx, dim3(cdiv(NN, 4), 2), dim3(256), 0, stream,
                       xb, a_s, a_d, offs, csr, Zb);

    // per-head GEMM: h1 = lrelu(Z_h @ W_h + b)  (writes brB, overwriting xb)
    hipLaunchKernelGGL(mfma_hgemm, dim3(NRB, 20), dim3(256), 0, stream,
                       Zb, WgT, gatb0, gatb1, xb);

    // gcnW -> transpose bf16
    hipLaunchKernelGGL(k_tbf, dim3(KP / 64, KP / 64, 2), dim3(256), 0, stream,
                       gcnW0, gcnW1, HFD, HFD, KP, Bt);

    // h2 = h1 @ gcnW (A = h1b in brB; C = h2b in brA over Z) — 3-stage counted-vmcnt
    hipLaunchKernelGGL(mfma_gemm, dim3(NRB * NCB, 2), dim3(256), 0, stream,
                       xb, Bt, KP, KP, NN, HFD, KP / 32, NCB, Zb, KP);

    // GCN aggregate -> hgcn bf16 (brB)
    hipLaunchKernelGGL(gcn_agg, dim3(cdiv(NN, 2), 2), dim3(256), 0, stream,
                       Zb, offs, csr, dinv, gcnb0, gcnb1, xb);

    // pooling (bf16 input)
    hipLaunchKernelGGL(k_pool, dim3(GG, 3, 2), dim3(64), 0, stream, xb, gstart, gend, gpool);

    // fcg1 split-K (partials into brA; h2 dead)
    hipLaunchKernelGGL(k_fcg1_part, dim3(16, 4, F1KS), dim3(256), 0, stream,
                       gpool, f1W0, f1W1, f1p0, f1p1);
    hipLaunchKernelGGL(k_fcg1_red, dim3(cdiv(GG * 1000, 256), 2), dim3(256), 0, stream,
                       f1p0, f1p1, f1b0, f1b1, fc1out);

    // fcg2
    hipLaunchKernelGGL(k_fcg2, dim3(GG, 2), dim3(256), 0, stream,
                       fc1out, f2W0, f2W1, f2b0, f2b1, bout);

    hipLaunchKernelGGL(k_final, dim3(GG), dim3(256), 0, stream,
                       bout, bout + (size_t)GG * 64, target,
                       (const float*)d_in[27], (const float*)d_in[28],
                       (const float*)d_in[29], (const float*)d_in[30],
                       (const float*)d_in[31], (const float*)d_in[32],
                       (const float*)d_in[33], (const float*)d_in[34],
                       (float*)d_out);
}